// Round 1
// baseline (803.638 us; speedup 1.0000x reference)
//
#include <hip/hip_runtime.h>
#include <math.h>

// Problem constants
#define BB   4
#define HH   32
#define WW   32
#define DIM  768
#define NH   12
#define HD   64
#define HWN  1024          // H*W tokens per image
#define MROWS 4096         // B*HW
#define BHEADS 48          // B*NH

// ---------------------------------------------------------------------------
// fp32 tiled GEMM: Y = X @ W + bias.  X: (4096,768), W: (768,768), tile 64x64.
// head_layout=1: write into (B*NH, HW, HD) layout (col-block == head).
// head_layout=0: plain row-major (4096,768).
// ---------------------------------------------------------------------------
__global__ __launch_bounds__(256) void gemm64_kernel(
    const float* __restrict__ X, const float* __restrict__ W,
    const float* __restrict__ bias, float* __restrict__ Y, int head_layout)
{
    __shared__ float As[16][68];   // transposed: As[k][row], padded
    __shared__ float Bs[16][68];   // Bs[k][col], padded

    const int cb = blockIdx.x;     // col block (0..11) == head when head_layout
    const int rb = blockIdx.y;     // row block (0..63)
    const int t  = threadIdx.x;
    const int tx = t & 15, ty = t >> 4;
    const int row0 = rb * 64, col0 = cb * 64;

    const int ar = t >> 2, ak = (t & 3) * 4;   // A-load mapping
    const int bk = t >> 4, bc = (t & 15) * 4;  // B-load mapping

    float acc[4][4] = {};

    for (int k0 = 0; k0 < DIM; k0 += 16) {
        float4 av = *(const float4*)(X + (size_t)(row0 + ar) * DIM + k0 + ak);
        float4 bv = *(const float4*)(W + (size_t)(k0 + bk) * DIM + col0 + bc);
        As[ak + 0][ar] = av.x; As[ak + 1][ar] = av.y;
        As[ak + 2][ar] = av.z; As[ak + 3][ar] = av.w;
        *(float4*)&Bs[bk][bc] = bv;
        __syncthreads();
        #pragma unroll
        for (int k = 0; k < 16; ++k) {
            float4 a4 = *(const float4*)&As[k][ty * 4];
            float4 b4 = *(const float4*)&Bs[k][tx * 4];
            float aa[4] = {a4.x, a4.y, a4.z, a4.w};
            float bb[4] = {b4.x, b4.y, b4.z, b4.w};
            #pragma unroll
            for (int i = 0; i < 4; ++i)
                #pragma unroll
                for (int j = 0; j < 4; ++j)
                    acc[i][j] += aa[i] * bb[j];
        }
        __syncthreads();
    }

    float4 bv4 = *(const float4*)(bias + col0 + tx * 4);
    float bb[4] = {bv4.x, bv4.y, bv4.z, bv4.w};

    if (head_layout) {
        #pragma unroll
        for (int i = 0; i < 4; ++i) {
            int r = row0 + ty * 4 + i;
            int b_ = r >> 10, hw = r & 1023;
            float* op = Y + ((size_t)(b_ * NH + cb) * HWN + hw) * HD + tx * 4;
            *(float4*)op = make_float4(acc[i][0] + bb[0], acc[i][1] + bb[1],
                                       acc[i][2] + bb[2], acc[i][3] + bb[3]);
        }
    } else {
        #pragma unroll
        for (int i = 0; i < 4; ++i) {
            int r = row0 + ty * 4 + i;
            float* op = Y + (size_t)r * DIM + col0 + tx * 4;
            *(float4*)op = make_float4(acc[i][0] + bb[0], acc[i][1] + bb[1],
                                       acc[i][2] + bb[2], acc[i][3] + bb[3]);
        }
    }
}

// ---------------------------------------------------------------------------
// Fused attention with decomposed rel-pos bias + online softmax.
// One block = one (head bh, query-row h): 32 queries (h, w=0..31).
// 256 threads: thread t -> qi = t>>3 (query w), j8 = t&7.
//   scores: keys j8 + 8*i (i=0..7)  |  output dims d = j8*8 .. +8
// ---------------------------------------------------------------------------
__global__ __launch_bounds__(256) void attn_kernel(
    const float* __restrict__ qh, const float* __restrict__ kh,
    const float* __restrict__ vh, const float* __restrict__ rel_pos_h,
    const float* __restrict__ rel_pos_w, float* __restrict__ xout)
{
    const int bh = blockIdx.y;   // 0..47
    const int h  = blockIdx.x;   // 0..31
    const int t  = threadIdx.x;
    const int qi = t >> 3;       // 0..31 (== w of query)
    const int j8 = t & 7;        // 0..7

    __shared__ float Qs[32][68];
    __shared__ float Ks[64][68];
    __shared__ float Vs[64][68];
    __shared__ float Ps[32][68];
    __shared__ float RelH[32][32];
    __shared__ float RelW[32][32];

    const float* qbase = qh + ((size_t)bh * HWN + h * 32) * HD;

    // load Q tile (unscaled)
    {
        int r = t >> 3, c = (t & 7) * 8;
        float4 v0 = *(const float4*)(qbase + r * HD + c);
        float4 v1 = *(const float4*)(qbase + r * HD + c + 4);
        *(float4*)&Qs[r][c]     = v0;
        *(float4*)&Qs[r][c + 4] = v1;
    }
    __syncthreads();

    // rel-pos bias tables: RelH[w][kh'], RelW[w][kw']  (uses UNscaled q)
    {
        int j0 = j8 * 4;
        #pragma unroll
        for (int jj = 0; jj < 4; ++jj) {
            int j = j0 + jj;
            const float* rh = rel_pos_h + (size_t)(h - j + 31) * HD;
            const float* rw = rel_pos_w + (size_t)(qi - j + 31) * HD;
            float sh = 0.f, sw = 0.f;
            #pragma unroll
            for (int c = 0; c < HD; c += 4) {
                float4 qv  = *(const float4*)&Qs[qi][c];
                float4 rhv = *(const float4*)(rh + c);
                float4 rwv = *(const float4*)(rw + c);
                sh += qv.x * rhv.x + qv.y * rhv.y + qv.z * rhv.z + qv.w * rhv.w;
                sw += qv.x * rwv.x + qv.y * rwv.y + qv.z * rwv.z + qv.w * rwv.w;
            }
            RelH[qi][j] = sh;
            RelW[qi][j] = sw;
        }
    }

    float m = -INFINITY, l = 0.f;
    float acc[8] = {};
    const int d0 = j8 * 8;
    const float* kbase = kh + (size_t)bh * HWN * HD;
    const float* vbase = vh + (size_t)bh * HWN * HD;

    for (int kt = 0; kt < 16; ++kt) {
        // stage K/V tile (64 keys x 64 dims)
        {
            int key = t >> 2, c = (t & 3) * 16;
            const float* kp = kbase + (size_t)(kt * 64 + key) * HD + c;
            const float* vp = vbase + (size_t)(kt * 64 + key) * HD + c;
            #pragma unroll
            for (int u = 0; u < 16; u += 4) {
                *(float4*)&Ks[key][c + u] = *(const float4*)(kp + u);
                *(float4*)&Vs[key][c + u] = *(const float4*)(vp + u);
            }
        }
        __syncthreads();

        // scores for keys j8 + 8*i
        float s[8] = {};
        for (int c = 0; c < HD; c += 4) {
            float4 qv = *(const float4*)&Qs[qi][c];
            #pragma unroll
            for (int i = 0; i < 8; ++i) {
                float4 kv = *(const float4*)&Ks[j8 + 8 * i][c];
                s[i] += qv.x * kv.x + qv.y * kv.y + qv.z * kv.z + qv.w * kv.w;
            }
        }
        float tmax = -INFINITY;
        #pragma unroll
        for (int i = 0; i < 8; ++i) {
            int klocal = j8 + 8 * i;
            int kidx = kt * 64 + klocal;
            s[i] = 0.125f * s[i] + RelH[qi][kidx >> 5] + RelW[qi][kidx & 31];
            tmax = fmaxf(tmax, s[i]);
        }
        tmax = fmaxf(tmax, __shfl_xor(tmax, 1));
        tmax = fmaxf(tmax, __shfl_xor(tmax, 2));
        tmax = fmaxf(tmax, __shfl_xor(tmax, 4));
        float mnew = fmaxf(m, tmax);
        float factor = __expf(m - mnew);
        float tsum = 0.f;
        #pragma unroll
        for (int i = 0; i < 8; ++i) {
            float p = __expf(s[i] - mnew);
            Ps[qi][j8 + 8 * i] = p;
            tsum += p;
        }
        tsum += __shfl_xor(tsum, 1);
        tsum += __shfl_xor(tsum, 2);
        tsum += __shfl_xor(tsum, 4);
        l = l * factor + tsum;
        m = mnew;
        #pragma unroll
        for (int d = 0; d < 8; ++d) acc[d] *= factor;
        __syncthreads();   // Ps visible; score-phase reads of Ks done

        // PV: acc[d0..d0+8) += P[qi][k] * V[k][d0..]
        for (int k = 0; k < 64; ++k) {
            float p = Ps[qi][k];
            float4 v0 = *(const float4*)&Vs[k][d0];
            float4 v1 = *(const float4*)&Vs[k][d0 + 4];
            acc[0] += p * v0.x; acc[1] += p * v0.y;
            acc[2] += p * v0.z; acc[3] += p * v0.w;
            acc[4] += p * v1.x; acc[5] += p * v1.y;
            acc[6] += p * v1.z; acc[7] += p * v1.w;
        }
        __syncthreads();   // PV reads done before next tile overwrite
    }

    float inv = 1.0f / l;
    int b_ = bh / NH, nh = bh % NH;
    float* op = xout + ((size_t)(b_ * HWN) + h * 32 + qi) * DIM + nh * HD + d0;
    *(float4*)op       = make_float4(acc[0] * inv, acc[1] * inv, acc[2] * inv, acc[3] * inv);
    *(float4*)(op + 4) = make_float4(acc[4] * inv, acc[5] * inv, acc[6] * inv, acc[7] * inv);
}

// ---------------------------------------------------------------------------
extern "C" void kernel_launch(void* const* d_in, const int* in_sizes, int n_in,
                              void* d_out, int out_size, void* d_ws, size_t ws_size,
                              hipStream_t stream) {
    const float* q   = (const float*)d_in[0];
    const float* k   = (const float*)d_in[1];
    const float* v   = (const float*)d_in[2];
    const float* Wq  = (const float*)d_in[3];
    const float* bq  = (const float*)d_in[4];
    const float* Wk  = (const float*)d_in[5];
    const float* bk  = (const float*)d_in[6];
    const float* Wv  = (const float*)d_in[7];
    const float* bv  = (const float*)d_in[8];
    const float* Wp  = (const float*)d_in[9];
    const float* bp  = (const float*)d_in[10];
    const float* rph = (const float*)d_in[11];
    const float* rpw = (const float*)d_in[12];

    float* out = (float*)d_out;
    float* ws  = (float*)d_ws;

    const size_t SZ = (size_t)MROWS * DIM;   // 3,145,728 floats
    float* qh = ws;
    float* khb = ws + SZ;
    float* vhb = ws + 2 * SZ;
    float* xa  = ws + 3 * SZ;

    dim3 gg(12, 64), blk(256);
    gemm64_kernel<<<gg, blk, 0, stream>>>(q, Wq, bq, qh, 1);
    gemm64_kernel<<<gg, blk, 0, stream>>>(k, Wk, bk, khb, 1);
    gemm64_kernel<<<gg, blk, 0, stream>>>(v, Wv, bv, vhb, 1);
    attn_kernel<<<dim3(32, 48), blk, 0, stream>>>(qh, khb, vhb, rph, rpw, xa);
    gemm64_kernel<<<gg, blk, 0, stream>>>(xa, Wp, bp, out, 0);
}

// Round 2
// 442.782 us; speedup vs baseline: 1.8150x; 1.8150x over previous
//
#include <hip/hip_runtime.h>
#include <hip/hip_bf16.h>
#include <math.h>

#define BB   4
#define DIM  768
#define NH   12
#define HD   64
#define HWN  1024
#define MROWS 4096

typedef __attribute__((ext_vector_type(8))) short short8;
typedef __attribute__((ext_vector_type(4))) short short4v;
typedef __attribute__((ext_vector_type(4))) float f32x4;

__device__ __forceinline__ short f2bf(float x) {
    __hip_bfloat16 h = __float2bfloat16(x);
    return *reinterpret_cast<short*>(&h);
}
__device__ __forceinline__ float bf2f(short s) {
    __hip_bfloat16 h;
    *reinterpret_cast<short*>(&h) = s;
    return __bfloat162float(h);
}

// ---------------------------------------------------------------------------
// fp32 tiled GEMM: Y = X @ W + bias.  Modes:
//  0: fp32 head layout (Q)          -> Yf
//  1: bf16 hi/lo head layout (K)    -> Yh, Yl
//  2: bf16 head layout (V)          -> Yh
//  3: fp32 flat (out-projection)    -> Yf
// ---------------------------------------------------------------------------
__global__ __launch_bounds__(256) void gemm64_kernel(
    const float* __restrict__ X, const float* __restrict__ W,
    const float* __restrict__ bias, float* __restrict__ Yf,
    short* __restrict__ Yh, short* __restrict__ Yl, int mode)
{
    __shared__ float As[16][68];
    __shared__ float Bs[16][68];

    const int cb = blockIdx.x;
    const int rb = blockIdx.y;
    const int t  = threadIdx.x;
    const int tx = t & 15, ty = t >> 4;
    const int row0 = rb * 64, col0 = cb * 64;

    const int ar = t >> 2, ak = (t & 3) * 4;
    const int bk = t >> 4, bc = (t & 15) * 4;

    float acc[4][4] = {};

    for (int k0 = 0; k0 < DIM; k0 += 16) {
        float4 av = *(const float4*)(X + (size_t)(row0 + ar) * DIM + k0 + ak);
        float4 bv = *(const float4*)(W + (size_t)(k0 + bk) * DIM + col0 + bc);
        As[ak + 0][ar] = av.x; As[ak + 1][ar] = av.y;
        As[ak + 2][ar] = av.z; As[ak + 3][ar] = av.w;
        *(float4*)&Bs[bk][bc] = bv;
        __syncthreads();
        #pragma unroll
        for (int k = 0; k < 16; ++k) {
            float4 a4 = *(const float4*)&As[k][ty * 4];
            float4 b4 = *(const float4*)&Bs[k][tx * 4];
            float aa[4] = {a4.x, a4.y, a4.z, a4.w};
            float bb[4] = {b4.x, b4.y, b4.z, b4.w};
            #pragma unroll
            for (int i = 0; i < 4; ++i)
                #pragma unroll
                for (int j = 0; j < 4; ++j)
                    acc[i][j] += aa[i] * bb[j];
        }
        __syncthreads();
    }

    float4 bv4 = *(const float4*)(bias + col0 + tx * 4);
    float bb[4] = {bv4.x, bv4.y, bv4.z, bv4.w};

    #pragma unroll
    for (int i = 0; i < 4; ++i) {
        int r = row0 + ty * 4 + i;
        float y[4];
        #pragma unroll
        for (int j = 0; j < 4; ++j) y[j] = acc[i][j] + bb[j];

        if (mode == 3) {
            float* op = Yf + (size_t)r * DIM + col0 + tx * 4;
            *(float4*)op = make_float4(y[0], y[1], y[2], y[3]);
        } else {
            int b_ = r >> 10, hw = r & 1023;
            size_t base = ((size_t)(b_ * NH + cb) * HWN + hw) * HD + tx * 4;
            if (mode == 0) {
                *(float4*)(Yf + base) = make_float4(y[0], y[1], y[2], y[3]);
            } else if (mode == 2) {
                short4v hv;
                #pragma unroll
                for (int j = 0; j < 4; ++j) hv[j] = f2bf(y[j]);
                *(short4v*)(Yh + base) = hv;
            } else {
                short4v hv, lv;
                #pragma unroll
                for (int j = 0; j < 4; ++j) {
                    short h_ = f2bf(y[j]);
                    hv[j] = h_;
                    lv[j] = f2bf(y[j] - bf2f(h_));
                }
                *(short4v*)(Yh + base) = hv;
                *(short4v*)(Yl + base) = lv;
            }
        }
    }
}

// ---------------------------------------------------------------------------
// MFMA fused attention. Block = (head bh, 64-query tile qb). 4 waves; wave w
// owns q rows [w*16, w*16+16). Split-bf16 QK^T (hi/lo), bf16 PV.
// LDS XOR-swizzle ((row&7)<<4) on K/Vt/P to kill 128B-row-stride conflicts.
// ---------------------------------------------------------------------------
#define LDS_RELH 0        // 64*33*4 = 8448
#define LDS_RELW 8448     // 8448  -> 16896
#define LDS_KHI  16896    // 8192  -> 25088
#define LDS_KLO  25088    // 8192  -> 33280
#define LDS_VT   33280    // 8192  -> 41472
#define LDS_P    41472    // 8192  -> 49664
#define LDS_QF   16896    // prologue only (64*68*4 = 17408, overlaps KHI/KLO)
#define LDS_OF   16896    // epilogue only
#define LDS_TOTAL 49664

__global__ __launch_bounds__(256) void attn_kernel(
    const float* __restrict__ qh, const short* __restrict__ khi,
    const short* __restrict__ klo, const short* __restrict__ vbf,
    const float* __restrict__ rel_pos_h, const float* __restrict__ rel_pos_w,
    float* __restrict__ xout)
{
    __shared__ __align__(16) char smem[LDS_TOTAL];
    const int bh = blockIdx.y;     // 0..47
    const int qb = blockIdx.x;     // 0..15
    const int t  = threadIdx.x;
    const int w  = t >> 6;
    const int lane = t & 63;
    const int l15 = lane & 15, l4 = lane >> 4;

    float* RelH = (float*)(smem + LDS_RELH);
    float* RelW = (float*)(smem + LDS_RELW);
    float* Qf   = (float*)(smem + LDS_QF);

    // ---- stage Q tile (fp32) ----
    {
        int r = t >> 2, dc = (t & 3) * 16;
        const float* qp = qh + ((size_t)bh * HWN + qb * 64 + r) * HD + dc;
        #pragma unroll
        for (int u = 0; u < 16; u += 4)
            *(float4*)&Qf[r * 68 + dc + u] = *(const float4*)(qp + u);
    }
    __syncthreads();

    // ---- rel-pos bias tables (fp32, unscaled q) ----
    {
        int ql = t >> 2, j0 = (t & 3) * 8;
        int hq = qb * 2 + (ql >> 5);
        int wq = ql & 31;
        const float* qrow = &Qf[ql * 68];
        #pragma unroll
        for (int jj = 0; jj < 8; ++jj) {
            int kk = j0 + jj;
            const float* rh = rel_pos_h + (size_t)(hq - kk + 31) * HD;
            const float* rw = rel_pos_w + (size_t)(wq - kk + 31) * HD;
            float sh = 0.f, sw = 0.f;
            for (int c = 0; c < HD; c += 4) {
                float4 qv = *(const float4*)(qrow + c);
                float4 a  = *(const float4*)(rh + c);
                float4 b  = *(const float4*)(rw + c);
                sh += qv.x * a.x + qv.y * a.y + qv.z * a.z + qv.w * a.w;
                sw += qv.x * b.x + qv.y * b.y + qv.z * b.z + qv.w * b.w;
            }
            RelH[ql * 33 + kk] = sh;
            RelW[ql * 33 + kk] = sw;
        }
    }

    // ---- Q fragments (hi/lo split), A-operand layout ----
    short8 qfh[2], qfl[2];
    {
        int qr = w * 16 + l15;
        #pragma unroll
        for (int ks = 0; ks < 2; ++ks) {
            const float* qp = &Qf[qr * 68 + ks * 32 + l4 * 8];
            #pragma unroll
            for (int j = 0; j < 8; ++j) {
                float x  = qp[j];
                short h_ = f2bf(x);
                qfh[ks][j] = h_;
                qfl[ks][j] = f2bf(x - bf2f(h_));
            }
        }
    }

    f32x4 acc_o[4] = {{0,0,0,0},{0,0,0,0},{0,0,0,0},{0,0,0,0}};
    float m_[4], l_[4];
    #pragma unroll
    for (int r = 0; r < 4; ++r) { m_[r] = -INFINITY; l_[r] = 0.f; }

    const size_t headoff = (size_t)bh * HWN * HD;
    const short* kh_b = khi + headoff;
    const short* kl_b = klo + headoff;
    const short* v_b  = vbf + headoff;
    char* Pw = smem + LDS_P + w * 2048;

    for (int kt = 0; kt < 16; ++kt) {
        __syncthreads();   // previous tile's reads (or prologue) complete
        // ---- stage K hi/lo + V^T (bf16) ----
        {
            int key = t >> 2, dc = (t & 3) * 16;
            const short* kp = kh_b + (size_t)(kt * 64 + key) * HD + dc;
            const short* lp = kl_b + (size_t)(kt * 64 + key) * HD + dc;
            const short* vp = v_b  + (size_t)(kt * 64 + key) * HD + dc;
            short8 k0 = *(const short8*)(kp);
            short8 k1 = *(const short8*)(kp + 8);
            short8 l0 = *(const short8*)(lp);
            short8 l1 = *(const short8*)(lp + 8);
            int swz = (key & 7) << 4;
            int c0 = (dc * 2) ^ swz, c1 = (dc * 2 + 16) ^ swz;
            *(short8*)(smem + LDS_KHI + key * 128 + c0) = k0;
            *(short8*)(smem + LDS_KHI + key * 128 + c1) = k1;
            *(short8*)(smem + LDS_KLO + key * 128 + c0) = l0;
            *(short8*)(smem + LDS_KLO + key * 128 + c1) = l1;
            short vv[16];
            *(short8*)&vv[0] = *(const short8*)(vp);
            *(short8*)&vv[8] = *(const short8*)(vp + 8);
            #pragma unroll
            for (int j = 0; j < 16; ++j) {
                int d = dc + j;
                *(short*)(smem + LDS_VT + d * 128 + ((key * 2) ^ ((d & 7) << 4))) = vv[j];
            }
        }
        __syncthreads();

        // ---- QK^T (split bf16: hi*hi + lo*hi + hi*lo) ----
        f32x4 accs[4] = {{0,0,0,0},{0,0,0,0},{0,0,0,0},{0,0,0,0}};
        #pragma unroll
        for (int ct = 0; ct < 4; ++ct) {
            int key = ct * 16 + l15;
            int swz = (key & 7) << 4;
            #pragma unroll
            for (int ks = 0; ks < 2; ++ks) {
                int cb = (ks * 64 + l4 * 16) ^ swz;
                short8 bh_ = *(short8*)(smem + LDS_KHI + key * 128 + cb);
                short8 bl_ = *(short8*)(smem + LDS_KLO + key * 128 + cb);
                accs[ct] = __builtin_amdgcn_mfma_f32_16x16x32_bf16(qfh[ks], bh_, accs[ct], 0, 0, 0);
                accs[ct] = __builtin_amdgcn_mfma_f32_16x16x32_bf16(qfl[ks], bh_, accs[ct], 0, 0, 0);
                accs[ct] = __builtin_amdgcn_mfma_f32_16x16x32_bf16(qfh[ks], bl_, accs[ct], 0, 0, 0);
            }
        }

        // ---- online softmax (D layout: row q = l4*4+reg, col key = ct*16+l15)
        float s[4][4];
        float tmax[4] = {-INFINITY, -INFINITY, -INFINITY, -INFINITY};
        #pragma unroll
        for (int reg = 0; reg < 4; ++reg) {
            int qloc = w * 16 + l4 * 4 + reg;
            #pragma unroll
            for (int ct = 0; ct < 4; ++ct) {
                float bias = RelH[qloc * 33 + (kt * 2 + (ct >> 1))]
                           + RelW[qloc * 33 + ((ct & 1) * 16 + l15)];
                float v = accs[ct][reg] * 0.125f + bias;
                s[ct][reg] = v;
                tmax[reg] = fmaxf(tmax[reg], v);
            }
        }
        #pragma unroll
        for (int reg = 0; reg < 4; ++reg) {
            float tv = tmax[reg];
            tv = fmaxf(tv, __shfl_xor(tv, 1));
            tv = fmaxf(tv, __shfl_xor(tv, 2));
            tv = fmaxf(tv, __shfl_xor(tv, 4));
            tv = fmaxf(tv, __shfl_xor(tv, 8));
            tmax[reg] = tv;
        }
        float factor[4], tsum[4];
        #pragma unroll
        for (int reg = 0; reg < 4; ++reg) {
            float mn = fmaxf(m_[reg], tmax[reg]);
            factor[reg] = __expf(m_[reg] - mn);
            m_[reg] = mn;
            tsum[reg] = 0.f;
        }
        #pragma unroll
        for (int ct = 0; ct < 4; ++ct) {
            #pragma unroll
            for (int reg = 0; reg < 4; ++reg) {
                float p = __expf(s[ct][reg] - m_[reg]);
                tsum[reg] += p;
                int q = l4 * 4 + reg;
                int col = ct * 16 + l15;
                *(short*)(Pw + q * 128 + ((col * 2) ^ ((q & 7) << 4))) = f2bf(p);
            }
        }
        #pragma unroll
        for (int reg = 0; reg < 4; ++reg) {
            float ts = tsum[reg];
            ts += __shfl_xor(ts, 1);
            ts += __shfl_xor(ts, 2);
            ts += __shfl_xor(ts, 4);
            ts += __shfl_xor(ts, 8);
            l_[reg] = l_[reg] * factor[reg] + ts;
        }
        #pragma unroll
        for (int dt = 0; dt < 4; ++dt)
            #pragma unroll
            for (int reg = 0; reg < 4; ++reg)
                acc_o[dt][reg] *= factor[reg];

        // ---- PV: O[q][d] += P[q][k] * V[k][d]  (A = P from LDS, B = Vt rows)
        #pragma unroll
        for (int ks = 0; ks < 2; ++ks) {
            int cbp = (ks * 64 + l4 * 16) ^ ((l15 & 7) << 4);
            short8 pa = *(short8*)(Pw + l15 * 128 + cbp);
            #pragma unroll
            for (int dt = 0; dt < 4; ++dt) {
                int d = dt * 16 + l15;
                int cbv = (ks * 64 + l4 * 16) ^ ((d & 7) << 4);
                short8 vf = *(short8*)(smem + LDS_VT + d * 128 + cbv);
                acc_o[dt] = __builtin_amdgcn_mfma_f32_16x16x32_bf16(pa, vf, acc_o[dt], 0, 0, 0);
            }
        }
    }

    // ---- epilogue: normalize, stage through LDS, coalesced store ----
    __syncthreads();
    float* Of = (float*)(smem + LDS_OF);
    #pragma unroll
    for (int reg = 0; reg < 4; ++reg) {
        float inv = 1.0f / l_[reg];
        int qloc = w * 16 + l4 * 4 + reg;
        #pragma unroll
        for (int dt = 0; dt < 4; ++dt)
            Of[qloc * 68 + dt * 16 + l15] = acc_o[dt][reg] * inv;
    }
    __syncthreads();
    {
        int r = t >> 2, dc = (t & 3) * 16;
        int b_ = bh / NH, nh = bh % NH;
        float* op = xout + ((size_t)b_ * HWN + qb * 64 + r) * DIM + nh * HD + dc;
        #pragma unroll
        for (int u = 0; u < 16; u += 4)
            *(float4*)(op + u) = *(const float4*)&Of[r * 68 + dc + u];
    }
}

// ---------------------------------------------------------------------------
extern "C" void kernel_launch(void* const* d_in, const int* in_sizes, int n_in,
                              void* d_out, int out_size, void* d_ws, size_t ws_size,
                              hipStream_t stream) {
    const float* q   = (const float*)d_in[0];
    const float* k   = (const float*)d_in[1];
    const float* v   = (const float*)d_in[2];
    const float* Wq  = (const float*)d_in[3];
    const float* bq  = (const float*)d_in[4];
    const float* Wk  = (const float*)d_in[5];
    const float* bk  = (const float*)d_in[6];
    const float* Wv  = (const float*)d_in[7];
    const float* bv  = (const float*)d_in[8];
    const float* Wp  = (const float*)d_in[9];
    const float* bp  = (const float*)d_in[10];
    const float* rph = (const float*)d_in[11];
    const float* rpw = (const float*)d_in[12];

    float* out = (float*)d_out;
    char*  w0  = (char*)d_ws;

    float* qhp  = (float*)(w0);                    // 12 MB fp32 head layout
    short* khip = (short*)(w0 + 12582912);         // 6 MB bf16 hi
    short* klop = (short*)(w0 + 18874368);         // 6 MB bf16 lo
    short* vbp  = (short*)(w0 + 25165824);         // 6 MB bf16
    float* xa   = (float*)(w0 + 31457280);         // 12 MB fp32 (B,HW,DIM)

    dim3 gg(12, 64), blk(256);
    gemm64_kernel<<<gg, blk, 0, stream>>>(q, Wq, bq, qhp, nullptr, nullptr, 0);
    gemm64_kernel<<<gg, blk, 0, stream>>>(k, Wk, bk, nullptr, khip, klop, 1);
    gemm64_kernel<<<gg, blk, 0, stream>>>(v, Wv, bv, nullptr, vbp, nullptr, 2);
    attn_kernel<<<dim3(16, 48), blk, 0, stream>>>(qhp, khip, klop, vbp, rph, rpw, xa);
    gemm64_kernel<<<gg, blk, 0, stream>>>(xa, Wp, bp, out, nullptr, nullptr, 3);
}

// Round 3
// 358.571 us; speedup vs baseline: 2.2412x; 1.2349x over previous
//
#include <hip/hip_runtime.h>
#include <hip/hip_bf16.h>
#include <math.h>

#define BB   4
#define DIM  768
#define NH   12
#define HD   64
#define HWN  1024
#define MROWS 4096

typedef __attribute__((ext_vector_type(8))) short short8;
typedef __attribute__((ext_vector_type(4))) short short4v;
typedef __attribute__((ext_vector_type(4))) float f32x4;

__device__ __forceinline__ short f2bf(float x) {
    __hip_bfloat16 h = __float2bfloat16(x);
    return *reinterpret_cast<short*>(&h);
}
__device__ __forceinline__ float bf2f(short s) {
    __hip_bfloat16 h;
    *reinterpret_cast<short*>(&h) = s;
    return __bfloat162float(h);
}

__device__ __forceinline__ void gl_lds16(const void* g, void* l) {
    __builtin_amdgcn_global_load_lds(
        (const __attribute__((address_space(1))) void*)g,
        (__attribute__((address_space(3))) void*)l, 16, 0, 0);
}

// ---------------------------------------------------------------------------
// split fp32 -> bf16 hi + bf16 lo (elementwise)
// ---------------------------------------------------------------------------
__global__ __launch_bounds__(256) void split_kernel(
    const float* __restrict__ in, short* __restrict__ hi,
    short* __restrict__ lo, int n4)
{
    int i = blockIdx.x * 256 + threadIdx.x;
    const int stride = gridDim.x * 256;
    for (; i < n4; i += stride) {
        float4 v = ((const float4*)in)[i];
        float vv[4] = {v.x, v.y, v.z, v.w};
        short4v h, l;
        #pragma unroll
        for (int j = 0; j < 4; ++j) {
            short h_ = f2bf(vv[j]);
            h[j] = h_;
            l[j] = f2bf(vv[j] - bf2f(h_));
        }
        ((short4v*)hi)[i] = h;
        ((short4v*)lo)[i] = l;
    }
}

// ---------------------------------------------------------------------------
// W (768x768, k-major) -> Wt hi/lo (768x768, n-major = transposed), bf16
// ---------------------------------------------------------------------------
__global__ __launch_bounds__(256) void wsplit_kernel(
    const float* __restrict__ W, short* __restrict__ Whi, short* __restrict__ Wlo)
{
    __shared__ float Ws[64][65];
    const int k0 = blockIdx.y * 64, n0 = blockIdx.x * 64;
    const int t = threadIdx.x;
    {
        int r = t >> 2, c4 = (t & 3) * 16;
        #pragma unroll
        for (int u = 0; u < 16; u += 4)
            *(float4*)&Ws[r][c4 + u] = *(const float4*)(W + (size_t)(k0 + r) * DIM + n0 + c4 + u);
    }
    __syncthreads();
    const int n = t >> 2, kseg = (t & 3) * 16;
    short8 h0, h1, l0, l1;
    #pragma unroll
    for (int j = 0; j < 8; ++j) {
        float x = Ws[kseg + j][n];
        short hx = f2bf(x);
        h0[j] = hx; l0[j] = f2bf(x - bf2f(hx));
        float y = Ws[kseg + 8 + j][n];
        short hy = f2bf(y);
        h1[j] = hy; l1[j] = f2bf(y - bf2f(hy));
    }
    size_t base = (size_t)(n0 + n) * DIM + k0 + kseg;
    *(short8*)(Whi + base) = h0; *(short8*)(Whi + base + 8) = h1;
    *(short8*)(Wlo + base) = l0; *(short8*)(Wlo + base + 8) = l1;
}

// ---------------------------------------------------------------------------
// Split-bf16 MFMA GEMM: C = (Ahi+Alo)(Bhi+Blo) ~= AhiBhi + AloBhi + AhiBlo.
// A: 4096x768 bf16 row-major (hi/lo). Bt: 768x768 bf16 n-major (hi/lo).
// Tile 128x64, BK=64, 4 waves, wave tile 64x32 (4x2 frags of 16x16x32).
// Fragment-major LDS (1KB/frag) via global_load_lds -> conflict-free ds_read.
// Modes: 0 fp32 head layout | 1 bf16 hi/lo head | 2 bf16 head | 3 fp32 flat
// ---------------------------------------------------------------------------
__global__ __launch_bounds__(256, 3) void gemm_mfma_kernel(
    const short* __restrict__ Ahi, const short* __restrict__ Alo,
    const short* __restrict__ Bthi, const short* __restrict__ Btlo,
    const float* __restrict__ bias, float* __restrict__ Yf,
    short* __restrict__ Yh, short* __restrict__ Yl, int mode)
{
    __shared__ __align__(16) char smem[49152];
    const int t = threadIdx.x;
    const int w = t >> 6, lane = t & 63;
    const int l15 = lane & 15, l4 = lane >> 4;

    // XCD-chunked swizzle: 384 blocks = 8 xcd * 48; each XCD gets 4 row-blocks
    const int sw = (blockIdx.x & 7) * 48 + (blockIdx.x >> 3);
    const int rb = sw / 12, cb = sw - rb * 12;
    const int row0 = rb * 128, col0 = cb * 64;

    f32x4 acc[4][2];
    #pragma unroll
    for (int i = 0; i < 4; ++i)
        #pragma unroll
        for (int j = 0; j < 2; ++j) acc[i][j] = (f32x4){0, 0, 0, 0};

    for (int kt = 0; kt < 12; ++kt) {
        const int kbyte = kt * 128;
        #pragma unroll
        for (int it = 0; it < 4; ++it) {
            const int f = it * 4 + w;              // 0..15
            const int ks = f >> 3, rf = f & 7;
            const size_t off = (size_t)(row0 + rf * 16 + l15) * 1536 + kbyte + ks * 64 + l4 * 16;
            gl_lds16((const char*)Ahi + off, smem + f * 1024);
            gl_lds16((const char*)Alo + off, smem + 16384 + f * 1024);
        }
        #pragma unroll
        for (int it = 0; it < 2; ++it) {
            const int f = it * 4 + w;              // 0..7
            const int ks = f >> 2, cf = f & 3;
            const size_t off = (size_t)(col0 + cf * 16 + l15) * 1536 + kbyte + ks * 64 + l4 * 16;
            gl_lds16((const char*)Bthi + off, smem + 32768 + f * 1024);
            gl_lds16((const char*)Btlo + off, smem + 40960 + f * 1024);
        }
        __syncthreads();

        __builtin_amdgcn_s_setprio(1);
        #pragma unroll
        for (int ks = 0; ks < 2; ++ks) {
            const int fb = ks * 4 + (w & 1) * 2;
            short8 bh0 = *(const short8*)(smem + 32768 + (fb    ) * 1024 + lane * 16);
            short8 bh1 = *(const short8*)(smem + 32768 + (fb + 1) * 1024 + lane * 16);
            short8 bl0 = *(const short8*)(smem + 40960 + (fb    ) * 1024 + lane * 16);
            short8 bl1 = *(const short8*)(smem + 40960 + (fb + 1) * 1024 + lane * 16);
            #pragma unroll
            for (int rf = 0; rf < 4; ++rf) {
                const int fa = ks * 8 + (w >> 1) * 4 + rf;
                short8 ah = *(const short8*)(smem + fa * 1024 + lane * 16);
                short8 al = *(const short8*)(smem + 16384 + fa * 1024 + lane * 16);
                acc[rf][0] = __builtin_amdgcn_mfma_f32_16x16x32_bf16(ah, bh0, acc[rf][0], 0, 0, 0);
                acc[rf][1] = __builtin_amdgcn_mfma_f32_16x16x32_bf16(ah, bh1, acc[rf][1], 0, 0, 0);
                acc[rf][0] = __builtin_amdgcn_mfma_f32_16x16x32_bf16(al, bh0, acc[rf][0], 0, 0, 0);
                acc[rf][1] = __builtin_amdgcn_mfma_f32_16x16x32_bf16(al, bh1, acc[rf][1], 0, 0, 0);
                acc[rf][0] = __builtin_amdgcn_mfma_f32_16x16x32_bf16(ah, bl0, acc[rf][0], 0, 0, 0);
                acc[rf][1] = __builtin_amdgcn_mfma_f32_16x16x32_bf16(ah, bl1, acc[rf][1], 0, 0, 0);
            }
        }
        __builtin_amdgcn_s_setprio(0);
        __syncthreads();
    }

    const int wrow0 = row0 + (w >> 1) * 64;
    const int wcol0 = col0 + (w & 1) * 32;
    #pragma unroll
    for (int cf = 0; cf < 2; ++cf) {
        const float bb = bias[wcol0 + cf * 16 + l15];
        const int c = wcol0 + cf * 16 + l15;
        #pragma unroll
        for (int rf = 0; rf < 4; ++rf) {
            #pragma unroll
            for (int reg = 0; reg < 4; ++reg) {
                const int r = wrow0 + rf * 16 + l4 * 4 + reg;
                float y = acc[rf][cf][reg] + bb;
                if (mode == 3) {
                    Yf[(size_t)r * DIM + c] = y;
                } else {
                    size_t base = ((size_t)((r >> 10) * NH + cb) * HWN + (r & 1023)) * HD + (c - col0);
                    if (mode == 0) {
                        Yf[base] = y;
                    } else if (mode == 2) {
                        Yh[base] = f2bf(y);
                    } else {
                        short h_ = f2bf(y);
                        Yh[base] = h_;
                        Yl[base] = f2bf(y - bf2f(h_));
                    }
                }
            }
        }
    }
}

// ---------------------------------------------------------------------------
// MFMA fused attention (unchanged core) + conflict-light V^T staging +
// hi/lo bf16 output epilogue + setprio around MFMA clusters.
// ---------------------------------------------------------------------------
#define LDS_RELH 0
#define LDS_RELW 8448
#define LDS_KHI  16896
#define LDS_KLO  25088
#define LDS_VT   33280
#define LDS_P    41472
#define LDS_QF   16896
#define LDS_OF   16896
#define LDS_TOTAL 49664

__global__ __launch_bounds__(256) void attn_kernel(
    const float* __restrict__ qh, const short* __restrict__ khi,
    const short* __restrict__ klo, const short* __restrict__ vbf,
    const float* __restrict__ rel_pos_h, const float* __restrict__ rel_pos_w,
    short* __restrict__ xahi, short* __restrict__ xalo)
{
    __shared__ __align__(16) char smem[LDS_TOTAL];
    const int bh = blockIdx.y;
    const int qb = blockIdx.x;
    const int t  = threadIdx.x;
    const int w  = t >> 6;
    const int lane = t & 63;
    const int l15 = lane & 15, l4 = lane >> 4;

    float* RelH = (float*)(smem + LDS_RELH);
    float* RelW = (float*)(smem + LDS_RELW);
    float* Qf   = (float*)(smem + LDS_QF);

    {
        int r = t >> 2, dc = (t & 3) * 16;
        const float* qp = qh + ((size_t)bh * HWN + qb * 64 + r) * HD + dc;
        #pragma unroll
        for (int u = 0; u < 16; u += 4)
            *(float4*)&Qf[r * 68 + dc + u] = *(const float4*)(qp + u);
    }
    __syncthreads();

    {
        int ql = t >> 2, j0 = (t & 3) * 8;
        int hq = qb * 2 + (ql >> 5);
        int wq = ql & 31;
        const float* qrow = &Qf[ql * 68];
        #pragma unroll
        for (int jj = 0; jj < 8; ++jj) {
            int kk = j0 + jj;
            const float* rh = rel_pos_h + (size_t)(hq - kk + 31) * HD;
            const float* rw = rel_pos_w + (size_t)(wq - kk + 31) * HD;
            float sh = 0.f, sw = 0.f;
            for (int c = 0; c < HD; c += 4) {
                float4 qv = *(const float4*)(qrow + c);
                float4 a  = *(const float4*)(rh + c);
                float4 b  = *(const float4*)(rw + c);
                sh += qv.x * a.x + qv.y * a.y + qv.z * a.z + qv.w * a.w;
                sw += qv.x * b.x + qv.y * b.y + qv.z * b.z + qv.w * b.w;
            }
            RelH[ql * 33 + kk] = sh;
            RelW[ql * 33 + kk] = sw;
        }
    }

    short8 qfh[2], qfl[2];
    {
        int qr = w * 16 + l15;
        #pragma unroll
        for (int ks = 0; ks < 2; ++ks) {
            const float* qp = &Qf[qr * 68 + ks * 32 + l4 * 8];
            #pragma unroll
            for (int j = 0; j < 8; ++j) {
                float x  = qp[j];
                short h_ = f2bf(x);
                qfh[ks][j] = h_;
                qfl[ks][j] = f2bf(x - bf2f(h_));
            }
        }
    }

    f32x4 acc_o[4] = {{0,0,0,0},{0,0,0,0},{0,0,0,0},{0,0,0,0}};
    float m_[4], l_[4];
    #pragma unroll
    for (int r = 0; r < 4; ++r) { m_[r] = -INFINITY; l_[r] = 0.f; }

    const size_t headoff = (size_t)bh * HWN * HD;
    const short* kh_b = khi + headoff;
    const short* kl_b = klo + headoff;
    const short* v_b  = vbf + headoff;
    char* Pw = smem + LDS_P + w * 2048;

    for (int kt = 0; kt < 16; ++kt) {
        __syncthreads();
        {
            int key = t >> 2, dc = (t & 3) * 16;
            const short* kp = kh_b + (size_t)(kt * 64 + key) * HD + dc;
            const short* lp = kl_b + (size_t)(kt * 64 + key) * HD + dc;
            short8 k0 = *(const short8*)(kp);
            short8 k1 = *(const short8*)(kp + 8);
            short8 l0 = *(const short8*)(lp);
            short8 l1 = *(const short8*)(lp + 8);
            int swz = (key & 7) << 4;
            int c0 = (dc * 2) ^ swz, c1 = (dc * 2 + 16) ^ swz;
            *(short8*)(smem + LDS_KHI + key * 128 + c0) = k0;
            *(short8*)(smem + LDS_KHI + key * 128 + c1) = k1;
            *(short8*)(smem + LDS_KLO + key * 128 + c0) = l0;
            *(short8*)(smem + LDS_KLO + key * 128 + c1) = l1;
        }
        {
            int key2 = (t & 31) * 2, dgrp = t >> 5;
            const short* vp = v_b + (size_t)(kt * 64 + key2) * HD + dgrp * 8;
            short8 va = *(const short8*)vp;
            short8 vb2 = *(const short8*)(vp + HD);
            #pragma unroll
            for (int j = 0; j < 8; ++j) {
                int d = dgrp * 8 + j;
                unsigned pk = ((unsigned short)va[j]) | (((unsigned)(unsigned short)vb2[j]) << 16);
                *(unsigned*)(smem + LDS_VT + d * 128 + ((key2 * 2) ^ ((d & 7) << 4))) = pk;
            }
        }
        __syncthreads();

        f32x4 accs[4] = {{0,0,0,0},{0,0,0,0},{0,0,0,0},{0,0,0,0}};
        __builtin_amdgcn_s_setprio(1);
        #pragma unroll
        for (int ct = 0; ct < 4; ++ct) {
            int key = ct * 16 + l15;
            int swz = (key & 7) << 4;
            #pragma unroll
            for (int ks = 0; ks < 2; ++ks) {
                int cb = (ks * 64 + l4 * 16) ^ swz;
                short8 bh_ = *(short8*)(smem + LDS_KHI + key * 128 + cb);
                short8 bl_ = *(short8*)(smem + LDS_KLO + key * 128 + cb);
                accs[ct] = __builtin_amdgcn_mfma_f32_16x16x32_bf16(qfh[ks], bh_, accs[ct], 0, 0, 0);
                accs[ct] = __builtin_amdgcn_mfma_f32_16x16x32_bf16(qfl[ks], bh_, accs[ct], 0, 0, 0);
                accs[ct] = __builtin_amdgcn_mfma_f32_16x16x32_bf16(qfh[ks], bl_, accs[ct], 0, 0, 0);
            }
        }
        __builtin_amdgcn_s_setprio(0);

        float s[4][4];
        float tmax[4] = {-INFINITY, -INFINITY, -INFINITY, -INFINITY};
        #pragma unroll
        for (int reg = 0; reg < 4; ++reg) {
            int qloc = w * 16 + l4 * 4 + reg;
            #pragma unroll
            for (int ct = 0; ct < 4; ++ct) {
                float bias = RelH[qloc * 33 + (kt * 2 + (ct >> 1))]
                           + RelW[qloc * 33 + ((ct & 1) * 16 + l15)];
                float v = accs[ct][reg] * 0.125f + bias;
                s[ct][reg] = v;
                tmax[reg] = fmaxf(tmax[reg], v);
            }
        }
        #pragma unroll
        for (int reg = 0; reg < 4; ++reg) {
            float tv = tmax[reg];
            tv = fmaxf(tv, __shfl_xor(tv, 1));
            tv = fmaxf(tv, __shfl_xor(tv, 2));
            tv = fmaxf(tv, __shfl_xor(tv, 4));
            tv = fmaxf(tv, __shfl_xor(tv, 8));
            tmax[reg] = tv;
        }
        float factor[4], tsum[4];
        #pragma unroll
        for (int reg = 0; reg < 4; ++reg) {
            float mn = fmaxf(m_[reg], tmax[reg]);
            factor[reg] = __expf(m_[reg] - mn);
            m_[reg] = mn;
            tsum[reg] = 0.f;
        }
        #pragma unroll
        for (int ct = 0; ct < 4; ++ct) {
            #pragma unroll
            for (int reg = 0; reg < 4; ++reg) {
                float p = __expf(s[ct][reg] - m_[reg]);
                tsum[reg] += p;
                int q = l4 * 4 + reg;
                int col = ct * 16 + l15;
                *(short*)(Pw + q * 128 + ((col * 2) ^ ((q & 7) << 4))) = f2bf(p);
            }
        }
        #pragma unroll
        for (int reg = 0; reg < 4; ++reg) {
            float ts = tsum[reg];
            ts += __shfl_xor(ts, 1);
            ts += __shfl_xor(ts, 2);
            ts += __shfl_xor(ts, 4);
            ts += __shfl_xor(ts, 8);
            l_[reg] = l_[reg] * factor[reg] + ts;
        }
        #pragma unroll
        for (int dt = 0; dt < 4; ++dt)
            #pragma unroll
            for (int reg = 0; reg < 4; ++reg)
                acc_o[dt][reg] *= factor[reg];

        __builtin_amdgcn_s_setprio(1);
        #pragma unroll
        for (int ks = 0; ks < 2; ++ks) {
            int cbp = (ks * 64 + l4 * 16) ^ ((l15 & 7) << 4);
            short8 pa = *(short8*)(Pw + l15 * 128 + cbp);
            #pragma unroll
            for (int dt = 0; dt < 4; ++dt) {
                int d = dt * 16 + l15;
                int cbv = (ks * 64 + l4 * 16) ^ ((d & 7) << 4);
                short8 vf = *(short8*)(smem + LDS_VT + d * 128 + cbv);
                acc_o[dt] = __builtin_amdgcn_mfma_f32_16x16x32_bf16(pa, vf, acc_o[dt], 0, 0, 0);
            }
        }
        __builtin_amdgcn_s_setprio(0);
    }

    __syncthreads();
    float* Of = (float*)(smem + LDS_OF);
    #pragma unroll
    for (int reg = 0; reg < 4; ++reg) {
        float inv = 1.0f / l_[reg];
        int qloc = w * 16 + l4 * 4 + reg;
        #pragma unroll
        for (int dt = 0; dt < 4; ++dt)
            Of[qloc * 68 + dt * 16 + l15] = acc_o[dt][reg] * inv;
    }
    __syncthreads();
    {
        int r = t >> 2, dc = (t & 3) * 16;
        int b_ = bh / NH, nh = bh % NH;
        size_t base = ((size_t)b_ * HWN + qb * 64 + r) * DIM + nh * HD + dc;
        short8 hh[2], ll[2];
        #pragma unroll
        for (int g = 0; g < 2; ++g)
            #pragma unroll
            for (int j = 0; j < 8; ++j) {
                float x = Of[r * 68 + dc + g * 8 + j];
                short h_ = f2bf(x);
                hh[g][j] = h_;
                ll[g][j] = f2bf(x - bf2f(h_));
            }
        *(short8*)(xahi + base)     = hh[0];
        *(short8*)(xahi + base + 8) = hh[1];
        *(short8*)(xalo + base)     = ll[0];
        *(short8*)(xalo + base + 8) = ll[1];
    }
}

// ---------------------------------------------------------------------------
extern "C" void kernel_launch(void* const* d_in, const int* in_sizes, int n_in,
                              void* d_out, int out_size, void* d_ws, size_t ws_size,
                              hipStream_t stream) {
    const float* q   = (const float*)d_in[0];
    const float* k   = (const float*)d_in[1];
    const float* v   = (const float*)d_in[2];
    const float* Wq  = (const float*)d_in[3];
    const float* bq  = (const float*)d_in[4];
    const float* Wk  = (const float*)d_in[5];
    const float* bk  = (const float*)d_in[6];
    const float* Wv  = (const float*)d_in[7];
    const float* bv  = (const float*)d_in[8];
    const float* Wp  = (const float*)d_in[9];
    const float* bp  = (const float*)d_in[10];
    const float* rph = (const float*)d_in[11];
    const float* rpw = (const float*)d_in[12];

    float* out = (float*)d_out;
    char*  w0  = (char*)d_ws;

    // workspace layout (bytes)
    short* xhi  = (short*)(w0);                    //  6,291,456
    short* xlo  = (short*)(w0 + 6291456);          //  6,291,456
    short* wthi = (short*)(w0 + 12582912);         //  1,179,648
    short* wtlo = (short*)(w0 + 13762560);         //  1,179,648
    short* khib = (short*)(w0 + 14942208);         //  6,291,456
    short* klob = (short*)(w0 + 21233664);         //  6,291,456
    short* vbp  = (short*)(w0 + 27525120);         //  6,291,456 -> 33,816,576 total
    float* qhp  = out;                             // d_out doubles as Q scratch

    const int NQ4 = MROWS * DIM / 4;
    dim3 blk(256);
    dim3 wg(12, 12);

    split_kernel<<<1024, blk, 0, stream>>>(q, xhi, xlo, NQ4);
    wsplit_kernel<<<wg, blk, 0, stream>>>(Wq, wthi, wtlo);
    gemm_mfma_kernel<<<384, blk, 0, stream>>>(xhi, xlo, wthi, wtlo, bq, qhp, nullptr, nullptr, 0);

    split_kernel<<<1024, blk, 0, stream>>>(k, xhi, xlo, NQ4);
    wsplit_kernel<<<wg, blk, 0, stream>>>(Wk, wthi, wtlo);
    gemm_mfma_kernel<<<384, blk, 0, stream>>>(xhi, xlo, wthi, wtlo, bk, nullptr, khib, klob, 1);

    split_kernel<<<1024, blk, 0, stream>>>(v, xhi, xlo, NQ4);
    wsplit_kernel<<<wg, blk, 0, stream>>>(Wv, wthi, wtlo);
    gemm_mfma_kernel<<<384, blk, 0, stream>>>(xhi, xlo, wthi, wtlo, bv, nullptr, vbp, nullptr, 2);

    attn_kernel<<<dim3(16, 48), blk, 0, stream>>>(qhp, khib, klob, vbp, rph, rpw, xhi, xlo);

    wsplit_kernel<<<wg, blk, 0, stream>>>(Wp, wthi, wtlo);
    gemm_mfma_kernel<<<384, blk, 0, stream>>>(xhi, xlo, wthi, wtlo, bp, out, nullptr, nullptr, 3);
}

// Round 4
// 227.895 us; speedup vs baseline: 3.5264x; 1.5734x over previous
//
#include <hip/hip_runtime.h>
#include <hip/hip_bf16.h>
#include <math.h>

#define DIM  768
#define NH   12
#define HD   64
#define HWN  1024
#define MROWS 4096

typedef __attribute__((ext_vector_type(8))) short short8;
typedef __attribute__((ext_vector_type(4))) float f32x4;
typedef _Float16 h8 __attribute__((ext_vector_type(8)));

__device__ __forceinline__ short f2bf(float x) {
    __hip_bfloat16 h = __float2bfloat16(x);
    return *reinterpret_cast<short*>(&h);
}
__device__ __forceinline__ float bf2f(short s) {
    __hip_bfloat16 h;
    *reinterpret_cast<short*>(&h) = s;
    return __bfloat162float(h);
}

__device__ __forceinline__ void gl_lds16(const void* g, void* l) {
    __builtin_amdgcn_global_load_lds(
        (const __attribute__((address_space(1))) void*)g,
        (__attribute__((address_space(3))) void*)l, 16, 0, 0);
}

// ---------------------------------------------------------------------------
// W (768x768 k-major fp32) -> Wt hi/lo bf16 (n-major). z selects Wq/Wk/Wv/Wp.
// ---------------------------------------------------------------------------
__global__ __launch_bounds__(256) void wsplit_kernel(
    const float* __restrict__ Wq, const float* __restrict__ Wk,
    const float* __restrict__ Wv, const float* __restrict__ Wp,
    short* __restrict__ WhiAll, short* __restrict__ WloAll)
{
    __shared__ float Ws[64][65];
    const int z = blockIdx.z;
    const float* W = (z == 0) ? Wq : (z == 1) ? Wk : (z == 2) ? Wv : Wp;
    short* Whi = WhiAll + (size_t)z * 589824;
    short* Wlo = WloAll + (size_t)z * 589824;

    const int k0 = blockIdx.y * 64, n0 = blockIdx.x * 64;
    const int t = threadIdx.x;
    {
        int r = t >> 2, c4 = (t & 3) * 16;
        #pragma unroll
        for (int u = 0; u < 16; u += 4)
            *(float4*)&Ws[r][c4 + u] = *(const float4*)(W + (size_t)(k0 + r) * DIM + n0 + c4 + u);
    }
    __syncthreads();
    const int n = t >> 2, kseg = (t & 3) * 16;
    short8 h0, h1, l0, l1;
    #pragma unroll
    for (int j = 0; j < 8; ++j) {
        float x = Ws[kseg + j][n];
        short hx = f2bf(x);
        h0[j] = hx; l0[j] = f2bf(x - bf2f(hx));
        float y = Ws[kseg + 8 + j][n];
        short hy = f2bf(y);
        h1[j] = hy; l1[j] = f2bf(y - bf2f(hy));
    }
    size_t base = (size_t)(n0 + n) * DIM + k0 + kseg;
    *(short8*)(Whi + base) = h0; *(short8*)(Whi + base + 8) = h1;
    *(short8*)(Wlo + base) = l0; *(short8*)(Wlo + base + 8) = l1;
}

// ---------------------------------------------------------------------------
// Split-bf16 MFMA GEMM, A staged raw + in-register hi/lo split.
// AMODE 0: A = fp32 (q/k/v fused, 1152 blocks), out = fp16 head layout.
// AMODE 1: A = fp16 (attnout, 384 blocks), out = fp32 flat (d_out).
// Tile 128x64, BK=64, 4 waves, wave tile 64x32.
// ---------------------------------------------------------------------------
template<int AMODE>
__global__ __launch_bounds__(256, 3) void gemm_mfma_kernel(
    const void* __restrict__ X0, const void* __restrict__ X1,
    const void* __restrict__ X2,
    const short* __restrict__ BhiAll, const short* __restrict__ BloAll,
    const float* __restrict__ bias0, const float* __restrict__ bias1,
    const float* __restrict__ bias2,
    void* __restrict__ Y0, void* __restrict__ Y1, void* __restrict__ Y2)
{
    __shared__ __align__(16) char smem[49152];   // A 32KB | B hi 8KB | B lo 8KB
    const int t = threadIdx.x;
    const int w = t >> 6, lane = t & 63;
    const int l15 = lane & 15, l4 = lane >> 4;

    int sel, rem;
    if (AMODE == 0) {
        const int sw = (blockIdx.x & 7) * 144 + (blockIdx.x >> 3);
        sel = sw / 384; rem = sw - sel * 384;
    } else {
        const int sw = (blockIdx.x & 7) * 48 + (blockIdx.x >> 3);
        sel = 3; rem = sw;
    }
    const int rb = rem / 12, cb = rem - rb * 12;
    const int row0 = rb * 128, col0 = cb * 64;

    const char* Ab = (const char*)((AMODE == 1 || sel == 0) ? X0 : (sel == 1) ? X1 : X2);
    const short* Bh = BhiAll + (size_t)sel * 589824;
    const short* Bl = BloAll + (size_t)sel * 589824;
    const float* bias = (AMODE == 1) ? bias0 : (sel == 0) ? bias0 : (sel == 1) ? bias1 : bias2;

    f32x4 acc[4][2];
    #pragma unroll
    for (int i = 0; i < 4; ++i)
        #pragma unroll
        for (int j = 0; j < 2; ++j) acc[i][j] = (f32x4){0, 0, 0, 0};

    for (int kt = 0; kt < 12; ++kt) {
        // ---- stage A (raw) ----
        if (AMODE == 0) {
            #pragma unroll
            for (int i = 0; i < 8; ++i) {
                const int fi = w * 8 + i;
                const int row = fi * 4 + (lane >> 4);
                const int kbs = (lane & 15) * 16;
                const int real = kbs ^ ((row & 7) << 5);
                gl_lds16(Ab + (size_t)(row0 + row) * 3072 + kt * 256 + real, smem + fi * 1024);
            }
        } else {
            #pragma unroll
            for (int i = 0; i < 4; ++i) {
                const int fi = w * 4 + i;
                const int row = fi * 8 + (lane >> 3);
                const int kbs = (lane & 7) * 16;
                const int real = kbs ^ ((row & 7) << 4);
                gl_lds16(Ab + (size_t)(row0 + row) * 1536 + kt * 128 + real, smem + fi * 1024);
            }
        }
        // ---- stage B (pre-split bf16, fragment-major) ----
        #pragma unroll
        for (int it = 0; it < 2; ++it) {
            const int f = it * 4 + w;
            const int ks = f >> 2, cf = f & 3;
            const size_t off = (size_t)(col0 + cf * 16 + l15) * 1536 + kt * 128 + ks * 64 + l4 * 16;
            gl_lds16((const char*)Bh + off, smem + 32768 + f * 1024);
            gl_lds16((const char*)Bl + off, smem + 40960 + f * 1024);
        }
        __syncthreads();

        __builtin_amdgcn_s_setprio(1);
        #pragma unroll
        for (int ks = 0; ks < 2; ++ks) {
            const int fb = ks * 4 + (w & 1) * 2;
            short8 bh0 = *(const short8*)(smem + 32768 + (fb    ) * 1024 + lane * 16);
            short8 bh1 = *(const short8*)(smem + 32768 + (fb + 1) * 1024 + lane * 16);
            short8 bl0 = *(const short8*)(smem + 40960 + (fb    ) * 1024 + lane * 16);
            short8 bl1 = *(const short8*)(smem + 40960 + (fb + 1) * 1024 + lane * 16);
            #pragma unroll
            for (int rf = 0; rf < 4; ++rf) {
                const int arow = (w >> 1) * 64 + rf * 16 + l15;
                float af[8];
                if (AMODE == 0) {
                    const int base = arow * 256 + ((ks * 128 + l4 * 32) ^ ((arow & 7) << 5));
                    f32x4 a0 = *(const f32x4*)(smem + base);
                    f32x4 a1 = *(const f32x4*)(smem + base + 16);
                    af[0] = a0[0]; af[1] = a0[1]; af[2] = a0[2]; af[3] = a0[3];
                    af[4] = a1[0]; af[5] = a1[1]; af[6] = a1[2]; af[7] = a1[3];
                } else {
                    const int base = arow * 128 + ((ks * 64 + l4 * 16) ^ ((arow & 7) << 4));
                    h8 av = *(const h8*)(smem + base);
                    #pragma unroll
                    for (int j = 0; j < 8; ++j) af[j] = (float)av[j];
                }
                short8 ah, al;
                #pragma unroll
                for (int j = 0; j < 8; ++j) {
                    short h_ = f2bf(af[j]);
                    ah[j] = h_;
                    al[j] = f2bf(af[j] - bf2f(h_));
                }
                acc[rf][0] = __builtin_amdgcn_mfma_f32_16x16x32_bf16(ah, bh0, acc[rf][0], 0, 0, 0);
                acc[rf][1] = __builtin_amdgcn_mfma_f32_16x16x32_bf16(ah, bh1, acc[rf][1], 0, 0, 0);
                acc[rf][0] = __builtin_amdgcn_mfma_f32_16x16x32_bf16(al, bh0, acc[rf][0], 0, 0, 0);
                acc[rf][1] = __builtin_amdgcn_mfma_f32_16x16x32_bf16(al, bh1, acc[rf][1], 0, 0, 0);
                acc[rf][0] = __builtin_amdgcn_mfma_f32_16x16x32_bf16(ah, bl0, acc[rf][0], 0, 0, 0);
                acc[rf][1] = __builtin_amdgcn_mfma_f32_16x16x32_bf16(ah, bl1, acc[rf][1], 0, 0, 0);
            }
        }
        __builtin_amdgcn_s_setprio(0);
        __syncthreads();
    }

    const int wrow0 = row0 + (w >> 1) * 64;
    const int wcol0 = col0 + (w & 1) * 32;
    #pragma unroll
    for (int cf = 0; cf < 2; ++cf) {
        const int c = wcol0 + cf * 16 + l15;
        const float bb = bias[c];
        #pragma unroll
        for (int rf = 0; rf < 4; ++rf) {
            #pragma unroll
            for (int reg = 0; reg < 4; ++reg) {
                const int r = wrow0 + rf * 16 + l4 * 4 + reg;
                float y = acc[rf][cf][reg] + bb;
                if (AMODE == 1) {
                    ((float*)Y0)[(size_t)r * DIM + c] = y;
                } else {
                    _Float16* Yh = (_Float16*)((sel == 0) ? Y0 : (sel == 1) ? Y1 : Y2);
                    size_t base = ((size_t)((r >> 10) * NH + cb) * HWN + (r & 1023)) * HD + (c - col0);
                    Yh[base] = (_Float16)y;
                }
            }
        }
    }
}

// ---------------------------------------------------------------------------
// fp16 MFMA fused attention, 1-term QK^T, reg-prefetched K/V staging,
// bf16 rel tables, fp16 P/V, fp16 output. 4 blocks/CU (33KB LDS).
// ---------------------------------------------------------------------------
#define AT_RELH 0        // 64*33*2 = 4224
#define AT_RELW 4224     // -> 8448
#define AT_KF   8448     // 8192 -> 16640
#define AT_VT   16640    // 8192 -> 24832
#define AT_P    24832    // 8192 -> 33024
#define AT_Q16  8448     // prologue overlay (64*72*2 = 9216)
#define AT_OF   8448     // epilogue overlay
#define AT_TOTAL 33024

__global__ __launch_bounds__(256, 4) void attn_kernel(
    const _Float16* __restrict__ qh, const _Float16* __restrict__ kh,
    const _Float16* __restrict__ vh, const float* __restrict__ rel_pos_h,
    const float* __restrict__ rel_pos_w, _Float16* __restrict__ aout)
{
    __shared__ __align__(16) char smem[AT_TOTAL];
    const int bh = blockIdx.y;
    const int qb = blockIdx.x;
    const int t  = threadIdx.x;
    const int w  = t >> 6;
    const int lane = t & 63;
    const int l15 = lane & 15, l4 = lane >> 4;

    short* RelH = (short*)(smem + AT_RELH);
    short* RelW = (short*)(smem + AT_RELW);
    _Float16* Qf = (_Float16*)(smem + AT_Q16);

    const int r  = t >> 2, dc = (t & 3) * 16;   // shared by prologue/epilogue
    // ---- stage Q tile (fp16) ----
    {
        const _Float16* qp = qh + ((size_t)bh * HWN + qb * 64 + r) * HD + dc;
        *(short8*)(&Qf[r * 72 + dc])     = *(const short8*)(qp);
        *(short8*)(&Qf[r * 72 + dc + 8]) = *(const short8*)(qp + 8);
    }
    __syncthreads();

    // ---- prefetch K/V tile 0 into registers ----
    const _Float16* kb_ = kh + (size_t)bh * HWN * HD;
    const _Float16* vb_ = vh + (size_t)bh * HWN * HD;
    const int key = t >> 2, kdc = (t & 3) * 16;
    const int key2 = (t & 31) * 2, dgrp = t >> 5;
    short8 rk0, rk1, rv0, rv1;
#define LOADKV(KT) {                                                         \
        const _Float16* kp = kb_ + (size_t)((KT) * 64 + key) * HD + kdc;     \
        rk0 = *(const short8*)kp; rk1 = *(const short8*)(kp + 8);            \
        const _Float16* vp = vb_ + (size_t)((KT) * 64 + key2) * HD + dgrp * 8; \
        rv0 = *(const short8*)vp; rv1 = *(const short8*)(vp + HD); }
    LOADKV(0);

    // ---- rel-pos bias tables (bf16), unscaled q ----
    {
        const int ql = t >> 2, j0 = (t & 3) * 8;
        const int hq = qb * 2 + (ql >> 5);
        const int wq = ql & 31;
        const _Float16* qrow = &Qf[ql * 72];
        #pragma unroll
        for (int jj = 0; jj < 8; ++jj) {
            const int kk = j0 + jj;
            const float* rh = rel_pos_h + (size_t)(hq - kk + 31) * HD;
            const float* rw = rel_pos_w + (size_t)(wq - kk + 31) * HD;
            float sh = 0.f, sw2 = 0.f;
            for (int c = 0; c < HD; c += 8) {
                h8 qv = *(const h8*)(&qrow[c]);
                #pragma unroll
                for (int u = 0; u < 8; ++u) {
                    float qf_ = (float)qv[u];
                    sh += qf_ * rh[c + u];
                    sw2 += qf_ * rw[c + u];
                }
            }
            RelH[ql * 33 + kk] = f2bf(sh);
            RelW[ql * 33 + kk] = f2bf(sw2);
        }
    }

    // ---- Q fragments (fp16) ----
    h8 qf[2];
    {
        const int qr = w * 16 + l15;
        qf[0] = *(const h8*)(&Qf[qr * 72 + l4 * 8]);
        qf[1] = *(const h8*)(&Qf[qr * 72 + 32 + l4 * 8]);
    }

    f32x4 acc_o[4] = {{0,0,0,0},{0,0,0,0},{0,0,0,0},{0,0,0,0}};
    float m_[4], l_[4];
    #pragma unroll
    for (int i = 0; i < 4; ++i) { m_[i] = -INFINITY; l_[i] = 0.f; }

    char* Pw = smem + AT_P + w * 2048;
    const int swzk = (key & 7) << 4;
    const int c0 = (kdc * 2) ^ swzk, c1 = (kdc * 2 + 16) ^ swzk;

    for (int kt = 0; kt < 16; ++kt) {
        __syncthreads();   // previous tile's LDS reads (or prologue) done
        // ---- write prefetched regs -> LDS ----
        *(short8*)(smem + AT_KF + key * 128 + c0) = rk0;
        *(short8*)(smem + AT_KF + key * 128 + c1) = rk1;
        #pragma unroll
        for (int j = 0; j < 8; ++j) {
            const int d = dgrp * 8 + j;
            unsigned pk = ((unsigned short)rv0[j]) | (((unsigned)(unsigned short)rv1[j]) << 16);
            *(unsigned*)(smem + AT_VT + d * 128 + ((key2 * 2) ^ ((d & 7) << 4))) = pk;
        }
        __syncthreads();
        if (kt < 15) LOADKV(kt + 1);   // fly during compute below

        // ---- QK^T (fp16, 1 term) ----
        f32x4 accs[4] = {{0,0,0,0},{0,0,0,0},{0,0,0,0},{0,0,0,0}};
        __builtin_amdgcn_s_setprio(1);
        #pragma unroll
        for (int ct = 0; ct < 4; ++ct) {
            const int keyc = ct * 16 + l15;
            const int swz = (keyc & 7) << 4;
            #pragma unroll
            for (int ks = 0; ks < 2; ++ks) {
                const int cbk = (ks * 64 + l4 * 16) ^ swz;
                h8 kf = *(const h8*)(smem + AT_KF + keyc * 128 + cbk);
                accs[ct] = __builtin_amdgcn_mfma_f32_16x16x32_f16(qf[ks], kf, accs[ct], 0, 0, 0);
            }
        }
        __builtin_amdgcn_s_setprio(0);

        // ---- online softmax ----
        float s[4][4];
        float tmax[4] = {-INFINITY, -INFINITY, -INFINITY, -INFINITY};
        #pragma unroll
        for (int reg = 0; reg < 4; ++reg) {
            const int qloc = w * 16 + l4 * 4 + reg;
            #pragma unroll
            for (int ct = 0; ct < 4; ++ct) {
                float bias = bf2f(RelH[qloc * 33 + (kt * 2 + (ct >> 1))])
                           + bf2f(RelW[qloc * 33 + ((ct & 1) * 16 + l15)]);
                float v = accs[ct][reg] * 0.125f + bias;
                s[ct][reg] = v;
                tmax[reg] = fmaxf(tmax[reg], v);
            }
        }
        #pragma unroll
        for (int reg = 0; reg < 4; ++reg) {
            float tv = tmax[reg];
            tv = fmaxf(tv, __shfl_xor(tv, 1));
            tv = fmaxf(tv, __shfl_xor(tv, 2));
            tv = fmaxf(tv, __shfl_xor(tv, 4));
            tv = fmaxf(tv, __shfl_xor(tv, 8));
            tmax[reg] = tv;
        }
        float factor[4], tsum[4];
        #pragma unroll
        for (int reg = 0; reg < 4; ++reg) {
            float mn = fmaxf(m_[reg], tmax[reg]);
            factor[reg] = __expf(m_[reg] - mn);
            m_[reg] = mn;
            tsum[reg] = 0.f;
        }
        #pragma unroll
        for (int ct = 0; ct < 4; ++ct) {
            #pragma unroll
            for (int reg = 0; reg < 4; ++reg) {
                float p = __expf(s[ct][reg] - m_[reg]);
                tsum[reg] += p;
                const int q = l4 * 4 + reg;
                const int col = ct * 16 + l15;
                *(_Float16*)(Pw + q * 128 + ((col * 2) ^ ((q & 7) << 4))) = (_Float16)p;
            }
        }
        #pragma unroll
        for (int reg = 0; reg < 4; ++reg) {
            float ts = tsum[reg];
            ts += __shfl_xor(ts, 1);
            ts += __shfl_xor(ts, 2);
            ts += __shfl_xor(ts, 4);
            ts += __shfl_xor(ts, 8);
            l_[reg] = l_[reg] * factor[reg] + ts;
        }
        #pragma unroll
        for (int dt = 0; dt < 4; ++dt)
            #pragma unroll
            for (int reg = 0; reg < 4; ++reg)
                acc_o[dt][reg] *= factor[reg];

        // ---- PV (fp16) ----
        __builtin_amdgcn_s_setprio(1);
        #pragma unroll
        for (int ks = 0; ks < 2; ++ks) {
            const int cbp = (ks * 64 + l4 * 16) ^ ((l15 & 7) << 4);
            h8 pa = *(const h8*)(Pw + l15 * 128 + cbp);
            #pragma unroll
            for (int dt = 0; dt < 4; ++dt) {
                const int d = dt * 16 + l15;
                const int cbv = (ks * 64 + l4 * 16) ^ ((d & 7) << 4);
                h8 vf = *(const h8*)(smem + AT_VT + d * 128 + cbv);
                acc_o[dt] = __builtin_amdgcn_mfma_f32_16x16x32_f16(pa, vf, acc_o[dt], 0, 0, 0);
            }
        }
        __builtin_amdgcn_s_setprio(0);
    }

    // ---- epilogue ----
    __syncthreads();
    _Float16* Of = (_Float16*)(smem + AT_OF);
    #pragma unroll
    for (int reg = 0; reg < 4; ++reg) {
        float inv = 1.0f / l_[reg];
        const int qloc = w * 16 + l4 * 4 + reg;
        #pragma unroll
        for (int dt = 0; dt < 4; ++dt)
            Of[qloc * 72 + dt * 16 + l15] = (_Float16)(acc_o[dt][reg] * inv);
    }
    __syncthreads();
    {
        const int b_ = bh / NH, nh = bh % NH;
        _Float16* op = aout + ((size_t)b_ * HWN + qb * 64 + r) * DIM + nh * HD + dc;
        *(short8*)op       = *(const short8*)(&Of[r * 72 + dc]);
        *(short8*)(op + 8) = *(const short8*)(&Of[r * 72 + dc + 8]);
    }
}

// ---------------------------------------------------------------------------
extern "C" void kernel_launch(void* const* d_in, const int* in_sizes, int n_in,
                              void* d_out, int out_size, void* d_ws, size_t ws_size,
                              hipStream_t stream) {
    const float* q   = (const float*)d_in[0];
    const float* k   = (const float*)d_in[1];
    const float* v   = (const float*)d_in[2];
    const float* Wq  = (const float*)d_in[3];
    const float* bq  = (const float*)d_in[4];
    const float* Wk  = (const float*)d_in[5];
    const float* bk  = (const float*)d_in[6];
    const float* Wv  = (const float*)d_in[7];
    const float* bv  = (const float*)d_in[8];
    const float* Wp  = (const float*)d_in[9];
    const float* bp  = (const float*)d_in[10];
    const float* rph = (const float*)d_in[11];
    const float* rpw = (const float*)d_in[12];

    float* out = (float*)d_out;
    char*  w0  = (char*)d_ws;

    short*    whiAll = (short*)(w0);                  // 4*1179648 = 4,718,592
    short*    wloAll = (short*)(w0 + 4718592);        // -> 9,437,184
    _Float16* qf16   = (_Float16*)(w0 + 9437184);     // 6,291,456
    _Float16* kf16   = (_Float16*)(w0 + 15728640);    // 6,291,456
    _Float16* vf16   = (_Float16*)(w0 + 22020096);    // 6,291,456
    _Float16* aout   = (_Float16*)(w0 + 28311552);    // 6,291,456 -> 34,603,008

    dim3 blk(256);
    wsplit_kernel<<<dim3(12, 12, 4), blk, 0, stream>>>(Wq, Wk, Wv, Wp, whiAll, wloAll);
    gemm_mfma_kernel<0><<<1152, blk, 0, stream>>>(
        q, k, v, whiAll, wloAll, bq, bk, bv, qf16, kf16, vf16);
    attn_kernel<<<dim3(16, 48), blk, 0, stream>>>(qf16, kf16, vf16, rph, rpw, aout);
    gemm_mfma_kernel<1><<<384, blk, 0, stream>>>(
        aout, nullptr, nullptr, whiAll, wloAll, bp, nullptr, nullptr,
        out, nullptr, nullptr);
}

// Round 6
// 207.064 us; speedup vs baseline: 3.8811x; 1.1006x over previous
//
#include <hip/hip_runtime.h>
#include <math.h>

#define DIM  768
#define NH   12
#define HD   64
#define HWN  1024
#define MROWS 4096

typedef __attribute__((ext_vector_type(8))) short short8;
typedef __attribute__((ext_vector_type(4))) float f32x4;
typedef _Float16 h8 __attribute__((ext_vector_type(8)));
typedef _Float16 h2 __attribute__((ext_vector_type(2)));

__device__ __forceinline__ void gl_lds16(const void* g, void* l) {
    __builtin_amdgcn_global_load_lds(
        (const __attribute__((address_space(1))) void*)g,
        (__attribute__((address_space(3))) void*)l, 16, 0, 0);
}

// ---------------------------------------------------------------------------
// W (768x768 k-major fp32) -> Wt fp16 (n-major). z selects Wq/Wk/Wv/Wp.
// ---------------------------------------------------------------------------
__global__ __launch_bounds__(256) void wconv_kernel(
    const float* __restrict__ Wq, const float* __restrict__ Wk,
    const float* __restrict__ Wv, const float* __restrict__ Wp,
    _Float16* __restrict__ WtAll)
{
    __shared__ float Ws[64][65];
    const int z = blockIdx.z;
    const float* W = (z == 0) ? Wq : (z == 1) ? Wk : (z == 2) ? Wv : Wp;
    _Float16* Wt = WtAll + (size_t)z * 589824;

    const int k0 = blockIdx.y * 64, n0 = blockIdx.x * 64;
    const int t = threadIdx.x;
    {
        int r = t >> 2, c4 = (t & 3) * 16;
        #pragma unroll
        for (int u = 0; u < 16; u += 4)
            *(float4*)&Ws[r][c4 + u] = *(const float4*)(W + (size_t)(k0 + r) * DIM + n0 + c4 + u);
    }
    __syncthreads();
    const int n = t >> 2, kseg = (t & 3) * 16;
    h8 h0, h1;
    #pragma unroll
    for (int j = 0; j < 8; ++j) {
        h0[j] = (_Float16)Ws[kseg + j][n];
        h1[j] = (_Float16)Ws[kseg + 8 + j][n];
    }
    size_t base = (size_t)(n0 + n) * DIM + k0 + kseg;
    *(h8*)(Wt + base) = h0;
    *(h8*)(Wt + base + 8) = h1;
}

// ---------------------------------------------------------------------------
// fp16 1-term MFMA GEMM. A staged raw via global_load_lds, cvt in-reg.
// AMODE 0: A fp32 (q/k/v fused, 1152 blocks), out fp16 head layout.
// AMODE 1: A fp16 (attn out, 384 blocks), out fp32 flat (d_out) + bias.
// Tile 128x64, BK=64, 4 waves, wave tile 64x32.
// ---------------------------------------------------------------------------
template<int AMODE>
__global__ __launch_bounds__(256, 3) void gemm_mfma_kernel(
    const void* __restrict__ X0, const void* __restrict__ X1,
    const void* __restrict__ X2, const _Float16* __restrict__ WtAll,
    const float* __restrict__ bias0, const float* __restrict__ bias1,
    const float* __restrict__ bias2,
    void* __restrict__ Y0, void* __restrict__ Y1, void* __restrict__ Y2)
{
    // A: 32KB (fp32) or 16KB (fp16) | B: 8KB fp16
    __shared__ __align__(16) char smem[AMODE == 0 ? 40960 : 24576];
    const int BOFF = (AMODE == 0) ? 32768 : 16384;
    const int t = threadIdx.x;
    const int w = t >> 6, lane = t & 63;
    const int l15 = lane & 15, l4 = lane >> 4;

    int sel, rem;
    if (AMODE == 0) {
        const int sw = (blockIdx.x & 7) * 144 + (blockIdx.x >> 3);
        sel = sw / 384; rem = sw - sel * 384;
    } else {
        const int sw = (blockIdx.x & 7) * 48 + (blockIdx.x >> 3);
        sel = 3; rem = sw;
    }
    const int rb = rem / 12, cb = rem - rb * 12;
    const int row0 = rb * 128, col0 = cb * 64;

    const char* Ab = (const char*)((AMODE == 1 || sel == 0) ? X0 : (sel == 1) ? X1 : X2);
    const _Float16* Bt = WtAll + (size_t)sel * 589824;
    const float* bias = (AMODE == 1) ? bias0 : (sel == 0) ? bias0 : (sel == 1) ? bias1 : bias2;

    f32x4 acc[4][2];
    #pragma unroll
    for (int i = 0; i < 4; ++i)
        #pragma unroll
        for (int j = 0; j < 2; ++j) acc[i][j] = (f32x4){0, 0, 0, 0};

    for (int kt = 0; kt < 12; ++kt) {
        // ---- stage A raw ----
        if (AMODE == 0) {
            #pragma unroll
            for (int i = 0; i < 8; ++i) {
                const int fi = w * 8 + i;
                const int row = fi * 4 + (lane >> 4);
                const int real = ((lane & 15) * 16) ^ ((row & 7) << 5);
                gl_lds16(Ab + (size_t)(row0 + row) * 3072 + kt * 256 + real, smem + fi * 1024);
            }
        } else {
            #pragma unroll
            for (int i = 0; i < 4; ++i) {
                const int fi = w * 4 + i;
                const int row = fi * 8 + (lane >> 3);
                const int real = ((lane & 7) * 16) ^ ((row & 7) << 4);
                gl_lds16(Ab + (size_t)(row0 + row) * 1536 + kt * 128 + real, smem + fi * 1024);
            }
        }
        // ---- stage B (fp16 n-major, fragment-major LDS) ----
        #pragma unroll
        for (int it = 0; it < 2; ++it) {
            const int f = it * 4 + w;
            const int ks = f >> 2, cf = f & 3;
            const size_t off = (size_t)(col0 + cf * 16 + l15) * 1536 + kt * 128 + ks * 64 + l4 * 16;
            gl_lds16((const char*)Bt + off, smem + BOFF + f * 1024);
        }
        __syncthreads();

        __builtin_amdgcn_s_setprio(1);
        #pragma unroll
        for (int ks = 0; ks < 2; ++ks) {
            const int fb = ks * 4 + (w & 1) * 2;
            h8 b0 = *(const h8*)(smem + BOFF + (fb    ) * 1024 + lane * 16);
            h8 b1 = *(const h8*)(smem + BOFF + (fb + 1) * 1024 + lane * 16);
            #pragma unroll
            for (int rf = 0; rf < 4; ++rf) {
                const int arow = (w >> 1) * 64 + rf * 16 + l15;
                h8 ah;
                if (AMODE == 0) {
                    const int base = arow * 256 + ((ks * 128 + l4 * 32) ^ ((arow & 7) << 5));
                    f32x4 a0 = *(const f32x4*)(smem + base);
                    f32x4 a1 = *(const f32x4*)(smem + base + 16);
                    ah[0] = (_Float16)a0[0]; ah[1] = (_Float16)a0[1];
                    ah[2] = (_Float16)a0[2]; ah[3] = (_Float16)a0[3];
                    ah[4] = (_Float16)a1[0]; ah[5] = (_Float16)a1[1];
                    ah[6] = (_Float16)a1[2]; ah[7] = (_Float16)a1[3];
                } else {
                    const int base = arow * 128 + ((ks * 64 + l4 * 16) ^ ((arow & 7) << 4));
                    ah = *(const h8*)(smem + base);
                }
                acc[rf][0] = __builtin_amdgcn_mfma_f32_16x16x32_f16(ah, b0, acc[rf][0], 0, 0, 0);
                acc[rf][1] = __builtin_amdgcn_mfma_f32_16x16x32_f16(ah, b1, acc[rf][1], 0, 0, 0);
            }
        }
        __builtin_amdgcn_s_setprio(0);
        __syncthreads();
    }

    const int wrow0 = row0 + (w >> 1) * 64;
    const int wcol0 = col0 + (w & 1) * 32;
    #pragma unroll
    for (int cf = 0; cf < 2; ++cf) {
        const int c = wcol0 + cf * 16 + l15;
        const float bb = bias[c];
        #pragma unroll
        for (int rf = 0; rf < 4; ++rf) {
            #pragma unroll
            for (int reg = 0; reg < 4; ++reg) {
                const int r = wrow0 + rf * 16 + l4 * 4 + reg;
                float y = acc[rf][cf][reg] + bb;
                if (AMODE == 1) {
                    ((float*)Y0)[(size_t)r * DIM + c] = y;
                } else {
                    _Float16* Yh = (_Float16*)((sel == 0) ? Y0 : (sel == 1) ? Y1 : Y2);
                    size_t base = ((size_t)((r >> 10) * NH + cb) * HWN + (r & 1023)) * HD + (c - col0);
                    Yh[base] = (_Float16)y;
                }
            }
        }
    }
}

// ---------------------------------------------------------------------------
// fp16 MFMA fused attention, swapped QK^T (D[key][q]) -> lane-local softmax.
// K direct from global (L2-resident), double-buffered V^T (1 barrier/kt),
// bias folded into MFMA C-init, defer-max rescale (THR=8).
// BUGFIX R6: bias table rows are q = w*16 + l15 (was l15 — waves 1-3 read
// wave-0's bias rows, 9.2e-3 absmax).
// ---------------------------------------------------------------------------
#define AT_RELH 0        // 64*33*4 = 8448
#define AT_RELW 8448     // -> 16896
#define AT_VT   16896    // 2 x 8192 -> 33280
#define AT_P    33280    // 4 x 2048 -> 41472
#define AT_QF   16896    // prologue overlay (64*72*2 = 9216)
#define AT_OF   16896    // epilogue overlay
#define AT_TOTAL 41472

__global__ __launch_bounds__(256, 3) void attn_kernel(
    const _Float16* __restrict__ qh, const _Float16* __restrict__ kh,
    const _Float16* __restrict__ vh, const float* __restrict__ rel_pos_h,
    const float* __restrict__ rel_pos_w, _Float16* __restrict__ aout)
{
    __shared__ __align__(16) char smem[AT_TOTAL];
    const int bh = blockIdx.y;     // 0..47
    const int qb = blockIdx.x;     // 0..15
    const int t  = threadIdx.x;
    const int w  = t >> 6;
    const int lane = t & 63;
    const int l15 = lane & 15, l4 = lane >> 4;

    float* RelH = (float*)(smem + AT_RELH);
    float* RelW = (float*)(smem + AT_RELW);
    _Float16* Qf = (_Float16*)(smem + AT_QF);

    const int r = t >> 2, dc = (t & 3) * 16;
    // ---- stage Q tile (fp16) ----
    {
        const _Float16* qp = qh + ((size_t)bh * HWN + qb * 64 + r) * HD + dc;
        *(short8*)(&Qf[r * 72 + dc])     = *(const short8*)(qp);
        *(short8*)(&Qf[r * 72 + dc + 8]) = *(const short8*)(qp + 8);
    }
    __syncthreads();

    const _Float16* kb_ = kh + (size_t)bh * HWN * HD;
    const _Float16* vb_ = vh + (size_t)bh * HWN * HD;
    const int key2 = (t & 31) * 2, dgrp = t >> 5;
    short8 rv0, rv1;
#define LOADV(KT) {                                                            \
        const _Float16* vp = vb_ + (size_t)((KT) * 64 + key2) * HD + dgrp * 8; \
        rv0 = *(const short8*)vp; rv1 = *(const short8*)(vp + HD); }
    LOADV(0);   // in flight during rel-table compute

    // ---- rel-pos bias tables (fp32, unscaled q) ----
    {
        const int ql = t >> 2, j0 = (t & 3) * 8;
        const int hq = qb * 2 + (ql >> 5);
        const int wq = ql & 31;
        const _Float16* qrow = &Qf[ql * 72];
        #pragma unroll
        for (int jj = 0; jj < 8; ++jj) {
            const int kk = j0 + jj;
            const float* rh = rel_pos_h + (size_t)(hq - kk + 31) * HD;
            const float* rw = rel_pos_w + (size_t)(wq - kk + 31) * HD;
            float sh = 0.f, sw2 = 0.f;
            for (int c = 0; c < HD; c += 8) {
                h8 qv = *(const h8*)(&qrow[c]);
                #pragma unroll
                for (int u = 0; u < 8; ++u) {
                    float qf_ = (float)qv[u];
                    sh += qf_ * rh[c + u];
                    sw2 += qf_ * rw[c + u];
                }
            }
            RelH[ql * 33 + kk] = sh;
            RelW[ql * 33 + kk] = sw2;
        }
    }
    __syncthreads();

    // ---- Q fragments (B-operand), pre-scaled by 1/8 ----
    h8 qf2[2];
    {
        const int qr = w * 16 + l15;
        qf2[0] = *(const h8*)(&Qf[qr * 72 + l4 * 8]);
        qf2[1] = *(const h8*)(&Qf[qr * 72 + 32 + l4 * 8]);
        #pragma unroll
        for (int j = 0; j < 8; ++j) { qf2[0][j] *= (_Float16)0.125f; qf2[1][j] *= (_Float16)0.125f; }
    }
    // ---- hoisted RelW biases (kt-invariant), q = w*16 + l15 ----
    const int qrow_bias = w * 16 + l15;          // BUGFIX (was l15)
    float rw_[2][4];
    #pragma unroll
    for (int c2 = 0; c2 < 2; ++c2)
        #pragma unroll
        for (int reg = 0; reg < 4; ++reg)
            rw_[c2][reg] = RelW[qrow_bias * 33 + c2 * 16 + l4 * 4 + reg];

    // ---- K fragments (A-operand) direct from global ----
    short8 kf[8];
#define LOADK(KT) {                                                            \
        _Pragma("unroll")                                                      \
        for (int ct = 0; ct < 4; ++ct)                                         \
            _Pragma("unroll")                                                  \
            for (int ks = 0; ks < 2; ++ks)                                     \
                kf[ct * 2 + ks] = *(const short8*)(kb_ +                       \
                    (size_t)((KT) * 64 + ct * 16 + l15) * HD + ks * 32 + l4 * 8); }
    LOADK(0);
    __syncthreads();   // Qf reads done; VT region reusable

#define WRITEVT(BUF) {                                                         \
        _Pragma("unroll")                                                      \
        for (int j = 0; j < 8; ++j) {                                          \
            const int d = dgrp * 8 + j;                                        \
            unsigned pk = ((unsigned short)rv0[j]) |                           \
                          (((unsigned)(unsigned short)rv1[j]) << 16);          \
            *(unsigned*)(smem + AT_VT + (BUF) * 8192 + d * 128 +               \
                         ((key2 * 2) ^ ((d & 7) << 4))) = pk; } }
    WRITEVT(0);

    f32x4 acc_o[4] = {{0,0,0,0},{0,0,0,0},{0,0,0,0},{0,0,0,0}};
    float m_ = -INFINITY, l_ = 0.f;
    char* Pw = smem + AT_P + w * 2048;
    const int swzP = (l15 & 7) << 4;

    for (int kt = 0; kt < 16; ++kt) {
        const int cur = kt & 1;
        __syncthreads();                 // VT[cur] writes visible
        if (kt < 15) LOADV(kt + 1);      // in flight across whole iteration

        // ---- QK^T swapped: D[key][q], C-init = rel bias ----
        const float rh0 = RelH[qrow_bias * 33 + kt * 2];        // BUGFIX row
        const float rh1 = RelH[qrow_bias * 33 + kt * 2 + 1];    // BUGFIX row
        f32x4 accs[4];
        #pragma unroll
        for (int ct = 0; ct < 4; ++ct) {
            const float rhc = (ct >> 1) ? rh1 : rh0;
            #pragma unroll
            for (int reg = 0; reg < 4; ++reg)
                accs[ct][reg] = rw_[ct & 1][reg] + rhc;
        }
        __builtin_amdgcn_s_setprio(1);
        #pragma unroll
        for (int ct = 0; ct < 4; ++ct)
            #pragma unroll
            for (int ks = 0; ks < 2; ++ks)
                accs[ct] = __builtin_amdgcn_mfma_f32_16x16x32_f16(
                    *(const h8*)&kf[ct * 2 + ks], qf2[ks], accs[ct], 0, 0, 0);
        __builtin_amdgcn_s_setprio(0);
        if (kt < 15) LOADK(kt + 1);      // prefetch next K frags

        // ---- lane-local online softmax (q = w*16 + l15) ----
        float tmax = -INFINITY;
        #pragma unroll
        for (int ct = 0; ct < 4; ++ct)
            #pragma unroll
            for (int reg = 0; reg < 4; ++reg)
                tmax = fmaxf(tmax, accs[ct][reg]);
        tmax = fmaxf(tmax, __shfl_xor(tmax, 16));
        tmax = fmaxf(tmax, __shfl_xor(tmax, 32));

        if (__any(tmax > m_ + 8.f)) {    // defer-max: rescale rarely
            const float mnew = fmaxf(m_, tmax);
            const float factor = __expf(m_ - mnew);
            m_ = mnew;
            l_ *= factor;
            #pragma unroll
            for (int reg = 0; reg < 4; ++reg) {
                const float fr = __shfl(factor, l4 * 4 + reg);
                #pragma unroll
                for (int dt = 0; dt < 4; ++dt) acc_o[dt][reg] *= fr;
            }
        }

        float tsum = 0.f;
        #pragma unroll
        for (int ct = 0; ct < 4; ++ct) {
            float p0 = __expf(accs[ct][0] - m_);
            float p1 = __expf(accs[ct][1] - m_);
            float p2 = __expf(accs[ct][2] - m_);
            float p3 = __expf(accs[ct][3] - m_);
            tsum += (p0 + p1) + (p2 + p3);
            h2 pa = {(_Float16)p0, (_Float16)p1};
            h2 pb = {(_Float16)p2, (_Float16)p3};
            uint2 pk;
            pk.x = *(unsigned*)&pa;
            pk.y = *(unsigned*)&pb;
            *(uint2*)(Pw + l15 * 128 + ((ct * 32 + l4 * 8) ^ swzP)) = pk;
        }
        tsum += __shfl_xor(tsum, 16);
        tsum += __shfl_xor(tsum, 32);
        l_ += tsum;

        // ---- PV: O[q][d] += P[q][k] V[k][d] ----
        __builtin_amdgcn_s_setprio(1);
        #pragma unroll
        for (int ks = 0; ks < 2; ++ks) {
            h8 pa = *(const h8*)(Pw + l15 * 128 + ((ks * 64 + l4 * 16) ^ swzP));
            #pragma unroll
            for (int dt = 0; dt < 4; ++dt) {
                const int d = dt * 16 + l15;
                h8 vf = *(const h8*)(smem + AT_VT + cur * 8192 + d * 128 +
                                     ((ks * 64 + l4 * 16) ^ ((d & 7) << 4)));
                acc_o[dt] = __builtin_amdgcn_mfma_f32_16x16x32_f16(pa, vf, acc_o[dt], 0, 0, 0);
            }
        }
        __builtin_amdgcn_s_setprio(0);

        if (kt < 15) WRITEVT(cur ^ 1);   // stage next tile into other buffer
    }

    // ---- epilogue ----
    const float invl = 1.0f / l_;
    float linv[4];
    #pragma unroll
    for (int reg = 0; reg < 4; ++reg) linv[reg] = __shfl(invl, l4 * 4 + reg);
    __syncthreads();
    _Float16* Of = (_Float16*)(smem + AT_OF);
    #pragma unroll
    for (int reg = 0; reg < 4; ++reg) {
        const int qloc = w * 16 + l4 * 4 + reg;
        #pragma unroll
        for (int dt = 0; dt < 4; ++dt)
            Of[qloc * 72 + dt * 16 + l15] = (_Float16)(acc_o[dt][reg] * linv[reg]);
    }
    __syncthreads();
    {
        const int b_ = bh / NH, nh = bh % NH;
        _Float16* op = aout + ((size_t)b_ * HWN + qb * 64 + r) * DIM + nh * HD + dc;
        *(short8*)op       = *(const short8*)(&Of[r * 72 + dc]);
        *(short8*)(op + 8) = *(const short8*)(&Of[r * 72 + dc + 8]);
    }
}

// ---------------------------------------------------------------------------
extern "C" void kernel_launch(void* const* d_in, const int* in_sizes, int n_in,
                              void* d_out, int out_size, void* d_ws, size_t ws_size,
                              hipStream_t stream) {
    const float* q   = (const float*)d_in[0];
    const float* k   = (const float*)d_in[1];
    const float* v   = (const float*)d_in[2];
    const float* Wq  = (const float*)d_in[3];
    const float* bq  = (const float*)d_in[4];
    const float* Wk  = (const float*)d_in[5];
    const float* bk  = (const float*)d_in[6];
    const float* Wv  = (const float*)d_in[7];
    const float* bv  = (const float*)d_in[8];
    const float* Wp  = (const float*)d_in[9];
    const float* bp  = (const float*)d_in[10];
    const float* rph = (const float*)d_in[11];
    const float* rpw = (const float*)d_in[12];

    float* out = (float*)d_out;
    char*  w0  = (char*)d_ws;

    _Float16* wtAll = (_Float16*)(w0);                // 4,718,592 B
    _Float16* qf16  = (_Float16*)(w0 + 4718592);      // 6,291,456
    _Float16* kf16  = (_Float16*)(w0 + 11010048);     // 6,291,456
    _Float16* vf16  = (_Float16*)(w0 + 17301504);     // 6,291,456
    _Float16* aout  = (_Float16*)(w0 + 23592960);     // 6,291,456 -> 29,884,416

    dim3 blk(256);
    wconv_kernel<<<dim3(12, 12, 4), blk, 0, stream>>>(Wq, Wk, Wv, Wp, wtAll);
    gemm_mfma_kernel<0><<<1152, blk, 0, stream>>>(
        q, k, v, wtAll, bq, bk, bv, qf16, kf16, vf16);
    attn_kernel<<<dim3(16, 48), blk, 0, stream>>>(qf16, kf16, vf16, rph, rpw, aout);
    gemm_mfma_kernel<1><<<384, blk, 0, stream>>>(
        aout, nullptr, nullptr, wtAll, bp, nullptr, nullptr,
        out, nullptr, nullptr);
}

// Round 7
// 128.993 us; speedup vs baseline: 6.2301x; 1.6052x over previous
//
#include <hip/hip_runtime.h>
#include <math.h>

#define DIM  768
#define NH   12
#define HD   64
#define HWN  1024
#define MROWS 4096

typedef __attribute__((ext_vector_type(8))) short short8;
typedef __attribute__((ext_vector_type(4))) float f32x4;
typedef _Float16 h8 __attribute__((ext_vector_type(8)));
typedef _Float16 h2 __attribute__((ext_vector_type(2)));

__device__ __forceinline__ void gl_lds16(const void* g, void* l) {
    __builtin_amdgcn_global_load_lds(
        (const __attribute__((address_space(1))) void*)g,
        (__attribute__((address_space(3))) void*)l, 16, 0, 0);
}

// ---------------------------------------------------------------------------
// W (768x768 k-major fp32) -> Wt fp16 (n-major). z selects Wq/Wk/Wv/Wp.
// ---------------------------------------------------------------------------
__global__ __launch_bounds__(256) void wconv_kernel(
    const float* __restrict__ Wq, const float* __restrict__ Wk,
    const float* __restrict__ Wv, const float* __restrict__ Wp,
    _Float16* __restrict__ WtAll)
{
    __shared__ float Ws[64][65];
    const int z = blockIdx.z;
    const float* W = (z == 0) ? Wq : (z == 1) ? Wk : (z == 2) ? Wv : Wp;
    _Float16* Wt = WtAll + (size_t)z * 589824;

    const int k0 = blockIdx.y * 64, n0 = blockIdx.x * 64;
    const int t = threadIdx.x;
    {
        int r = t >> 2, c4 = (t & 3) * 16;
        #pragma unroll
        for (int u = 0; u < 16; u += 4)
            *(float4*)&Ws[r][c4 + u] = *(const float4*)(W + (size_t)(k0 + r) * DIM + n0 + c4 + u);
    }
    __syncthreads();
    const int n = t >> 2, kseg = (t & 3) * 16;
    h8 h0, h1;
    #pragma unroll
    for (int j = 0; j < 8; ++j) {
        h0[j] = (_Float16)Ws[kseg + j][n];
        h1[j] = (_Float16)Ws[kseg + 8 + j][n];
    }
    size_t base = (size_t)(n0 + n) * DIM + k0 + kseg;
    *(h8*)(Wt + base) = h0;
    *(h8*)(Wt + base + 8) = h1;
}

// ---------------------------------------------------------------------------
// Pack [rel_pos_h(63x64) ; pad ; rel_pos_w(63x64) ; pad] -> fp16 n-major
// RelT[128][64]: row j<63 = rph[j], 64<=j<127 = rpw[j-64], rows 63/127 = 0.
// ---------------------------------------------------------------------------
__global__ __launch_bounds__(256) void rel2frag_kernel(
    const float* __restrict__ rph, const float* __restrict__ rpw,
    _Float16* __restrict__ relTg)
{
    const int t = threadIdx.x;
    const int row = t >> 1, c0 = (t & 1) * 32;
    const float* src = (row < 63) ? rph + (size_t)row * HD
                     : (row >= 64 && row < 127) ? rpw + (size_t)(row - 64) * HD
                     : nullptr;
    #pragma unroll
    for (int g = 0; g < 4; ++g) {
        h8 o;
        #pragma unroll
        for (int j = 0; j < 8; ++j)
            o[j] = src ? (_Float16)src[c0 + g * 8 + j] : (_Float16)0.0f;
        *(h8*)(relTg + (size_t)row * HD + c0 + g * 8) = o;
    }
}

// ---------------------------------------------------------------------------
// fp16 1-term MFMA GEMM. A staged raw via global_load_lds, cvt in-reg.
// AMODE 0: A fp32 (q/k/v fused, 1152 blocks), out fp16 head layout.
// AMODE 1: A fp16 (attn out, 384 blocks), out fp32 flat (d_out) + bias.
// ---------------------------------------------------------------------------
template<int AMODE>
__global__ __launch_bounds__(256, 3) void gemm_mfma_kernel(
    const void* __restrict__ X0, const void* __restrict__ X1,
    const void* __restrict__ X2, const _Float16* __restrict__ WtAll,
    const float* __restrict__ bias0, const float* __restrict__ bias1,
    const float* __restrict__ bias2,
    void* __restrict__ Y0, void* __restrict__ Y1, void* __restrict__ Y2)
{
    __shared__ __align__(16) char smem[AMODE == 0 ? 40960 : 24576];
    const int BOFF = (AMODE == 0) ? 32768 : 16384;
    const int t = threadIdx.x;
    const int w = t >> 6, lane = t & 63;
    const int l15 = lane & 15, l4 = lane >> 4;

    int sel, rem;
    if (AMODE == 0) {
        const int sw = (blockIdx.x & 7) * 144 + (blockIdx.x >> 3);
        sel = sw / 384; rem = sw - sel * 384;
    } else {
        const int sw = (blockIdx.x & 7) * 48 + (blockIdx.x >> 3);
        sel = 3; rem = sw;
    }
    const int rb = rem / 12, cb = rem - rb * 12;
    const int row0 = rb * 128, col0 = cb * 64;

    const char* Ab = (const char*)((AMODE == 1 || sel == 0) ? X0 : (sel == 1) ? X1 : X2);
    const _Float16* Bt = WtAll + (size_t)sel * 589824;
    const float* bias = (AMODE == 1) ? bias0 : (sel == 0) ? bias0 : (sel == 1) ? bias1 : bias2;

    f32x4 acc[4][2];
    #pragma unroll
    for (int i = 0; i < 4; ++i)
        #pragma unroll
        for (int j = 0; j < 2; ++j) acc[i][j] = (f32x4){0, 0, 0, 0};

    for (int kt = 0; kt < 12; ++kt) {
        if (AMODE == 0) {
            #pragma unroll
            for (int i = 0; i < 8; ++i) {
                const int fi = w * 8 + i;
                const int row = fi * 4 + (lane >> 4);
                const int real = ((lane & 15) * 16) ^ ((row & 7) << 5);
                gl_lds16(Ab + (size_t)(row0 + row) * 3072 + kt * 256 + real, smem + fi * 1024);
            }
        } else {
            #pragma unroll
            for (int i = 0; i < 4; ++i) {
                const int fi = w * 4 + i;
                const int row = fi * 8 + (lane >> 3);
                const int real = ((lane & 7) * 16) ^ ((row & 7) << 4);
                gl_lds16(Ab + (size_t)(row0 + row) * 1536 + kt * 128 + real, smem + fi * 1024);
            }
        }
        #pragma unroll
        for (int it = 0; it < 2; ++it) {
            const int f = it * 4 + w;
            const int ks = f >> 2, cf = f & 3;
            const size_t off = (size_t)(col0 + cf * 16 + l15) * 1536 + kt * 128 + ks * 64 + l4 * 16;
            gl_lds16((const char*)Bt + off, smem + BOFF + f * 1024);
        }
        __syncthreads();

        __builtin_amdgcn_s_setprio(1);
        #pragma unroll
        for (int ks = 0; ks < 2; ++ks) {
            const int fb = ks * 4 + (w & 1) * 2;
            h8 b0 = *(const h8*)(smem + BOFF + (fb    ) * 1024 + lane * 16);
            h8 b1 = *(const h8*)(smem + BOFF + (fb + 1) * 1024 + lane * 16);
            #pragma unroll
            for (int rf = 0; rf < 4; ++rf) {
                const int arow = (w >> 1) * 64 + rf * 16 + l15;
                h8 ah;
                if (AMODE == 0) {
                    const int base = arow * 256 + ((ks * 128 + l4 * 32) ^ ((arow & 7) << 5));
                    f32x4 a0 = *(const f32x4*)(smem + base);
                    f32x4 a1 = *(const f32x4*)(smem + base + 16);
                    ah[0] = (_Float16)a0[0]; ah[1] = (_Float16)a0[1];
                    ah[2] = (_Float16)a0[2]; ah[3] = (_Float16)a0[3];
                    ah[4] = (_Float16)a1[0]; ah[5] = (_Float16)a1[1];
                    ah[6] = (_Float16)a1[2]; ah[7] = (_Float16)a1[3];
                } else {
                    const int base = arow * 128 + ((ks * 64 + l4 * 16) ^ ((arow & 7) << 4));
                    ah = *(const h8*)(smem + base);
                }
                acc[rf][0] = __builtin_amdgcn_mfma_f32_16x16x32_f16(ah, b0, acc[rf][0], 0, 0, 0);
                acc[rf][1] = __builtin_amdgcn_mfma_f32_16x16x32_f16(ah, b1, acc[rf][1], 0, 0, 0);
            }
        }
        __builtin_amdgcn_s_setprio(0);
        __syncthreads();
    }

    const int wrow0 = row0 + (w >> 1) * 64;
    const int wcol0 = col0 + (w & 1) * 32;
    #pragma unroll
    for (int cf = 0; cf < 2; ++cf) {
        const int c = wcol0 + cf * 16 + l15;
        const float bb = bias[c];
        #pragma unroll
        for (int rf = 0; rf < 4; ++rf) {
            #pragma unroll
            for (int reg = 0; reg < 4; ++reg) {
                const int r = wrow0 + rf * 16 + l4 * 4 + reg;
                float y = acc[rf][cf][reg] + bb;
                if (AMODE == 1) {
                    ((float*)Y0)[(size_t)r * DIM + c] = y;
                } else {
                    _Float16* Yh = (_Float16*)((sel == 0) ? Y0 : (sel == 1) ? Y1 : Y2);
                    size_t base = ((size_t)((r >> 10) * NH + cb) * HWN + (r & 1023)) * HD + (c - col0);
                    Yh[base] = (_Float16)y;
                }
            }
        }
    }
}

// ---------------------------------------------------------------------------
// fp16 MFMA fused attention. R7: rel-pos bias tables computed via MFMA
// (Q-tile x RelT frags) + gather, replacing the serial scalar prologue.
// Rel stored fp16 -> 34.6KB LDS -> 4 blocks/CU. Inner loop = R6 (verified).
// ---------------------------------------------------------------------------
#define AT_REL   0        // 64*68*2 = 8704
#define AT_VT    8704     // 2 x 8192 -> 25088
#define AT_P     25088    // 4 x 2048 -> 33280
#define AT_QF    8704     // prologue overlay: 64*72*2 = 9216 -> 17920
#define AT_RELT  17920    // prologue overlay: 16*1024 = 16384 -> 34304
#define AT_PG    17920    // prologue overlay: 64*130*2 = 16640 -> 34560
#define AT_OF    8704     // epilogue overlay
#define AT_TOTAL 34560

__global__ __launch_bounds__(256, 4) void attn_kernel(
    const _Float16* __restrict__ qh, const _Float16* __restrict__ kh,
    const _Float16* __restrict__ vh, const _Float16* __restrict__ relTg,
    _Float16* __restrict__ aout)
{
    __shared__ __align__(16) char smem[AT_TOTAL];
    const int bh = blockIdx.y;     // 0..47
    const int qb = blockIdx.x;     // 0..15
    const int t  = threadIdx.x;
    const int w  = t >> 6;
    const int lane = t & 63;
    const int l15 = lane & 15, l4 = lane >> 4;

    _Float16* Rel = (_Float16*)(smem + AT_REL);
    _Float16* Qf  = (_Float16*)(smem + AT_QF);

    const int r = t >> 2, dc = (t & 3) * 16;
    // ---- stage Q tile (fp16) + RelT frags ----
    {
        const _Float16* qp = qh + ((size_t)bh * HWN + qb * 64 + r) * HD + dc;
        *(short8*)(&Qf[r * 72 + dc])     = *(const short8*)(qp);
        *(short8*)(&Qf[r * 72 + dc + 8]) = *(const short8*)(qp + 8);
        #pragma unroll
        for (int it = 0; it < 4; ++it) {
            const int f = it * 4 + w;          // f = ct*2 + ks
            const int ct = f >> 1, ks = f & 1;
            gl_lds16((const char*)relTg + (ct * 16 + l15) * 128 + ks * 64 + l4 * 16,
                     smem + AT_RELT + f * 1024);
        }
    }
    __syncthreads();

    // ---- Q fragments (B-operand), pre-scaled by 1/8 ----
    h8 qf2[2];
    {
        const int qr = w * 16 + l15;
        qf2[0] = *(const h8*)(&Qf[qr * 72 + l4 * 8]);
        qf2[1] = *(const h8*)(&Qf[qr * 72 + 32 + l4 * 8]);
        #pragma unroll
        for (int j = 0; j < 8; ++j) { qf2[0][j] *= (_Float16)0.125f; qf2[1][j] *= (_Float16)0.125f; }
    }

    // ---- rel product: P[q][j] = q_row . RelT[j]   (unscaled q) ----
    f32x4 pacc[4][2];
    #pragma unroll
    for (int i = 0; i < 4; ++i)
        #pragma unroll
        for (int j = 0; j < 2; ++j) pacc[i][j] = (f32x4){0, 0, 0, 0};
    #pragma unroll
    for (int ks = 0; ks < 2; ++ks) {
        h8 b0 = *(const h8*)(smem + AT_RELT + ((w * 2 + 0) * 2 + ks) * 1024 + lane * 16);
        h8 b1 = *(const h8*)(smem + AT_RELT + ((w * 2 + 1) * 2 + ks) * 1024 + lane * 16);
        #pragma unroll
        for (int rt = 0; rt < 4; ++rt) {
            h8 a = *(const h8*)(&Qf[(rt * 16 + l15) * 72 + ks * 32 + l4 * 8]);
            pacc[rt][0] = __builtin_amdgcn_mfma_f32_16x16x32_f16(a, b0, pacc[rt][0], 0, 0, 0);
            pacc[rt][1] = __builtin_amdgcn_mfma_f32_16x16x32_f16(a, b1, pacc[rt][1], 0, 0, 0);
        }
    }

    // ---- K/V prefetch for tile 0 (regs) ----
    const _Float16* kb_ = kh + (size_t)bh * HWN * HD;
    const _Float16* vb_ = vh + (size_t)bh * HWN * HD;
    const int key2 = (t & 31) * 2, dgrp = t >> 5;
    short8 rv0, rv1;
#define LOADV(KT) {                                                            \
        const _Float16* vp = vb_ + (size_t)((KT) * 64 + key2) * HD + dgrp * 8; \
        rv0 = *(const short8*)vp; rv1 = *(const short8*)(vp + HD); }
    short8 kf[8];
#define LOADK(KT) {                                                            \
        _Pragma("unroll")                                                      \
        for (int ct = 0; ct < 4; ++ct)                                         \
            _Pragma("unroll")                                                  \
            for (int ks = 0; ks < 2; ++ks)                                     \
                kf[ct * 2 + ks] = *(const short8*)(kb_ +                       \
                    (size_t)((KT) * 64 + ct * 16 + l15) * HD + ks * 32 + l4 * 8); }
    LOADK(0);
    LOADV(0);

    __syncthreads();   // RelT frag reads done -> Pg region writable
    // ---- stage rel product to LDS (D-layout -> row-major) ----
    _Float16* Pg = (_Float16*)(smem + AT_PG);
    #pragma unroll
    for (int rt = 0; rt < 4; ++rt)
        #pragma unroll
        for (int cb = 0; cb < 2; ++cb)
            #pragma unroll
            for (int reg = 0; reg < 4; ++reg)
                Pg[(rt * 16 + l4 * 4 + reg) * 130 + w * 32 + cb * 16 + l15] =
                    (_Float16)pacc[rt][cb][reg];
    __syncthreads();

    // ---- gather reversed windows into Rel[q][0..31]=RelH, [32..63]=RelW ----
    {
        const int q = t >> 2, kk0 = (t & 3) * 8;
        const int hw = qb * 64 + q;
        const int hq = hw >> 5, wq = hw & 31;
        short8 vh_, vw_;
        #pragma unroll
        for (int j = 0; j < 8; ++j) {
            const int kk = kk0 + j;
            vh_[j] = *(const short*)&Pg[q * 130 + (hq + 31 - kk)];
            vw_[j] = *(const short*)&Pg[q * 130 + 64 + (wq + 31 - kk)];
        }
        *(short8*)(&Rel[q * 68 + kk0])      = vh_;
        *(short8*)(&Rel[q * 68 + 32 + kk0]) = vw_;
    }
    __syncthreads();   // Rel ready; Qf/RelT/Pg regions now free (VT usable)

    // ---- hoisted RelW biases (kt-invariant), q = w*16 + l15 ----
    const int qrow_bias = w * 16 + l15;
    float rw_[2][4];
    #pragma unroll
    for (int c2 = 0; c2 < 2; ++c2)
        #pragma unroll
        for (int reg = 0; reg < 4; ++reg)
            rw_[c2][reg] = (float)Rel[qrow_bias * 68 + 32 + c2 * 16 + l4 * 4 + reg];

#define WRITEVT(BUF) {                                                         \
        _Pragma("unroll")                                                      \
        for (int j = 0; j < 8; ++j) {                                          \
            const int d = dgrp * 8 + j;                                        \
            unsigned pk = ((unsigned short)rv0[j]) |                           \
                          (((unsigned)(unsigned short)rv1[j]) << 16);          \
            *(unsigned*)(smem + AT_VT + (BUF) * 8192 + d * 128 +               \
                         ((key2 * 2) ^ ((d & 7) << 4))) = pk; } }
    WRITEVT(0);

    f32x4 acc_o[4] = {{0,0,0,0},{0,0,0,0},{0,0,0,0},{0,0,0,0}};
    float m_ = -INFINITY, l_ = 0.f;
    char* Pw = smem + AT_P + w * 2048;
    const int swzP = (l15 & 7) << 4;

    for (int kt = 0; kt < 16; ++kt) {
        const int cur = kt & 1;
        __syncthreads();                 // VT[cur] writes visible
        if (kt < 15) LOADV(kt + 1);

        // ---- QK^T swapped: D[key][q], C-init = rel bias ----
        const float rh0 = (float)Rel[qrow_bias * 68 + kt * 2];
        const float rh1 = (float)Rel[qrow_bias * 68 + kt * 2 + 1];
        f32x4 accs[4];
        #pragma unroll
        for (int ct = 0; ct < 4; ++ct) {
            const float rhc = (ct >> 1) ? rh1 : rh0;
            #pragma unroll
            for (int reg = 0; reg < 4; ++reg)
                accs[ct][reg] = rw_[ct & 1][reg] + rhc;
        }
        __builtin_amdgcn_s_setprio(1);
        #pragma unroll
        for (int ct = 0; ct < 4; ++ct)
            #pragma unroll
            for (int ks = 0; ks < 2; ++ks)
                accs[ct] = __builtin_amdgcn_mfma_f32_16x16x32_f16(
                    *(const h8*)&kf[ct * 2 + ks], qf2[ks], accs[ct], 0, 0, 0);
        __builtin_amdgcn_s_setprio(0);
        if (kt < 15) LOADK(kt + 1);

        // ---- lane-local online softmax (q = w*16 + l15) ----
        float tmax = -INFINITY;
        #pragma unroll
        for (int ct = 0; ct < 4; ++ct)
            #pragma unroll
            for (int reg = 0; reg < 4; ++reg)
                tmax = fmaxf(tmax, accs[ct][reg]);
        tmax = fmaxf(tmax, __shfl_xor(tmax, 16));
        tmax = fmaxf(tmax, __shfl_xor(tmax, 32));

        if (__any(tmax > m_ + 8.f)) {
            const float mnew = fmaxf(m_, tmax);
            const float factor = __expf(m_ - mnew);
            m_ = mnew;
            l_ *= factor;
            #pragma unroll
            for (int reg = 0; reg < 4; ++reg) {
                const float fr = __shfl(factor, l4 * 4 + reg);
                #pragma unroll
                for (int dt = 0; dt < 4; ++dt) acc_o[dt][reg] *= fr;
            }
        }

        float tsum = 0.f;
        #pragma unroll
        for (int ct = 0; ct < 4; ++ct) {
            float p0 = __expf(accs[ct][0] - m_);
            float p1 = __expf(accs[ct][1] - m_);
            float p2 = __expf(accs[ct][2] - m_);
            float p3 = __expf(accs[ct][3] - m_);
            tsum += (p0 + p1) + (p2 + p3);
            h2 pa = {(_Float16)p0, (_Float16)p1};
            h2 pb = {(_Float16)p2, (_Float16)p3};
            uint2 pk;
            pk.x = *(unsigned*)&pa;
            pk.y = *(unsigned*)&pb;
            *(uint2*)(Pw + l15 * 128 + ((ct * 32 + l4 * 8) ^ swzP)) = pk;
        }
        tsum += __shfl_xor(tsum, 16);
        tsum += __shfl_xor(tsum, 32);
        l_ += tsum;

        // ---- PV ----
        __builtin_amdgcn_s_setprio(1);
        #pragma unroll
        for (int ks = 0; ks < 2; ++ks) {
            h8 pa = *(const h8*)(Pw + l15 * 128 + ((ks * 64 + l4 * 16) ^ swzP));
            #pragma unroll
            for (int dt = 0; dt < 4; ++dt) {
                const int d = dt * 16 + l15;
                h8 vf = *(const h8*)(smem + AT_VT + cur * 8192 + d * 128 +
                                     ((ks * 64 + l4 * 16) ^ ((d & 7) << 4)));
                acc_o[dt] = __builtin_amdgcn_mfma_f32_16x16x32_f16(pa, vf, acc_o[dt], 0, 0, 0);
            }
        }
        __builtin_amdgcn_s_setprio(0);

        if (kt < 15) WRITEVT(cur ^ 1);
    }

    // ---- epilogue ----
    const float invl = 1.0f / l_;
    float linv[4];
    #pragma unroll
    for (int reg = 0; reg < 4; ++reg) linv[reg] = __shfl(invl, l4 * 4 + reg);
    __syncthreads();
    _Float16* Of = (_Float16*)(smem + AT_OF);
    #pragma unroll
    for (int reg = 0; reg < 4; ++reg) {
        const int qloc = w * 16 + l4 * 4 + reg;
        #pragma unroll
        for (int dt = 0; dt < 4; ++dt)
            Of[qloc * 72 + dt * 16 + l15] = (_Float16)(acc_o[dt][reg] * linv[reg]);
    }
    __syncthreads();
    {
        const int b_ = bh / NH, nh = bh % NH;
        _Float16* op = aout + ((size_t)b_ * HWN + qb * 64 + r) * DIM + nh * HD + dc;
        *(short8*)op       = *(const short8*)(&Of[r * 72 + dc]);
        *(short8*)(op + 8) = *(const short8*)(&Of[r * 72 + dc + 8]);
    }
}

// ---------------------------------------------------------------------------
extern "C" void kernel_launch(void* const* d_in, const int* in_sizes, int n_in,
                              void* d_out, int out_size, void* d_ws, size_t ws_size,
                              hipStream_t stream) {
    const float* q   = (const float*)d_in[0];
    const float* k   = (const float*)d_in[1];
    const float* v   = (const float*)d_in[2];
    const float* Wq  = (const float*)d_in[3];
    const float* bq  = (const float*)d_in[4];
    const float* Wk  = (const float*)d_in[5];
    const float* bk  = (const float*)d_in[6];
    const float* Wv  = (const float*)d_in[7];
    const float* bv  = (const float*)d_in[8];
    const float* Wp  = (const float*)d_in[9];
    const float* bp  = (const float*)d_in[10];
    const float* rph = (const float*)d_in[11];
    const float* rpw = (const float*)d_in[12];

    float* out = (float*)d_out;
    char*  w0  = (char*)d_ws;

    _Float16* wtAll = (_Float16*)(w0);                // 4,718,592
    _Float16* relTg = (_Float16*)(w0 + 4718592);      //    16,384
    _Float16* qf16  = (_Float16*)(w0 + 4734976);      // 6,291,456
    _Float16* kf16  = (_Float16*)(w0 + 11026432);     // 6,291,456
    _Float16* vf16  = (_Float16*)(w0 + 17317888);     // 6,291,456
    _Float16* aout  = (_Float16*)(w0 + 23609344);     // 6,291,456 -> 29,900,800

    dim3 blk(256);
    wconv_kernel<<<dim3(12, 12, 4), blk, 0, stream>>>(Wq, Wk, Wv, Wp, wtAll);
    rel2frag_kernel<<<1, blk, 0, stream>>>(rph, rpw, relTg);
    gemm_mfma_kernel<0><<<1152, blk, 0, stream>>>(
        q, k, v, wtAll, bq, bk, bv, qf16, kf16, vf16);
    attn_kernel<<<dim3(16, 48), blk, 0, stream>>>(qf16, kf16, vf16, relTg, aout);
    gemm_mfma_kernel<1><<<384, blk, 0, stream>>>(
        aout, nullptr, nullptr, wtAll, bp, nullptr, nullptr,
        out, nullptr, nullptr);
}

// Round 8
// 127.708 us; speedup vs baseline: 6.2928x; 1.0101x over previous
//
#include <hip/hip_runtime.h>
#include <math.h>

#define DIM  768
#define NH   12
#define HD   64
#define HWN  1024
#define MROWS 4096

typedef __attribute__((ext_vector_type(8))) short short8;
typedef __attribute__((ext_vector_type(4))) float f32x4;
typedef _Float16 h8 __attribute__((ext_vector_type(8)));
typedef _Float16 h2 __attribute__((ext_vector_type(2)));

__device__ __forceinline__ void gl_lds16(const void* g, void* l) {
    __builtin_amdgcn_global_load_lds(
        (const __attribute__((address_space(1))) void*)g,
        (__attribute__((address_space(3))) void*)l, 16, 0, 0);
}

// ---------------------------------------------------------------------------
// W (768x768 k-major fp32) -> Wt fp16 (n-major). z selects Wq/Wk/Wv/Wp.
// ---------------------------------------------------------------------------
__global__ __launch_bounds__(256) void wconv_kernel(
    const float* __restrict__ Wq, const float* __restrict__ Wk,
    const float* __restrict__ Wv, const float* __restrict__ Wp,
    _Float16* __restrict__ WtAll)
{
    __shared__ float Ws[64][65];
    const int z = blockIdx.z;
    const float* W = (z == 0) ? Wq : (z == 1) ? Wk : (z == 2) ? Wv : Wp;
    _Float16* Wt = WtAll + (size_t)z * 589824;

    const int k0 = blockIdx.y * 64, n0 = blockIdx.x * 64;
    const int t = threadIdx.x;
    {
        int r = t >> 2, c4 = (t & 3) * 16;
        #pragma unroll
        for (int u = 0; u < 16; u += 4)
            *(float4*)&Ws[r][c4 + u] = *(const float4*)(W + (size_t)(k0 + r) * DIM + n0 + c4 + u);
    }
    __syncthreads();
    const int n = t >> 2, kseg = (t & 3) * 16;
    h8 h0, h1;
    #pragma unroll
    for (int j = 0; j < 8; ++j) {
        h0[j] = (_Float16)Ws[kseg + j][n];
        h1[j] = (_Float16)Ws[kseg + 8 + j][n];
    }
    size_t base = (size_t)(n0 + n) * DIM + k0 + kseg;
    *(h8*)(Wt + base) = h0;
    *(h8*)(Wt + base + 8) = h1;
}

// ---------------------------------------------------------------------------
// Pack [rel_pos_h(63x64) ; pad ; rel_pos_w(63x64) ; pad] -> fp16 n-major
// ---------------------------------------------------------------------------
__global__ __launch_bounds__(256) void rel2frag_kernel(
    const float* __restrict__ rph, const float* __restrict__ rpw,
    _Float16* __restrict__ relTg)
{
    const int t = threadIdx.x;
    const int row = t >> 1, c0 = (t & 1) * 32;
    const float* src = (row < 63) ? rph + (size_t)row * HD
                     : (row >= 64 && row < 127) ? rpw + (size_t)(row - 64) * HD
                     : nullptr;
    #pragma unroll
    for (int g = 0; g < 4; ++g) {
        h8 o;
        #pragma unroll
        for (int j = 0; j < 8; ++j)
            o[j] = src ? (_Float16)src[c0 + g * 8 + j] : (_Float16)0.0f;
        *(h8*)(relTg + (size_t)row * HD + c0 + g * 8) = o;
    }
}

// ---------------------------------------------------------------------------
// fp16 1-term MFMA GEMM. A staged raw via global_load_lds, cvt in-reg.
// ---------------------------------------------------------------------------
template<int AMODE>
__global__ __launch_bounds__(256, 3) void gemm_mfma_kernel(
    const void* __restrict__ X0, const void* __restrict__ X1,
    const void* __restrict__ X2, const _Float16* __restrict__ WtAll,
    const float* __restrict__ bias0, const float* __restrict__ bias1,
    const float* __restrict__ bias2,
    void* __restrict__ Y0, void* __restrict__ Y1, void* __restrict__ Y2)
{
    __shared__ __align__(16) char smem[AMODE == 0 ? 40960 : 24576];
    const int BOFF = (AMODE == 0) ? 32768 : 16384;
    const int t = threadIdx.x;
    const int w = t >> 6, lane = t & 63;
    const int l15 = lane & 15, l4 = lane >> 4;

    int sel, rem;
    if (AMODE == 0) {
        const int sw = (blockIdx.x & 7) * 144 + (blockIdx.x >> 3);
        sel = sw / 384; rem = sw - sel * 384;
    } else {
        const int sw = (blockIdx.x & 7) * 48 + (blockIdx.x >> 3);
        sel = 3; rem = sw;
    }
    const int rb = rem / 12, cb = rem - rb * 12;
    const int row0 = rb * 128, col0 = cb * 64;

    const char* Ab = (const char*)((AMODE == 1 || sel == 0) ? X0 : (sel == 1) ? X1 : X2);
    const _Float16* Bt = WtAll + (size_t)sel * 589824;
    const float* bias = (AMODE == 1) ? bias0 : (sel == 0) ? bias0 : (sel == 1) ? bias1 : bias2;

    f32x4 acc[4][2];
    #pragma unroll
    for (int i = 0; i < 4; ++i)
        #pragma unroll
        for (int j = 0; j < 2; ++j) acc[i][j] = (f32x4){0, 0, 0, 0};

    for (int kt = 0; kt < 12; ++kt) {
        if (AMODE == 0) {
            #pragma unroll
            for (int i = 0; i < 8; ++i) {
                const int fi = w * 8 + i;
                const int row = fi * 4 + (lane >> 4);
                const int real = ((lane & 15) * 16) ^ ((row & 7) << 5);
                gl_lds16(Ab + (size_t)(row0 + row) * 3072 + kt * 256 + real, smem + fi * 1024);
            }
        } else {
            #pragma unroll
            for (int i = 0; i < 4; ++i) {
                const int fi = w * 4 + i;
                const int row = fi * 8 + (lane >> 3);
                const int real = ((lane & 7) * 16) ^ ((row & 7) << 4);
                gl_lds16(Ab + (size_t)(row0 + row) * 1536 + kt * 128 + real, smem + fi * 1024);
            }
        }
        #pragma unroll
        for (int it = 0; it < 2; ++it) {
            const int f = it * 4 + w;
            const int ks = f >> 2, cf = f & 3;
            const size_t off = (size_t)(col0 + cf * 16 + l15) * 1536 + kt * 128 + ks * 64 + l4 * 16;
            gl_lds16((const char*)Bt + off, smem + BOFF + f * 1024);
        }
        __syncthreads();

        __builtin_amdgcn_s_setprio(1);
        #pragma unroll
        for (int ks = 0; ks < 2; ++ks) {
            const int fb = ks * 4 + (w & 1) * 2;
            h8 b0 = *(const h8*)(smem + BOFF + (fb    ) * 1024 + lane * 16);
            h8 b1 = *(const h8*)(smem + BOFF + (fb + 1) * 1024 + lane * 16);
            #pragma unroll
            for (int rf = 0; rf < 4; ++rf) {
                const int arow = (w >> 1) * 64 + rf * 16 + l15;
                h8 ah;
                if (AMODE == 0) {
                    const int base = arow * 256 + ((ks * 128 + l4 * 32) ^ ((arow & 7) << 5));
                    f32x4 a0 = *(const f32x4*)(smem + base);
                    f32x4 a1 = *(const f32x4*)(smem + base + 16);
                    ah[0] = (_Float16)a0[0]; ah[1] = (_Float16)a0[1];
                    ah[2] = (_Float16)a0[2]; ah[3] = (_Float16)a0[3];
                    ah[4] = (_Float16)a1[0]; ah[5] = (_Float16)a1[1];
                    ah[6] = (_Float16)a1[2]; ah[7] = (_Float16)a1[3];
                } else {
                    const int base = arow * 128 + ((ks * 64 + l4 * 16) ^ ((arow & 7) << 4));
                    ah = *(const h8*)(smem + base);
                }
                acc[rf][0] = __builtin_amdgcn_mfma_f32_16x16x32_f16(ah, b0, acc[rf][0], 0, 0, 0);
                acc[rf][1] = __builtin_amdgcn_mfma_f32_16x16x32_f16(ah, b1, acc[rf][1], 0, 0, 0);
            }
        }
        __builtin_amdgcn_s_setprio(0);
        __syncthreads();
    }

    const int wrow0 = row0 + (w >> 1) * 64;
    const int wcol0 = col0 + (w & 1) * 32;
    #pragma unroll
    for (int cf = 0; cf < 2; ++cf) {
        const int c = wcol0 + cf * 16 + l15;
        const float bb = bias[c];
        #pragma unroll
        for (int rf = 0; rf < 4; ++rf) {
            #pragma unroll
            for (int reg = 0; reg < 4; ++reg) {
                const int r = wrow0 + rf * 16 + l4 * 4 + reg;
                float y = acc[rf][cf][reg] + bb;
                if (AMODE == 1) {
                    ((float*)Y0)[(size_t)r * DIM + c] = y;
                } else {
                    _Float16* Yh = (_Float16*)((sel == 0) ? Y0 : (sel == 1) ? Y1 : Y2);
                    size_t base = ((size_t)((r >> 10) * NH + cb) * HWN + (r & 1023)) * HD + (c - col0);
                    Yh[base] = (_Float16)y;
                }
            }
        }
    }
}

// ---------------------------------------------------------------------------
// fp16 MFMA fused attention. R8: (1) XCD-aware block swizzle — each XCD owns
// 6 whole heads so KV is fetched into its L2 once; (2) 2-deep kt pipeline —
// QK(kt+1) MFMAs issue before softmax(kt) VALU (MFMA || VALU overlap).
// ---------------------------------------------------------------------------
#define AT_REL   0        // 64*68*2 = 8704
#define AT_VT    8704     // 2 x 8192 -> 25088
#define AT_P     25088    // 4 x 2048 -> 33280
#define AT_QF    8704     // prologue overlay
#define AT_RELT  17920    // prologue overlay
#define AT_PG    17920    // prologue overlay
#define AT_OF    8704     // epilogue overlay
#define AT_TOTAL 34560

__global__ __launch_bounds__(256, 3) void attn_kernel(
    const _Float16* __restrict__ qh, const _Float16* __restrict__ kh,
    const _Float16* __restrict__ vh, const _Float16* __restrict__ relTg,
    _Float16* __restrict__ aout)
{
    __shared__ __align__(16) char smem[AT_TOTAL];
    // XCD swizzle: 768 blocks, xcd = bid&7 (round-robin dispatch), 96 per XCD
    // = 6 heads x 16 q-blocks. All q-blocks of one head share an XCD/L2.
    const int bid = blockIdx.x;
    const int j   = bid >> 3;
    const int bh  = (bid & 7) * 6 + (j >> 4);   // 0..47
    const int qb  = j & 15;                     // 0..15
    const int t  = threadIdx.x;
    const int w  = t >> 6;
    const int lane = t & 63;
    const int l15 = lane & 15, l4 = lane >> 4;

    _Float16* Rel = (_Float16*)(smem + AT_REL);
    _Float16* Qf  = (_Float16*)(smem + AT_QF);

    const int r = t >> 2, dc = (t & 3) * 16;
    // ---- stage Q tile (fp16) + RelT frags ----
    {
        const _Float16* qp = qh + ((size_t)bh * HWN + qb * 64 + r) * HD + dc;
        *(short8*)(&Qf[r * 72 + dc])     = *(const short8*)(qp);
        *(short8*)(&Qf[r * 72 + dc + 8]) = *(const short8*)(qp + 8);
        #pragma unroll
        for (int it = 0; it < 4; ++it) {
            const int f = it * 4 + w;
            const int ct = f >> 1, ks = f & 1;
            gl_lds16((const char*)relTg + (ct * 16 + l15) * 128 + ks * 64 + l4 * 16,
                     smem + AT_RELT + f * 1024);
        }
    }
    __syncthreads();

    // ---- Q fragments (B-operand), pre-scaled by 1/8 ----
    h8 qf2[2];
    {
        const int qr = w * 16 + l15;
        qf2[0] = *(const h8*)(&Qf[qr * 72 + l4 * 8]);
        qf2[1] = *(const h8*)(&Qf[qr * 72 + 32 + l4 * 8]);
        #pragma unroll
        for (int j2 = 0; j2 < 8; ++j2) { qf2[0][j2] *= (_Float16)0.125f; qf2[1][j2] *= (_Float16)0.125f; }
    }

    // ---- rel product via MFMA ----
    f32x4 pacc[4][2];
    #pragma unroll
    for (int i = 0; i < 4; ++i)
        #pragma unroll
        for (int j2 = 0; j2 < 2; ++j2) pacc[i][j2] = (f32x4){0, 0, 0, 0};
    #pragma unroll
    for (int ks = 0; ks < 2; ++ks) {
        h8 b0 = *(const h8*)(smem + AT_RELT + ((w * 2 + 0) * 2 + ks) * 1024 + lane * 16);
        h8 b1 = *(const h8*)(smem + AT_RELT + ((w * 2 + 1) * 2 + ks) * 1024 + lane * 16);
        #pragma unroll
        for (int rt = 0; rt < 4; ++rt) {
            h8 a = *(const h8*)(&Qf[(rt * 16 + l15) * 72 + ks * 32 + l4 * 8]);
            pacc[rt][0] = __builtin_amdgcn_mfma_f32_16x16x32_f16(a, b0, pacc[rt][0], 0, 0, 0);
            pacc[rt][1] = __builtin_amdgcn_mfma_f32_16x16x32_f16(a, b1, pacc[rt][1], 0, 0, 0);
        }
    }

    // ---- K/V prefetch regs ----
    const _Float16* kb_ = kh + (size_t)bh * HWN * HD;
    const _Float16* vb_ = vh + (size_t)bh * HWN * HD;
    const int key2 = (t & 31) * 2, dgrp = t >> 5;
    short8 rv0, rv1;
#define LOADV(KT) {                                                            \
        const _Float16* vp = vb_ + (size_t)((KT) * 64 + key2) * HD + dgrp * 8; \
        rv0 = *(const short8*)vp; rv1 = *(const short8*)(vp + HD); }
    short8 kfa[8], kfb[8];
#define LOADK(KT, KF) {                                                        \
        _Pragma("unroll")                                                      \
        for (int ct = 0; ct < 4; ++ct)                                         \
            _Pragma("unroll")                                                  \
            for (int ks = 0; ks < 2; ++ks)                                     \
                KF[ct * 2 + ks] = *(const short8*)(kb_ +                       \
                    (size_t)((KT) * 64 + ct * 16 + l15) * HD + ks * 32 + l4 * 8); }
    LOADK(0, kfa);
    LOADV(0);

    __syncthreads();
    _Float16* Pg = (_Float16*)(smem + AT_PG);
    #pragma unroll
    for (int rt = 0; rt < 4; ++rt)
        #pragma unroll
        for (int cb2 = 0; cb2 < 2; ++cb2)
            #pragma unroll
            for (int reg = 0; reg < 4; ++reg)
                Pg[(rt * 16 + l4 * 4 + reg) * 130 + w * 32 + cb2 * 16 + l15] =
                    (_Float16)pacc[rt][cb2][reg];
    __syncthreads();

    {
        const int q = t >> 2, kk0 = (t & 3) * 8;
        const int hw = qb * 64 + q;
        const int hq = hw >> 5, wq = hw & 31;
        short8 vh_, vw_;
        #pragma unroll
        for (int j2 = 0; j2 < 8; ++j2) {
            const int kk = kk0 + j2;
            vh_[j2] = *(const short*)&Pg[q * 130 + (hq + 31 - kk)];
            vw_[j2] = *(const short*)&Pg[q * 130 + 64 + (wq + 31 - kk)];
        }
        *(short8*)(&Rel[q * 68 + kk0])      = vh_;
        *(short8*)(&Rel[q * 68 + 32 + kk0]) = vw_;
    }
    __syncthreads();

    const int qrow_bias = w * 16 + l15;
    float rw_[2][4];
    #pragma unroll
    for (int c2 = 0; c2 < 2; ++c2)
        #pragma unroll
        for (int reg = 0; reg < 4; ++reg)
            rw_[c2][reg] = (float)Rel[qrow_bias * 68 + 32 + c2 * 16 + l4 * 4 + reg];

#define WRITEVT(BUF) {                                                         \
        _Pragma("unroll")                                                      \
        for (int j2 = 0; j2 < 8; ++j2) {                                       \
            const int d = dgrp * 8 + j2;                                       \
            unsigned pk = ((unsigned short)rv0[j2]) |                          \
                          (((unsigned)(unsigned short)rv1[j2]) << 16);         \
            *(unsigned*)(smem + AT_VT + (BUF) * 8192 + d * 128 +               \
                         ((key2 * 2) ^ ((d & 7) << 4))) = pk; } }
    WRITEVT(0);

    f32x4 acc_o[4] = {{0,0,0,0},{0,0,0,0},{0,0,0,0},{0,0,0,0}};
    float m_ = -INFINITY, l_ = 0.f;
    char* Pw = smem + AT_P + w * 2048;
    const int swzP = (l15 & 7) << 4;

    // QK with bias C-init into named acc
#define QK(KT, KF, ACC) {                                                      \
        const float rh0 = (float)Rel[qrow_bias * 68 + (KT) * 2];               \
        const float rh1 = (float)Rel[qrow_bias * 68 + (KT) * 2 + 1];           \
        _Pragma("unroll")                                                      \
        for (int ct = 0; ct < 4; ++ct) {                                       \
            const float rhc = (ct >> 1) ? rh1 : rh0;                           \
            _Pragma("unroll")                                                  \
            for (int reg = 0; reg < 4; ++reg)                                  \
                ACC[ct][reg] = rw_[ct & 1][reg] + rhc;                         \
        }                                                                      \
        __builtin_amdgcn_s_setprio(1);                                         \
        _Pragma("unroll")                                                      \
        for (int ct = 0; ct < 4; ++ct)                                         \
            _Pragma("unroll")                                                  \
            for (int ks = 0; ks < 2; ++ks)                                     \
                ACC[ct] = __builtin_amdgcn_mfma_f32_16x16x32_f16(              \
                    *(const h8*)&KF[ct * 2 + ks], qf2[ks], ACC[ct], 0, 0, 0);  \
        __builtin_amdgcn_s_setprio(0); }

    f32x4 accA[4], accB[4];
    QK(0, kfa, accA);          // prologue: scores for tile 0
    LOADK(1, kfb);

    // One pipeline stage: ACC_C holds scores(KT); KFN holds K(KT+1);
    // LOADK(KT+2)->KFO. QK(KT+1) issues BEFORE softmax(KT).
#define ITER(KT, KFN, KFO, ACC_C, ACC_N) {                                     \
        const int cur = (KT) & 1;                                              \
        __syncthreads();                         /* VT[cur] ready */           \
        if ((KT) < 15) LOADV((KT) + 1);                                        \
        if ((KT) < 15) QK((KT) + 1, KFN, ACC_N);                               \
        if ((KT) < 14) LOADK((KT) + 2, KFO);                                   \
        float tmax = -INFINITY;                                                \
        _Pragma("unroll")                                                      \
        for (int ct = 0; ct < 4; ++ct)                                         \
            _Pragma("unroll")                                                  \
            for (int reg = 0; reg < 4; ++reg)                                  \
                tmax = fmaxf(tmax, ACC_C[ct][reg]);                            \
        tmax = fmaxf(tmax, __shfl_xor(tmax, 16));                              \
        tmax = fmaxf(tmax, __shfl_xor(tmax, 32));                              \
        if (__any(tmax > m_ + 8.f)) {                                          \
            const float mnew = fmaxf(m_, tmax);                                \
            const float factor = __expf(m_ - mnew);                            \
            m_ = mnew;                                                         \
            l_ *= factor;                                                      \
            _Pragma("unroll")                                                  \
            for (int reg = 0; reg < 4; ++reg) {                                \
                const float fr = __shfl(factor, l4 * 4 + reg);                 \
                _Pragma("unroll")                                              \
                for (int dt = 0; dt < 4; ++dt) acc_o[dt][reg] *= fr;           \
            }                                                                  \
        }                                                                      \
        float tsum = 0.f;                                                      \
        _Pragma("unroll")                                                      \
        for (int ct = 0; ct < 4; ++ct) {                                       \
            float p0 = __expf(ACC_C[ct][0] - m_);                              \
            float p1 = __expf(ACC_C[ct][1] - m_);                              \
            float p2 = __expf(ACC_C[ct][2] - m_);                              \
            float p3 = __expf(ACC_C[ct][3] - m_);                              \
            tsum += (p0 + p1) + (p2 + p3);                                     \
            h2 pa = {(_Float16)p0, (_Float16)p1};                              \
            h2 pb = {(_Float16)p2, (_Float16)p3};                              \
            uint2 pk;                                                          \
            pk.x = *(unsigned*)&pa;                                            \
            pk.y = *(unsigned*)&pb;                                            \
            *(uint2*)(Pw + l15 * 128 + ((ct * 32 + l4 * 8) ^ swzP)) = pk;      \
        }                                                                      \
        tsum += __shfl_xor(tsum, 16);                                          \
        tsum += __shfl_xor(tsum, 32);                                          \
        l_ += tsum;                                                            \
        __builtin_amdgcn_s_setprio(1);                                         \
        _Pragma("unroll")                                                      \
        for (int ks = 0; ks < 2; ++ks) {                                       \
            h8 pa = *(const h8*)(Pw + l15 * 128 + ((ks * 64 + l4 * 16) ^ swzP)); \
            _Pragma("unroll")                                                  \
            for (int dt = 0; dt < 4; ++dt) {                                   \
                const int d = dt * 16 + l15;                                   \
                h8 vf = *(const h8*)(smem + AT_VT + cur * 8192 + d * 128 +     \
                                     ((ks * 64 + l4 * 16) ^ ((d & 7) << 4)));  \
                acc_o[dt] = __builtin_amdgcn_mfma_f32_16x16x32_f16(pa, vf, acc_o[dt], 0, 0, 0); \
            }                                                                  \
        }                                                                      \
        __builtin_amdgcn_s_setprio(0);                                         \
        if ((KT) < 15) WRITEVT(cur ^ 1); }

    #pragma unroll
    for (int kt = 0; kt < 16; kt += 2) {
        ITER(kt,     kfb, kfa, accA, accB);
        ITER(kt + 1, kfa, kfb, accB, accA);
    }

    // ---- epilogue ----
    const float invl = 1.0f / l_;
    float linv[4];
    #pragma unroll
    for (int reg = 0; reg < 4; ++reg) linv[reg] = __shfl(invl, l4 * 4 + reg);
    __syncthreads();
    _Float16* Of = (_Float16*)(smem + AT_OF);
    #pragma unroll
    for (int reg = 0; reg < 4; ++reg) {
        const int qloc = w * 16 + l4 * 4 + reg;
        #pragma unroll
        for (int dt = 0; dt < 4; ++dt)
            Of[qloc * 72 + dt * 16 + l15] = (_Float16)(acc_o[dt][reg] * linv[reg]);
    }
    __syncthreads();
    {
        const int b_ = bh / NH, nh = bh % NH;
        _Float16* op = aout + ((size_t)b_ * HWN + qb * 64 + r) * DIM + nh * HD + dc;
        *(short8*)op       = *(const short8*)(&Of[r * 72 + dc]);
        *(short8*)(op + 8) = *(const short8*)(&Of[r * 72 + dc + 8]);
    }
}

// ---------------------------------------------------------------------------
extern "C" void kernel_launch(void* const* d_in, const int* in_sizes, int n_in,
                              void* d_out, int out_size, void* d_ws, size_t ws_size,
                              hipStream_t stream) {
    const float* q   = (const float*)d_in[0];
    const float* k   = (const float*)d_in[1];
    const float* v   = (const float*)d_in[2];
    const float* Wq  = (const float*)d_in[3];
    const float* bq  = (const float*)d_in[4];
    const float* Wk  = (const float*)d_in[5];
    const float* bk  = (const float*)d_in[6];
    const float* Wv  = (const float*)d_in[7];
    const float* bv  = (const float*)d_in[8];
    const float* Wp  = (const float*)d_in[9];
    const float* bp  = (const float*)d_in[10];
    const float* rph = (const float*)d_in[11];
    const float* rpw = (const float*)d_in[12];

    float* out = (float*)d_out;
    char*  w0  = (char*)d_ws;

    _Float16* wtAll = (_Float16*)(w0);                // 4,718,592
    _Float16* relTg = (_Float16*)(w0 + 4718592);      //    16,384
    _Float16* qf16  = (_Float16*)(w0 + 4734976);      // 6,291,456
    _Float16* kf16  = (_Float16*)(w0 + 11026432);     // 6,291,456
    _Float16* vf16  = (_Float16*)(w0 + 17317888);     // 6,291,456
    _Float16* aout  = (_Float16*)(w0 + 23609344);     // 6,291,456 -> 29,900,800

    dim3 blk(256);
    wconv_kernel<<<dim3(12, 12, 4), blk, 0, stream>>>(Wq, Wk, Wv, Wp, wtAll);
    rel2frag_kernel<<<1, blk, 0, stream>>>(rph, rpw, relTg);
    gemm_mfma_kernel<0><<<1152, blk, 0, stream>>>(
        q, k, v, wtAll, bq, bk, bv, qf16, kf16, vf16);
    attn_kernel<<<768, blk, 0, stream>>>(qf16, kf16, vf16, relTg, aout);
    gemm_mfma_kernel<1><<<384, blk, 0, stream>>>(
        aout, nullptr, nullptr, wtAll, bp, nullptr, nullptr,
        out, nullptr, nullptr);
}

// Round 9
// 101.530 us; speedup vs baseline: 7.9153x; 1.2578x over previous
//
#include <hip/hip_runtime.h>
#include <math.h>

#define DIM  768
#define NH   12
#define HD   64
#define HWN  1024
#define MROWS 4096

typedef __attribute__((ext_vector_type(8))) short short8;
typedef __attribute__((ext_vector_type(4))) float f32x4;
typedef _Float16 h8 __attribute__((ext_vector_type(8)));
typedef _Float16 h2 __attribute__((ext_vector_type(2)));

__device__ __forceinline__ void gl_lds16(const void* g, void* l) {
    __builtin_amdgcn_global_load_lds(
        (const __attribute__((address_space(1))) void*)g,
        (__attribute__((address_space(3))) void*)l, 16, 0, 0);
}

// ---------------------------------------------------------------------------
// W (768x768 k-major fp32) -> Wt fp16 (n-major). z selects Wq/Wk/Wv/Wp.
// ---------------------------------------------------------------------------
__global__ __launch_bounds__(256) void wconv_kernel(
    const float* __restrict__ Wq, const float* __restrict__ Wk,
    const float* __restrict__ Wv, const float* __restrict__ Wp,
    _Float16* __restrict__ WtAll)
{
    __shared__ float Ws[64][65];
    const int z = blockIdx.z;
    const float* W = (z == 0) ? Wq : (z == 1) ? Wk : (z == 2) ? Wv : Wp;
    _Float16* Wt = WtAll + (size_t)z * 589824;

    const int k0 = blockIdx.y * 64, n0 = blockIdx.x * 64;
    const int t = threadIdx.x;
    {
        int r = t >> 2, c4 = (t & 3) * 16;
        #pragma unroll
        for (int u = 0; u < 16; u += 4)
            *(float4*)&Ws[r][c4 + u] = *(const float4*)(W + (size_t)(k0 + r) * DIM + n0 + c4 + u);
    }
    __syncthreads();
    const int n = t >> 2, kseg = (t & 3) * 16;
    h8 h0, h1;
    #pragma unroll
    for (int j = 0; j < 8; ++j) {
        h0[j] = (_Float16)Ws[kseg + j][n];
        h1[j] = (_Float16)Ws[kseg + 8 + j][n];
    }
    size_t base = (size_t)(n0 + n) * DIM + k0 + kseg;
    *(h8*)(Wt + base) = h0;
    *(h8*)(Wt + base + 8) = h1;
}

// ---------------------------------------------------------------------------
// Pack [rel_pos_h(63x64) ; pad ; rel_pos_w(63x64) ; pad] -> fp16 n-major
// ---------------------------------------------------------------------------
__global__ __launch_bounds__(256) void rel2frag_kernel(
    const float* __restrict__ rph, const float* __restrict__ rpw,
    _Float16* __restrict__ relTg)
{
    const int t = threadIdx.x;
    const int row = t >> 1, c0 = (t & 1) * 32;
    const float* src = (row < 63) ? rph + (size_t)row * HD
                     : (row >= 64 && row < 127) ? rpw + (size_t)(row - 64) * HD
                     : nullptr;
    #pragma unroll
    for (int g = 0; g < 4; ++g) {
        h8 o;
        #pragma unroll
        for (int j = 0; j < 8; ++j)
            o[j] = src ? (_Float16)src[c0 + g * 8 + j] : (_Float16)0.0f;
        *(h8*)(relTg + (size_t)row * HD + c0 + g * 8) = o;
    }
}

// ---------------------------------------------------------------------------
// fp16 1-term MFMA GEMM. A staged raw via global_load_lds, cvt in-reg.
// ---------------------------------------------------------------------------
template<int AMODE>
__global__ __launch_bounds__(256, 3) void gemm_mfma_kernel(
    const void* __restrict__ X0, const void* __restrict__ X1,
    const void* __restrict__ X2, const _Float16* __restrict__ WtAll,
    const float* __restrict__ bias0, const float* __restrict__ bias1,
    const float* __restrict__ bias2,
    void* __restrict__ Y0, void* __restrict__ Y1, void* __restrict__ Y2)
{
    __shared__ __align__(16) char smem[AMODE == 0 ? 40960 : 24576];
    const int BOFF = (AMODE == 0) ? 32768 : 16384;
    const int t = threadIdx.x;
    const int w = t >> 6, lane = t & 63;
    const int l15 = lane & 15, l4 = lane >> 4;

    int sel, rem;
    if (AMODE == 0) {
        const int sw = (blockIdx.x & 7) * 144 + (blockIdx.x >> 3);
        sel = sw / 384; rem = sw - sel * 384;
    } else {
        const int sw = (blockIdx.x & 7) * 48 + (blockIdx.x >> 3);
        sel = 3; rem = sw;
    }
    const int rb = rem / 12, cb = rem - rb * 12;
    const int row0 = rb * 128, col0 = cb * 64;

    const char* Ab = (const char*)((AMODE == 1 || sel == 0) ? X0 : (sel == 1) ? X1 : X2);
    const _Float16* Bt = WtAll + (size_t)sel * 589824;
    const float* bias = (AMODE == 1) ? bias0 : (sel == 0) ? bias0 : (sel == 1) ? bias1 : bias2;

    f32x4 acc[4][2];
    #pragma unroll
    for (int i = 0; i < 4; ++i)
        #pragma unroll
        for (int j = 0; j < 2; ++j) acc[i][j] = (f32x4){0, 0, 0, 0};

    for (int kt = 0; kt < 12; ++kt) {
        if (AMODE == 0) {
            #pragma unroll
            for (int i = 0; i < 8; ++i) {
                const int fi = w * 8 + i;
                const int row = fi * 4 + (lane >> 4);
                const int real = ((lane & 15) * 16) ^ ((row & 7) << 5);
                gl_lds16(Ab + (size_t)(row0 + row) * 3072 + kt * 256 + real, smem + fi * 1024);
            }
        } else {
            #pragma unroll
            for (int i = 0; i < 4; ++i) {
                const int fi = w * 4 + i;
                const int row = fi * 8 + (lane >> 3);
                const int real = ((lane & 7) * 16) ^ ((row & 7) << 4);
                gl_lds16(Ab + (size_t)(row0 + row) * 1536 + kt * 128 + real, smem + fi * 1024);
            }
        }
        #pragma unroll
        for (int it = 0; it < 2; ++it) {
            const int f = it * 4 + w;
            const int ks = f >> 2, cf = f & 3;
            const size_t off = (size_t)(col0 + cf * 16 + l15) * 1536 + kt * 128 + ks * 64 + l4 * 16;
            gl_lds16((const char*)Bt + off, smem + BOFF + f * 1024);
        }
        __syncthreads();

        __builtin_amdgcn_s_setprio(1);
        #pragma unroll
        for (int ks = 0; ks < 2; ++ks) {
            const int fb = ks * 4 + (w & 1) * 2;
            h8 b0 = *(const h8*)(smem + BOFF + (fb    ) * 1024 + lane * 16);
            h8 b1 = *(const h8*)(smem + BOFF + (fb + 1) * 1024 + lane * 16);
            #pragma unroll
            for (int rf = 0; rf < 4; ++rf) {
                const int arow = (w >> 1) * 64 + rf * 16 + l15;
                h8 ah;
                if (AMODE == 0) {
                    const int base = arow * 256 + ((ks * 128 + l4 * 32) ^ ((arow & 7) << 5));
                    f32x4 a0 = *(const f32x4*)(smem + base);
                    f32x4 a1 = *(const f32x4*)(smem + base + 16);
                    ah[0] = (_Float16)a0[0]; ah[1] = (_Float16)a0[1];
                    ah[2] = (_Float16)a0[2]; ah[3] = (_Float16)a0[3];
                    ah[4] = (_Float16)a1[0]; ah[5] = (_Float16)a1[1];
                    ah[6] = (_Float16)a1[2]; ah[7] = (_Float16)a1[3];
                } else {
                    const int base = arow * 128 + ((ks * 64 + l4 * 16) ^ ((arow & 7) << 4));
                    ah = *(const h8*)(smem + base);
                }
                acc[rf][0] = __builtin_amdgcn_mfma_f32_16x16x32_f16(ah, b0, acc[rf][0], 0, 0, 0);
                acc[rf][1] = __builtin_amdgcn_mfma_f32_16x16x32_f16(ah, b1, acc[rf][1], 0, 0, 0);
            }
        }
        __builtin_amdgcn_s_setprio(0);
        __syncthreads();
    }

    const int wrow0 = row0 + (w >> 1) * 64;
    const int wcol0 = col0 + (w & 1) * 32;
    #pragma unroll
    for (int cf = 0; cf < 2; ++cf) {
        const int c = wcol0 + cf * 16 + l15;
        const float bb = bias[c];
        #pragma unroll
        for (int rf = 0; rf < 4; ++rf) {
            #pragma unroll
            for (int reg = 0; reg < 4; ++reg) {
                const int r = wrow0 + rf * 16 + l4 * 4 + reg;
                float y = acc[rf][cf][reg] + bb;
                if (AMODE == 1) {
                    ((float*)Y0)[(size_t)r * DIM + c] = y;
                } else {
                    _Float16* Yh = (_Float16*)((sel == 0) ? Y0 : (sel == 1) ? Y1 : Y2);
                    size_t base = ((size_t)((r >> 10) * NH + cb) * HWN + (r & 1023)) * HD + (c - col0);
                    Yh[base] = (_Float16)y;
                }
            }
        }
    }
}

// ---------------------------------------------------------------------------
// fp16 MFMA fused attention. R9: K staged ONCE per block into LDS via async
// global_load_lds (double-buffered, swizzled) — removes the 4x-redundant
// per-wave global K loads that serialized every iteration on L1/L2 BW.
// ---------------------------------------------------------------------------
#define AT_REL   0        // 8704
#define AT_VT    8704     // 2 x 8192 -> 25088
#define AT_P     25088    // 4 x 2048 -> 33280
#define AT_KB    33280    // 2 x 8192 -> 49664
#define AT_QF    8704     // prologue overlay (dead before WRITEVT(0))
#define AT_RELT  17920    // prologue overlay (dead before STAGEK(0))
#define AT_PG    17920    // prologue overlay (dead before STAGEK(0))
#define AT_OF    8704     // epilogue overlay
#define AT_TOTAL 49664

__global__ __launch_bounds__(256, 3) void attn_kernel(
    const _Float16* __restrict__ qh, const _Float16* __restrict__ kh,
    const _Float16* __restrict__ vh, const _Float16* __restrict__ relTg,
    _Float16* __restrict__ aout)
{
    __shared__ __align__(16) char smem[AT_TOTAL];
    // XCD swizzle: each XCD owns 6 whole heads (KV L2-resident per XCD).
    const int bid = blockIdx.x;
    const int j   = bid >> 3;
    const int bh  = (bid & 7) * 6 + (j >> 4);   // 0..47
    const int qb  = j & 15;                     // 0..15
    const int t  = threadIdx.x;
    const int w  = t >> 6;
    const int lane = t & 63;
    const int l15 = lane & 15, l4 = lane >> 4;

    _Float16* Rel = (_Float16*)(smem + AT_REL);
    _Float16* Qf  = (_Float16*)(smem + AT_QF);

    const int r = t >> 2, dc = (t & 3) * 16;
    // ---- stage Q tile (fp16) + RelT frags ----
    {
        const _Float16* qp = qh + ((size_t)bh * HWN + qb * 64 + r) * HD + dc;
        *(short8*)(&Qf[r * 72 + dc])     = *(const short8*)(qp);
        *(short8*)(&Qf[r * 72 + dc + 8]) = *(const short8*)(qp + 8);
        #pragma unroll
        for (int it = 0; it < 4; ++it) {
            const int f = it * 4 + w;
            const int ct = f >> 1, ks = f & 1;
            gl_lds16((const char*)relTg + (ct * 16 + l15) * 128 + ks * 64 + l4 * 16,
                     smem + AT_RELT + f * 1024);
        }
    }
    __syncthreads();

    // ---- V prefetch regs (tile 0) ----
    const _Float16* kb_ = kh + (size_t)bh * HWN * HD;
    const _Float16* vb_ = vh + (size_t)bh * HWN * HD;
    const int key2 = (t & 31) * 2, dgrp = t >> 5;
    short8 rv0, rv1;
#define LOADV(KT) {                                                            \
        const _Float16* vp = vb_ + (size_t)((KT) * 64 + key2) * HD + dgrp * 8; \
        rv0 = *(const short8*)vp; rv1 = *(const short8*)(vp + HD); }
    LOADV(0);

    // ---- Q fragments (B-operand), pre-scaled by 1/8 ----
    h8 qf2[2];
    {
        const int qr = w * 16 + l15;
        qf2[0] = *(const h8*)(&Qf[qr * 72 + l4 * 8]);
        qf2[1] = *(const h8*)(&Qf[qr * 72 + 32 + l4 * 8]);
        #pragma unroll
        for (int j2 = 0; j2 < 8; ++j2) { qf2[0][j2] *= (_Float16)0.125f; qf2[1][j2] *= (_Float16)0.125f; }
    }

    // ---- rel product via MFMA ----
    f32x4 pacc[4][2];
    #pragma unroll
    for (int i = 0; i < 4; ++i)
        #pragma unroll
        for (int j2 = 0; j2 < 2; ++j2) pacc[i][j2] = (f32x4){0, 0, 0, 0};
    #pragma unroll
    for (int ks = 0; ks < 2; ++ks) {
        h8 b0 = *(const h8*)(smem + AT_RELT + ((w * 2 + 0) * 2 + ks) * 1024 + lane * 16);
        h8 b1 = *(const h8*)(smem + AT_RELT + ((w * 2 + 1) * 2 + ks) * 1024 + lane * 16);
        #pragma unroll
        for (int rt = 0; rt < 4; ++rt) {
            h8 a = *(const h8*)(&Qf[(rt * 16 + l15) * 72 + ks * 32 + l4 * 8]);
            pacc[rt][0] = __builtin_amdgcn_mfma_f32_16x16x32_f16(a, b0, pacc[rt][0], 0, 0, 0);
            pacc[rt][1] = __builtin_amdgcn_mfma_f32_16x16x32_f16(a, b1, pacc[rt][1], 0, 0, 0);
        }
    }

    __syncthreads();   // RelT frag reads done -> Pg region writable
    _Float16* Pg = (_Float16*)(smem + AT_PG);
    #pragma unroll
    for (int rt = 0; rt < 4; ++rt)
        #pragma unroll
        for (int cb2 = 0; cb2 < 2; ++cb2)
            #pragma unroll
            for (int reg = 0; reg < 4; ++reg)
                Pg[(rt * 16 + l4 * 4 + reg) * 130 + w * 32 + cb2 * 16 + l15] =
                    (_Float16)pacc[rt][cb2][reg];
    __syncthreads();

    {
        const int q = t >> 2, kk0 = (t & 3) * 8;
        const int hw = qb * 64 + q;
        const int hq = hw >> 5, wq = hw & 31;
        short8 vh_, vw_;
        #pragma unroll
        for (int j2 = 0; j2 < 8; ++j2) {
            const int kk = kk0 + j2;
            vh_[j2] = *(const short*)&Pg[q * 130 + (hq + 31 - kk)];
            vw_[j2] = *(const short*)&Pg[q * 130 + 64 + (wq + 31 - kk)];
        }
        *(short8*)(&Rel[q * 68 + kk0])      = vh_;
        *(short8*)(&Rel[q * 68 + 32 + kk0]) = vw_;
    }
    __syncthreads();   // Rel ready; Qf/RelT/Pg dead -> VT/KB usable

    const int qrow_bias = w * 16 + l15;
    float rw_[2][4];
    #pragma unroll
    for (int c2 = 0; c2 < 2; ++c2)
        #pragma unroll
        for (int reg = 0; reg < 4; ++reg)
            rw_[c2][reg] = (float)Rel[qrow_bias * 68 + 32 + c2 * 16 + l4 * 4 + reg];

    // K staging: async global->LDS, write-side source pre-swizzle; read-side
    // XOR makes ds_read_b128 fragments conflict-free (2 lanes/bank).
#define STAGEK(KT, BUF) {                                                      \
        _Pragma("unroll")                                                      \
        for (int i2 = 0; i2 < 2; ++i2) {                                       \
            const int f = w * 2 + i2;                                          \
            const int keyk = f * 8 + (lane >> 3);                              \
            const int srcb = ((lane & 7) * 16) ^ ((lane >> 3) << 4);           \
            gl_lds16((const char*)kb_ + (size_t)((KT) * 64 + keyk) * 128 + srcb, \
                     smem + AT_KB + (BUF) * 8192 + f * 1024);                  \
        } }

#define WRITEVT(BUF) {                                                         \
        _Pragma("unroll")                                                      \
        for (int j2 = 0; j2 < 8; ++j2) {                                       \
            const int d = dgrp * 8 + j2;                                       \
            unsigned pk = ((unsigned short)rv0[j2]) |                          \
                          (((unsigned)(unsigned short)rv1[j2]) << 16);         \
            *(unsigned*)(smem + AT_VT + (BUF) * 8192 + d * 128 +               \
                         ((key2 * 2) ^ ((d & 7) << 4))) = pk; } }
    WRITEVT(0);
    STAGEK(0, 0);

    f32x4 acc_o[4] = {{0,0,0,0},{0,0,0,0},{0,0,0,0},{0,0,0,0}};
    float m_ = -INFINITY, l_ = 0.f;
    char* Pw = smem + AT_P + w * 2048;
    const int swzP = (l15 & 7) << 4;

    #pragma unroll 2
    for (int kt = 0; kt < 16; ++kt) {
        const int cur = kt & 1;
        __syncthreads();                 // K/V buf[cur] ready (drains gl_lds)
        if (kt < 15) { LOADV(kt + 1); STAGEK(kt + 1, cur ^ 1); }

        // ---- QK^T swapped from K-LDS: D[key][q], C-init = rel bias ----
        const float rh0 = (float)Rel[qrow_bias * 68 + kt * 2];
        const float rh1 = (float)Rel[qrow_bias * 68 + kt * 2 + 1];
        f32x4 accs[4];
        #pragma unroll
        for (int ct = 0; ct < 4; ++ct) {
            const float rhc = (ct >> 1) ? rh1 : rh0;
            #pragma unroll
            for (int reg = 0; reg < 4; ++reg)
                accs[ct][reg] = rw_[ct & 1][reg] + rhc;
        }
        __builtin_amdgcn_s_setprio(1);
        #pragma unroll
        for (int ct = 0; ct < 4; ++ct) {
            const int row = ct * 16 + l15;
            const int swzK = (row & 7) << 4;
            #pragma unroll
            for (int ks = 0; ks < 2; ++ks) {
                h8 kfr = *(const h8*)(smem + AT_KB + cur * 8192 + row * 128 +
                                      ((ks * 64 + l4 * 16) ^ swzK));
                accs[ct] = __builtin_amdgcn_mfma_f32_16x16x32_f16(kfr, qf2[ks], accs[ct], 0, 0, 0);
            }
        }
        __builtin_amdgcn_s_setprio(0);

        // ---- lane-local online softmax (q = w*16 + l15), tree max ----
        float mx[4];
        #pragma unroll
        for (int ct = 0; ct < 4; ++ct)
            mx[ct] = fmaxf(fmaxf(accs[ct][0], accs[ct][1]),
                           fmaxf(accs[ct][2], accs[ct][3]));
        float tmax = fmaxf(fmaxf(mx[0], mx[1]), fmaxf(mx[2], mx[3]));
        tmax = fmaxf(tmax, __shfl_xor(tmax, 16));
        tmax = fmaxf(tmax, __shfl_xor(tmax, 32));

        if (__any(tmax > m_ + 8.f)) {    // defer-max: rescale rarely
            const float mnew = fmaxf(m_, tmax);
            const float factor = __expf(m_ - mnew);
            m_ = mnew;
            l_ *= factor;
            #pragma unroll
            for (int reg = 0; reg < 4; ++reg) {
                const float fr = __shfl(factor, l4 * 4 + reg);
                #pragma unroll
                for (int dt = 0; dt < 4; ++dt) acc_o[dt][reg] *= fr;
            }
        }

        float tsum = 0.f;
        #pragma unroll
        for (int ct = 0; ct < 4; ++ct) {
            float p0 = __expf(accs[ct][0] - m_);
            float p1 = __expf(accs[ct][1] - m_);
            float p2 = __expf(accs[ct][2] - m_);
            float p3 = __expf(accs[ct][3] - m_);
            tsum += (p0 + p1) + (p2 + p3);
            h2 pa = {(_Float16)p0, (_Float16)p1};
            h2 pb = {(_Float16)p2, (_Float16)p3};
            uint2 pk;
            pk.x = *(unsigned*)&pa;
            pk.y = *(unsigned*)&pb;
            *(uint2*)(Pw + l15 * 128 + ((ct * 32 + l4 * 8) ^ swzP)) = pk;
        }
        tsum += __shfl_xor(tsum, 16);
        tsum += __shfl_xor(tsum, 32);
        l_ += tsum;

        // ---- PV ----
        __builtin_amdgcn_s_setprio(1);
        #pragma unroll
        for (int ks = 0; ks < 2; ++ks) {
            h8 pa = *(const h8*)(Pw + l15 * 128 + ((ks * 64 + l4 * 16) ^ swzP));
            #pragma unroll
            for (int dt = 0; dt < 4; ++dt) {
                const int d = dt * 16 + l15;
                h8 vf = *(const h8*)(smem + AT_VT + cur * 8192 + d * 128 +
                                     ((ks * 64 + l4 * 16) ^ ((d & 7) << 4)));
                acc_o[dt] = __builtin_amdgcn_mfma_f32_16x16x32_f16(pa, vf, acc_o[dt], 0, 0, 0);
            }
        }
        __builtin_amdgcn_s_setprio(0);

        if (kt < 15) WRITEVT(cur ^ 1);
    }

    // ---- epilogue ----
    const float invl = 1.0f / l_;
    float linv[4];
    #pragma unroll
    for (int reg = 0; reg < 4; ++reg) linv[reg] = __shfl(invl, l4 * 4 + reg);
    __syncthreads();
    _Float16* Of = (_Float16*)(smem + AT_OF);
    #pragma unroll
    for (int reg = 0; reg < 4; ++reg) {
        const int qloc = w * 16 + l4 * 4 + reg;
        #pragma unroll
        for (int dt = 0; dt < 4; ++dt)
            Of[qloc * 72 + dt * 16 + l15] = (_Float16)(acc_o[dt][reg] * linv[reg]);
    }
    __syncthreads();
    {
        const int b_ = bh / NH, nh = bh % NH;
        _Float16* op = aout + ((size_t)b_ * HWN + qb * 64 + r) * DIM + nh * HD + dc;
        *(short8*)op       = *(const short8*)(&Of[r * 72 + dc]);
        *(short8*)(op + 8) = *(const short8*)(&Of[r * 72 + dc + 8]);
    }
}

// ---------------------------------------------------------------------------
extern "C" void kernel_launch(void* const* d_in, const int* in_sizes, int n_in,
                              void* d_out, int out_size, void* d_ws, size_t ws_size,
                              hipStream_t stream) {
    const float* q   = (const float*)d_in[0];
    const float* k   = (const float*)d_in[1];
    const float* v   = (const float*)d_in[2];
    const float* Wq  = (const float*)d_in[3];
    const float* bq  = (const float*)d_in[4];
    const float* Wk  = (const float*)d_in[5];
    const float* bk  = (const float*)d_in[6];
    const float* Wv  = (const float*)d_in[7];
    const float* bv  = (const float*)d_in[8];
    const float* Wp  = (const float*)d_in[9];
    const float* bp  = (const float*)d_in[10];
    const float* rph = (const float*)d_in[11];
    const float* rpw = (const float*)d_in[12];

    float* out = (float*)d_out;
    char*  w0  = (char*)d_ws;

    _Float16* wtAll = (_Float16*)(w0);                // 4,718,592
    _Float16* relTg = (_Float16*)(w0 + 4718592);      //    16,384
    _Float16* qf16  = (_Float16*)(w0 + 4734976);      // 6,291,456
    _Float16* kf16  = (_Float16*)(w0 + 11026432);     // 6,291,456
    _Float16* vf16  = (_Float16*)(w0 + 17317888);     // 6,291,456
    _Float16* aout  = (_Float16*)(w0 + 23609344);     // 6,291,456 -> 29,900,800

    dim3 blk(256);
    wconv_kernel<<<dim3(12, 12, 4), blk, 0, stream>>>(Wq, Wk, Wv, Wp, wtAll);
    rel2frag_kernel<<<1, blk, 0, stream>>>(rph, rpw, relTg);
    gemm_mfma_kernel<0><<<1152, blk, 0, stream>>>(
        q, k, v, wtAll, bq, bk, bv, qf16, kf16, vf16);
    attn_kernel<<<768, blk, 0, stream>>>(qf16, kf16, vf16, relTg, aout);
    gemm_mfma_kernel<1><<<384, blk, 0, stream>>>(
        aout, nullptr, nullptr, wtAll, bp, nullptr, nullptr,
        out, nullptr, nullptr);
}

// Round 10
// 100.350 us; speedup vs baseline: 8.0084x; 1.0118x over previous
//
#include <hip/hip_runtime.h>
#include <math.h>

#define DIM  768
#define NH   12
#define HD   64
#define HWN  1024
#define MROWS 4096

typedef __attribute__((ext_vector_type(8))) short short8;
typedef __attribute__((ext_vector_type(4))) float f32x4;
typedef _Float16 h8 __attribute__((ext_vector_type(8)));
typedef _Float16 h2 __attribute__((ext_vector_type(2)));

__device__ __forceinline__ void gl_lds16(const void* g, void* l) {
    __builtin_amdgcn_global_load_lds(
        (const __attribute__((address_space(1))) void*)g,
        (__attribute__((address_space(3))) void*)l, 16, 0, 0);
}

// ---------------------------------------------------------------------------
// q,k,v fp32 -> fp16 contiguous [3][4096*768] (memory-bound, ~56MB traffic)
// ---------------------------------------------------------------------------
__global__ __launch_bounds__(256) void xconv_kernel(
    const float* __restrict__ q, const float* __restrict__ k,
    const float* __restrict__ v, _Float16* __restrict__ xf16)
{
    const int N8 = MROWS * DIM / 8;            // 393216 per tensor
    int i = blockIdx.x * 256 + threadIdx.x;
    const int stride = gridDim.x * 256;
    for (; i < 3 * N8; i += stride) {
        const int sel = i / N8, j = i - sel * N8;
        const float* src = (sel == 0) ? q : (sel == 1) ? k : v;
        float4 a0 = ((const float4*)src)[j * 2];
        float4 a1 = ((const float4*)src)[j * 2 + 1];
        h8 o = {(_Float16)a0.x, (_Float16)a0.y, (_Float16)a0.z, (_Float16)a0.w,
                (_Float16)a1.x, (_Float16)a1.y, (_Float16)a1.z, (_Float16)a1.w};
        *(h8*)(xf16 + (size_t)sel * (MROWS * DIM) + (size_t)j * 8) = o;
    }
}

// ---------------------------------------------------------------------------
// W (768x768 k-major fp32) -> Wt fp16 (n-major). z selects Wq/Wk/Wv/Wp.
// ---------------------------------------------------------------------------
__global__ __launch_bounds__(256) void wconv_kernel(
    const float* __restrict__ Wq, const float* __restrict__ Wk,
    const float* __restrict__ Wv, const float* __restrict__ Wp,
    _Float16* __restrict__ WtAll)
{
    __shared__ float Ws[64][65];
    const int z = blockIdx.z;
    const float* W = (z == 0) ? Wq : (z == 1) ? Wk : (z == 2) ? Wv : Wp;
    _Float16* Wt = WtAll + (size_t)z * 589824;

    const int k0 = blockIdx.y * 64, n0 = blockIdx.x * 64;
    const int t = threadIdx.x;
    {
        int r = t >> 2, c4 = (t & 3) * 16;
        #pragma unroll
        for (int u = 0; u < 16; u += 4)
            *(float4*)&Ws[r][c4 + u] = *(const float4*)(W + (size_t)(k0 + r) * DIM + n0 + c4 + u);
    }
    __syncthreads();
    const int n = t >> 2, kseg = (t & 3) * 16;
    h8 h0, h1;
    #pragma unroll
    for (int j = 0; j < 8; ++j) {
        h0[j] = (_Float16)Ws[kseg + j][n];
        h1[j] = (_Float16)Ws[kseg + 8 + j][n];
    }
    size_t base = (size_t)(n0 + n) * DIM + k0 + kseg;
    *(h8*)(Wt + base) = h0;
    *(h8*)(Wt + base + 8) = h1;
}

// ---------------------------------------------------------------------------
// Pack [rel_pos_h(63x64) ; pad ; rel_pos_w(63x64) ; pad] -> fp16 n-major
// ---------------------------------------------------------------------------
__global__ __launch_bounds__(256) void rel2frag_kernel(
    const float* __restrict__ rph, const float* __restrict__ rpw,
    _Float16* __restrict__ relTg)
{
    const int t = threadIdx.x;
    const int row = t >> 1, c0 = (t & 1) * 32;
    const float* src = (row < 63) ? rph + (size_t)row * HD
                     : (row >= 64 && row < 127) ? rpw + (size_t)(row - 64) * HD
                     : nullptr;
    #pragma unroll
    for (int g = 0; g < 4; ++g) {
        h8 o;
        #pragma unroll
        for (int j = 0; j < 8; ++j)
            o[j] = src ? (_Float16)src[c0 + g * 8 + j] : (_Float16)0.0f;
        *(h8*)(relTg + (size_t)row * HD + c0 + g * 8) = o;
    }
}

// ---------------------------------------------------------------------------
// fp16 MFMA GEMM, all-fp16 A (pre-converted).
// AMODE 0: tile 128x128, q/k/v fused (576 blocks), out fp16 head layout.
// AMODE 1: tile 128x64, attn-out (384 blocks), out fp32 flat + bias.
// ---------------------------------------------------------------------------
template<int AMODE>
__global__ __launch_bounds__(256, 3) void gemm_mfma_kernel(
    const _Float16* __restrict__ X0, const _Float16* __restrict__ WtAll,
    const float* __restrict__ bias0, const float* __restrict__ bias1,
    const float* __restrict__ bias2,
    void* __restrict__ Y0, void* __restrict__ Y1, void* __restrict__ Y2)
{
    constexpr int NT  = (AMODE == 0) ? 128 : 64;   // tile N
    constexpr int NBF = NT / 16;                   // B frags per ks (8 / 4)
    constexpr int WCF = NT / 32;                   // col frags per wave (4 / 2)
    __shared__ __align__(16) char smem[16384 + 2 * NBF * 1024];
    constexpr int BOFF = 16384;

    const int t = threadIdx.x;
    const int w = t >> 6, lane = t & 63;
    const int l15 = lane & 15, l4 = lane >> 4;

    int sel, rem, rb, cb;
    if (AMODE == 0) {
        const int sw = (blockIdx.x & 7) * 72 + (blockIdx.x >> 3);   // 576 blocks
        sel = sw / 192; rem = sw - sel * 192;
        rb = rem / 6; cb = rem - rb * 6;
    } else {
        const int sw = (blockIdx.x & 7) * 48 + (blockIdx.x >> 3);   // 384 blocks
        sel = 3; rem = sw;
        rb = rem / 12; cb = rem - rb * 12;
    }
    const int row0 = rb * 128, col0 = cb * NT;

    const char* Ab = (const char*)(X0 + (AMODE == 0 ? (size_t)sel * (MROWS * DIM) : 0));
    const _Float16* Bt = WtAll + (size_t)sel * 589824;
    const float* bias = (AMODE == 1) ? bias0 : (sel == 0) ? bias0 : (sel == 1) ? bias1 : bias2;

    f32x4 acc[4][WCF];
    #pragma unroll
    for (int i = 0; i < 4; ++i)
        #pragma unroll
        for (int j = 0; j < WCF; ++j) acc[i][j] = (f32x4){0, 0, 0, 0};

    for (int kt = 0; kt < 12; ++kt) {
        // ---- stage A (fp16, 16KB, fragment rows w/ XOR swizzle) ----
        #pragma unroll
        for (int i = 0; i < 4; ++i) {
            const int fi = w * 4 + i;
            const int row = fi * 8 + (lane >> 3);
            const int srcb = ((lane & 7) * 16) ^ ((row & 7) << 4);
            gl_lds16(Ab + (size_t)(row0 + row) * 1536 + kt * 128 + srcb, smem + fi * 1024);
        }
        // ---- stage B (fp16 n-major, fragment-major) ----
        #pragma unroll
        for (int it = 0; it < 2 * NBF / 4; ++it) {
            const int f = it * 4 + w;
            const int ks = f / NBF, cf = f % NBF;
            const size_t off = (size_t)(col0 + cf * 16 + l15) * 1536 + kt * 128 + ks * 64 + l4 * 16;
            gl_lds16((const char*)Bt + off, smem + BOFF + f * 1024);
        }
        __syncthreads();

        __builtin_amdgcn_s_setprio(1);
        #pragma unroll
        for (int ks = 0; ks < 2; ++ks) {
            h8 b[WCF];
            #pragma unroll
            for (int cf4 = 0; cf4 < WCF; ++cf4) {
                const int fb = ks * NBF + (w & 1) * WCF + cf4;
                b[cf4] = *(const h8*)(smem + BOFF + fb * 1024 + lane * 16);
            }
            #pragma unroll
            for (int rf = 0; rf < 4; ++rf) {
                const int arow = (w >> 1) * 64 + rf * 16 + l15;
                const int base = arow * 128 + ((ks * 64 + l4 * 16) ^ ((arow & 7) << 4));
                h8 ah = *(const h8*)(smem + base);
                #pragma unroll
                for (int cf4 = 0; cf4 < WCF; ++cf4)
                    acc[rf][cf4] = __builtin_amdgcn_mfma_f32_16x16x32_f16(ah, b[cf4], acc[rf][cf4], 0, 0, 0);
            }
        }
        __builtin_amdgcn_s_setprio(0);
        __syncthreads();
    }

    const int wrow0 = row0 + (w >> 1) * 64;
    const int wcol0 = col0 + (w & 1) * (WCF * 16);
    #pragma unroll
    for (int cf4 = 0; cf4 < WCF; ++cf4) {
        const int c = wcol0 + cf4 * 16 + l15;
        const float bb = bias[c - (AMODE == 0 ? 0 : col0) + (AMODE == 0 ? 0 : col0)]; // = bias[c]
        #pragma unroll
        for (int rf = 0; rf < 4; ++rf) {
            #pragma unroll
            for (int reg = 0; reg < 4; ++reg) {
                const int r = wrow0 + rf * 16 + l4 * 4 + reg;
                float y = acc[rf][cf4][reg] + bb;
                if (AMODE == 1) {
                    ((float*)Y0)[(size_t)r * DIM + c] = y;
                } else {
                    _Float16* Yh = (_Float16*)((sel == 0) ? Y0 : (sel == 1) ? Y1 : Y2);
                    size_t base = ((size_t)((r >> 10) * NH + (c >> 6)) * HWN + (r & 1023)) * HD + (c & 63);
                    Yh[base] = (_Float16)y;
                }
            }
        }
    }
}

// ---------------------------------------------------------------------------
// fp16 MFMA fused attention (R9 structure, unchanged): K staged once per
// block into LDS (async, double-buffered, swizzled); XCD-owned heads;
// MFMA rel-pos prologue; swapped QK^T lane-local softmax; defer-max.
// ---------------------------------------------------------------------------
#define AT_REL   0        // 8704
#define AT_VT    8704     // 2 x 8192 -> 25088
#define AT_P     25088    // 4 x 2048 -> 33280
#define AT_KB    33280    // 2 x 8192 -> 49664
#define AT_QF    8704     // prologue overlay
#define AT_RELT  17920    // prologue overlay
#define AT_PG    17920    // prologue overlay
#define AT_OF    8704     // epilogue overlay
#define AT_TOTAL 49664

__global__ __launch_bounds__(256, 3) void attn_kernel(
    const _Float16* __restrict__ qh, const _Float16* __restrict__ kh,
    const _Float16* __restrict__ vh, const _Float16* __restrict__ relTg,
    _Float16* __restrict__ aout)
{
    __shared__ __align__(16) char smem[AT_TOTAL];
    const int bid = blockIdx.x;
    const int j   = bid >> 3;
    const int bh  = (bid & 7) * 6 + (j >> 4);   // 0..47
    const int qb  = j & 15;                     // 0..15
    const int t  = threadIdx.x;
    const int w  = t >> 6;
    const int lane = t & 63;
    const int l15 = lane & 15, l4 = lane >> 4;

    _Float16* Rel = (_Float16*)(smem + AT_REL);
    _Float16* Qf  = (_Float16*)(smem + AT_QF);

    const int r = t >> 2, dc = (t & 3) * 16;
    {
        const _Float16* qp = qh + ((size_t)bh * HWN + qb * 64 + r) * HD + dc;
        *(short8*)(&Qf[r * 72 + dc])     = *(const short8*)(qp);
        *(short8*)(&Qf[r * 72 + dc + 8]) = *(const short8*)(qp + 8);
        #pragma unroll
        for (int it = 0; it < 4; ++it) {
            const int f = it * 4 + w;
            const int ct = f >> 1, ks = f & 1;
            gl_lds16((const char*)relTg + (ct * 16 + l15) * 128 + ks * 64 + l4 * 16,
                     smem + AT_RELT + f * 1024);
        }
    }
    __syncthreads();

    const _Float16* kb_ = kh + (size_t)bh * HWN * HD;
    const _Float16* vb_ = vh + (size_t)bh * HWN * HD;
    const int key2 = (t & 31) * 2, dgrp = t >> 5;
    short8 rv0, rv1;
#define LOADV(KT) {                                                            \
        const _Float16* vp = vb_ + (size_t)((KT) * 64 + key2) * HD + dgrp * 8; \
        rv0 = *(const short8*)vp; rv1 = *(const short8*)(vp + HD); }
    LOADV(0);

    h8 qf2[2];
    {
        const int qr = w * 16 + l15;
        qf2[0] = *(const h8*)(&Qf[qr * 72 + l4 * 8]);
        qf2[1] = *(const h8*)(&Qf[qr * 72 + 32 + l4 * 8]);
        #pragma unroll
        for (int j2 = 0; j2 < 8; ++j2) { qf2[0][j2] *= (_Float16)0.125f; qf2[1][j2] *= (_Float16)0.125f; }
    }

    f32x4 pacc[4][2];
    #pragma unroll
    for (int i = 0; i < 4; ++i)
        #pragma unroll
        for (int j2 = 0; j2 < 2; ++j2) pacc[i][j2] = (f32x4){0, 0, 0, 0};
    #pragma unroll
    for (int ks = 0; ks < 2; ++ks) {
        h8 b0 = *(const h8*)(smem + AT_RELT + ((w * 2 + 0) * 2 + ks) * 1024 + lane * 16);
        h8 b1 = *(const h8*)(smem + AT_RELT + ((w * 2 + 1) * 2 + ks) * 1024 + lane * 16);
        #pragma unroll
        for (int rt = 0; rt < 4; ++rt) {
            h8 a = *(const h8*)(&Qf[(rt * 16 + l15) * 72 + ks * 32 + l4 * 8]);
            pacc[rt][0] = __builtin_amdgcn_mfma_f32_16x16x32_f16(a, b0, pacc[rt][0], 0, 0, 0);
            pacc[rt][1] = __builtin_amdgcn_mfma_f32_16x16x32_f16(a, b1, pacc[rt][1], 0, 0, 0);
        }
    }

    __syncthreads();
    _Float16* Pg = (_Float16*)(smem + AT_PG);
    #pragma unroll
    for (int rt = 0; rt < 4; ++rt)
        #pragma unroll
        for (int cb2 = 0; cb2 < 2; ++cb2)
            #pragma unroll
            for (int reg = 0; reg < 4; ++reg)
                Pg[(rt * 16 + l4 * 4 + reg) * 130 + w * 32 + cb2 * 16 + l15] =
                    (_Float16)pacc[rt][cb2][reg];
    __syncthreads();

    {
        const int q = t >> 2, kk0 = (t & 3) * 8;
        const int hw = qb * 64 + q;
        const int hq = hw >> 5, wq = hw & 31;
        short8 vh_, vw_;
        #pragma unroll
        for (int j2 = 0; j2 < 8; ++j2) {
            const int kk = kk0 + j2;
            vh_[j2] = *(const short*)&Pg[q * 130 + (hq + 31 - kk)];
            vw_[j2] = *(const short*)&Pg[q * 130 + 64 + (wq + 31 - kk)];
        }
        *(short8*)(&Rel[q * 68 + kk0])      = vh_;
        *(short8*)(&Rel[q * 68 + 32 + kk0]) = vw_;
    }
    __syncthreads();

    const int qrow_bias = w * 16 + l15;
    float rw_[2][4];
    #pragma unroll
    for (int c2 = 0; c2 < 2; ++c2)
        #pragma unroll
        for (int reg = 0; reg < 4; ++reg)
            rw_[c2][reg] = (float)Rel[qrow_bias * 68 + 32 + c2 * 16 + l4 * 4 + reg];

#define STAGEK(KT, BUF) {                                                      \
        _Pragma("unroll")                                                      \
        for (int i2 = 0; i2 < 2; ++i2) {                                       \
            const int f = w * 2 + i2;                                          \
            const int keyk = f * 8 + (lane >> 3);                              \
            const int srcb = ((lane & 7) * 16) ^ ((lane >> 3) << 4);           \
            gl_lds16((const char*)kb_ + (size_t)((KT) * 64 + keyk) * 128 + srcb, \
                     smem + AT_KB + (BUF) * 8192 + f * 1024);                  \
        } }

#define WRITEVT(BUF) {                                                         \
        _Pragma("unroll")                                                      \
        for (int j2 = 0; j2 < 8; ++j2) {                                       \
            const int d = dgrp * 8 + j2;                                       \
            unsigned pk = ((unsigned short)rv0[j2]) |                          \
                          (((unsigned)(unsigned short)rv1[j2]) << 16);         \
            *(unsigned*)(smem + AT_VT + (BUF) * 8192 + d * 128 +               \
                         ((key2 * 2) ^ ((d & 7) << 4))) = pk; } }
    WRITEVT(0);
    STAGEK(0, 0);

    f32x4 acc_o[4] = {{0,0,0,0},{0,0,0,0},{0,0,0,0},{0,0,0,0}};
    float m_ = -INFINITY, l_ = 0.f;
    char* Pw = smem + AT_P + w * 2048;
    const int swzP = (l15 & 7) << 4;

    #pragma unroll 2
    for (int kt = 0; kt < 16; ++kt) {
        const int cur = kt & 1;
        __syncthreads();
        if (kt < 15) { LOADV(kt + 1); STAGEK(kt + 1, cur ^ 1); }

        const float rh0 = (float)Rel[qrow_bias * 68 + kt * 2];
        const float rh1 = (float)Rel[qrow_bias * 68 + kt * 2 + 1];
        f32x4 accs[4];
        #pragma unroll
        for (int ct = 0; ct < 4; ++ct) {
            const float rhc = (ct >> 1) ? rh1 : rh0;
            #pragma unroll
            for (int reg = 0; reg < 4; ++reg)
                accs[ct][reg] = rw_[ct & 1][reg] + rhc;
        }
        __builtin_amdgcn_s_setprio(1);
        #pragma unroll
        for (int ct = 0; ct < 4; ++ct) {
            const int row = ct * 16 + l15;
            const int swzK = (row & 7) << 4;
            #pragma unroll
            for (int ks = 0; ks < 2; ++ks) {
                h8 kfr = *(const h8*)(smem + AT_KB + cur * 8192 + row * 128 +
                                      ((ks * 64 + l4 * 16) ^ swzK));
                accs[ct] = __builtin_amdgcn_mfma_f32_16x16x32_f16(kfr, qf2[ks], accs[ct], 0, 0, 0);
            }
        }
        __builtin_amdgcn_s_setprio(0);

        float mx[4];
        #pragma unroll
        for (int ct = 0; ct < 4; ++ct)
            mx[ct] = fmaxf(fmaxf(accs[ct][0], accs[ct][1]),
                           fmaxf(accs[ct][2], accs[ct][3]));
        float tmax = fmaxf(fmaxf(mx[0], mx[1]), fmaxf(mx[2], mx[3]));
        tmax = fmaxf(tmax, __shfl_xor(tmax, 16));
        tmax = fmaxf(tmax, __shfl_xor(tmax, 32));

        if (__any(tmax > m_ + 8.f)) {
            const float mnew = fmaxf(m_, tmax);
            const float factor = __expf(m_ - mnew);
            m_ = mnew;
            l_ *= factor;
            #pragma unroll
            for (int reg = 0; reg < 4; ++reg) {
                const float fr = __shfl(factor, l4 * 4 + reg);
                #pragma unroll
                for (int dt = 0; dt < 4; ++dt) acc_o[dt][reg] *= fr;
            }
        }

        float tsum = 0.f;
        #pragma unroll
        for (int ct = 0; ct < 4; ++ct) {
            float p0 = __expf(accs[ct][0] - m_);
            float p1 = __expf(accs[ct][1] - m_);
            float p2 = __expf(accs[ct][2] - m_);
            float p3 = __expf(accs[ct][3] - m_);
            tsum += (p0 + p1) + (p2 + p3);
            h2 pa = {(_Float16)p0, (_Float16)p1};
            h2 pb = {(_Float16)p2, (_Float16)p3};
            uint2 pk;
            pk.x = *(unsigned*)&pa;
            pk.y = *(unsigned*)&pb;
            *(uint2*)(Pw + l15 * 128 + ((ct * 32 + l4 * 8) ^ swzP)) = pk;
        }
        tsum += __shfl_xor(tsum, 16);
        tsum += __shfl_xor(tsum, 32);
        l_ += tsum;

        __builtin_amdgcn_s_setprio(1);
        #pragma unroll
        for (int ks = 0; ks < 2; ++ks) {
            h8 pa = *(const h8*)(Pw + l15 * 128 + ((ks * 64 + l4 * 16) ^ swzP));
            #pragma unroll
            for (int dt = 0; dt < 4; ++dt) {
                const int d = dt * 16 + l15;
                h8 vf = *(const h8*)(smem + AT_VT + cur * 8192 + d * 128 +
                                     ((ks * 64 + l4 * 16) ^ ((d & 7) << 4)));
                acc_o[dt] = __builtin_amdgcn_mfma_f32_16x16x32_f16(pa, vf, acc_o[dt], 0, 0, 0);
            }
        }
        __builtin_amdgcn_s_setprio(0);

        if (kt < 15) WRITEVT(cur ^ 1);
    }

    const float invl = 1.0f / l_;
    float linv[4];
    #pragma unroll
    for (int reg = 0; reg < 4; ++reg) linv[reg] = __shfl(invl, l4 * 4 + reg);
    __syncthreads();
    _Float16* Of = (_Float16*)(smem + AT_OF);
    #pragma unroll
    for (int reg = 0; reg < 4; ++reg) {
        const int qloc = w * 16 + l4 * 4 + reg;
        #pragma unroll
        for (int dt = 0; dt < 4; ++dt)
            Of[qloc * 72 + dt * 16 + l15] = (_Float16)(acc_o[dt][reg] * linv[reg]);
    }
    __syncthreads();
    {
        const int b_ = bh / NH, nh = bh % NH;
        _Float16* op = aout + ((size_t)b_ * HWN + qb * 64 + r) * DIM + nh * HD + dc;
        *(short8*)op       = *(const short8*)(&Of[r * 72 + dc]);
        *(short8*)(op + 8) = *(const short8*)(&Of[r * 72 + dc + 8]);
    }
}

// ---------------------------------------------------------------------------
extern "C" void kernel_launch(void* const* d_in, const int* in_sizes, int n_in,
                              void* d_out, int out_size, void* d_ws, size_t ws_size,
                              hipStream_t stream) {
    const float* q   = (const float*)d_in[0];
    const float* k   = (const float*)d_in[1];
    const float* v   = (const float*)d_in[2];
    const float* Wq  = (const float*)d_in[3];
    const float* bq  = (const float*)d_in[4];
    const float* Wk  = (const float*)d_in[5];
    const float* bk  = (const float*)d_in[6];
    const float* Wv  = (const float*)d_in[7];
    const float* bv  = (const float*)d_in[8];
    const float* Wp  = (const float*)d_in[9];
    const float* bp  = (const float*)d_in[10];
    const float* rph = (const float*)d_in[11];
    const float* rpw = (const float*)d_in[12];

    float* out = (float*)d_out;
    char*  w0  = (char*)d_ws;

    _Float16* wtAll = (_Float16*)(w0);                // 4,718,592
    _Float16* relTg = (_Float16*)(w0 + 4718592);      //    16,384
    _Float16* xf16  = (_Float16*)(w0 + 4734976);      // 18,874,368 (q,k,v fp16)
    _Float16* aout  = (_Float16*)(w0 + 4734976);      // overlays xf16 (dead by attn)
    _Float16* qf16  = (_Float16*)(w0 + 23609344);     // 6,291,456
    _Float16* kf16  = (_Float16*)(w0 + 29900800);     // 6,291,456
    _Float16* vf16  = (_Float16*)(w0 + 36192256);     // 6,291,456 -> 42,483,712

    dim3 blk(256);
    xconv_kernel<<<2048, blk, 0, stream>>>(q, k, v, xf16);
    wconv_kernel<<<dim3(12, 12, 4), blk, 0, stream>>>(Wq, Wk, Wv, Wp, wtAll);
    rel2frag_kernel<<<1, blk, 0, stream>>>(rph, rpw, relTg);
    gemm_mfma_kernel<0><<<576, blk, 0, stream>>>(
        xf16, wtAll, bq, bk, bv, qf16, kf16, vf16);
    attn_kernel<<<768, blk, 0, stream>>>(qf16, kf16, vf16, relTg, aout);
    gemm_mfma_kernel<1><<<384, blk, 0, stream>>>(
        aout, wtAll, bp, nullptr, nullptr, out, nullptr, nullptr);
}

// Round 11
// 95.117 us; speedup vs baseline: 8.4490x; 1.0550x over previous
//
#include <hip/hip_runtime.h>
#include <math.h>

#define DIM  768
#define NH   12
#define HD   64
#define HWN  1024
#define MROWS 4096

typedef __attribute__((ext_vector_type(8))) short short8;
typedef __attribute__((ext_vector_type(4))) float f32x4;
typedef _Float16 h8 __attribute__((ext_vector_type(8)));
typedef _Float16 h2 __attribute__((ext_vector_type(2)));

__device__ __forceinline__ void gl_lds16(const void* g, void* l) {
    __builtin_amdgcn_global_load_lds(
        (const __attribute__((address_space(1))) void*)g,
        (__attribute__((address_space(3))) void*)l, 16, 0, 0);
}

// ---------------------------------------------------------------------------
// q,k,v fp32 -> fp16 contiguous [3][4096*768]
// ---------------------------------------------------------------------------
__global__ __launch_bounds__(256) void xconv_kernel(
    const float* __restrict__ q, const float* __restrict__ k,
    const float* __restrict__ v, _Float16* __restrict__ xf16)
{
    const int N8 = MROWS * DIM / 8;
    int i = blockIdx.x * 256 + threadIdx.x;
    const int stride = gridDim.x * 256;
    for (; i < 3 * N8; i += stride) {
        const int sel = i / N8, j = i - sel * N8;
        const float* src = (sel == 0) ? q : (sel == 1) ? k : v;
        float4 a0 = ((const float4*)src)[j * 2];
        float4 a1 = ((const float4*)src)[j * 2 + 1];
        h8 o = {(_Float16)a0.x, (_Float16)a0.y, (_Float16)a0.z, (_Float16)a0.w,
                (_Float16)a1.x, (_Float16)a1.y, (_Float16)a1.z, (_Float16)a1.w};
        *(h8*)(xf16 + (size_t)sel * (MROWS * DIM) + (size_t)j * 8) = o;
    }
}

// ---------------------------------------------------------------------------
// W (768x768 k-major fp32) -> Wt fp16 (n-major). z selects Wq/Wk/Wv/Wp.
// ---------------------------------------------------------------------------
__global__ __launch_bounds__(256) void wconv_kernel(
    const float* __restrict__ Wq, const float* __restrict__ Wk,
    const float* __restrict__ Wv, const float* __restrict__ Wp,
    _Float16* __restrict__ WtAll)
{
    __shared__ float Ws[64][65];
    const int z = blockIdx.z;
    const float* W = (z == 0) ? Wq : (z == 1) ? Wk : (z == 2) ? Wv : Wp;
    _Float16* Wt = WtAll + (size_t)z * 589824;

    const int k0 = blockIdx.y * 64, n0 = blockIdx.x * 64;
    const int t = threadIdx.x;
    {
        int r = t >> 2, c4 = (t & 3) * 16;
        #pragma unroll
        for (int u = 0; u < 16; u += 4)
            *(float4*)&Ws[r][c4 + u] = *(const float4*)(W + (size_t)(k0 + r) * DIM + n0 + c4 + u);
    }
    __syncthreads();
    const int n = t >> 2, kseg = (t & 3) * 16;
    h8 h0, h1;
    #pragma unroll
    for (int j = 0; j < 8; ++j) {
        h0[j] = (_Float16)Ws[kseg + j][n];
        h1[j] = (_Float16)Ws[kseg + 8 + j][n];
    }
    size_t base = (size_t)(n0 + n) * DIM + k0 + kseg;
    *(h8*)(Wt + base) = h0;
    *(h8*)(Wt + base + 8) = h1;
}

// ---------------------------------------------------------------------------
// Pack [rel_pos_h(63x64) ; pad ; rel_pos_w(63x64) ; pad] -> fp16 n-major
// ---------------------------------------------------------------------------
__global__ __launch_bounds__(256) void rel2frag_kernel(
    const float* __restrict__ rph, const float* __restrict__ rpw,
    _Float16* __restrict__ relTg)
{
    const int t = threadIdx.x;
    const int row = t >> 1, c0 = (t & 1) * 32;
    const float* src = (row < 63) ? rph + (size_t)row * HD
                     : (row >= 64 && row < 127) ? rpw + (size_t)(row - 64) * HD
                     : nullptr;
    #pragma unroll
    for (int g = 0; g < 4; ++g) {
        h8 o;
        #pragma unroll
        for (int j = 0; j < 8; ++j)
            o[j] = src ? (_Float16)src[c0 + g * 8 + j] : (_Float16)0.0f;
        *(h8*)(relTg + (size_t)row * HD + c0 + g * 8) = o;
    }
}

// ---------------------------------------------------------------------------
// fp16 MFMA GEMM, 96-wide tiles for exact CU balance.
// AMODE 0: tile 128x96, q/k/v fused -> 768 blocks (3.00/CU), out fp16 heads.
// AMODE 1: tile  64x96, attn-out    -> 512 blocks (2.00/CU), out fp32 + bias.
// ---------------------------------------------------------------------------
template<int AMODE>
__global__ __launch_bounds__(256, 3) void gemm_mfma_kernel(
    const _Float16* __restrict__ X0, const _Float16* __restrict__ WtAll,
    const float* __restrict__ bias0, const float* __restrict__ bias1,
    const float* __restrict__ bias2,
    void* __restrict__ Y0, void* __restrict__ Y1, void* __restrict__ Y2)
{
    constexpr int MT = (AMODE == 0) ? 128 : 64;    // tile M
    constexpr int RF = MT / 32;                    // A row-frags per wave
    __shared__ __align__(16) char smem[MT * 128 + 12 * 1024];
    constexpr int BOFF = MT * 128;

    const int t = threadIdx.x;
    const int w = t >> 6, lane = t & 63;
    const int l15 = lane & 15, l4 = lane >> 4;

    int sel, rb, cb;
    if (AMODE == 0) {
        const int sw = (blockIdx.x & 7) * 96 + (blockIdx.x >> 3);   // 768
        sel = sw >> 8;
        const int rem = sw & 255;
        rb = rem >> 3; cb = rem & 7;
    } else {
        const int sw = (blockIdx.x & 7) * 64 + (blockIdx.x >> 3);   // 512
        sel = 3;
        rb = sw >> 3; cb = sw & 7;
    }
    const int row0 = rb * MT, col0 = cb * 96;

    const char* Ab = (const char*)(X0 + (AMODE == 0 ? (size_t)sel * (MROWS * DIM) : 0));
    const _Float16* Bt = WtAll + (size_t)sel * 589824;
    const float* bias = (AMODE == 1) ? bias0 : (sel == 0) ? bias0 : (sel == 1) ? bias1 : bias2;

    f32x4 acc[RF][3];
    #pragma unroll
    for (int i = 0; i < RF; ++i)
        #pragma unroll
        for (int j = 0; j < 3; ++j) acc[i][j] = (f32x4){0, 0, 0, 0};

    for (int kt = 0; kt < 12; ++kt) {
        // ---- stage A (fp16, fragment rows w/ XOR swizzle) ----
        #pragma unroll
        for (int i = 0; i < MT / 32; ++i) {
            const int fi = w * (MT / 32) + i;
            const int row = fi * 8 + (lane >> 3);
            const int srcb = ((lane & 7) * 16) ^ ((row & 7) << 4);
            gl_lds16(Ab + (size_t)(row0 + row) * 1536 + kt * 128 + srcb, smem + fi * 1024);
        }
        // ---- stage B (fp16 n-major, fragment-major, 12 frags) ----
        #pragma unroll
        for (int it = 0; it < 3; ++it) {
            const int f = it * 4 + w;
            const int ks = f / 6, cf = f % 6;
            const size_t off = (size_t)(col0 + cf * 16 + l15) * 1536 + kt * 128 + ks * 64 + l4 * 16;
            gl_lds16((const char*)Bt + off, smem + BOFF + f * 1024);
        }
        __syncthreads();

        __builtin_amdgcn_s_setprio(1);
        #pragma unroll
        for (int ks = 0; ks < 2; ++ks) {
            h8 b[3];
            #pragma unroll
            for (int cf4 = 0; cf4 < 3; ++cf4) {
                const int fb = ks * 6 + (w & 1) * 3 + cf4;
                b[cf4] = *(const h8*)(smem + BOFF + fb * 1024 + lane * 16);
            }
            #pragma unroll
            for (int rf = 0; rf < RF; ++rf) {
                const int arow = (w >> 1) * (MT / 2) + rf * 16 + l15;
                const int base = arow * 128 + ((ks * 64 + l4 * 16) ^ ((arow & 7) << 4));
                h8 ah = *(const h8*)(smem + base);
                #pragma unroll
                for (int cf4 = 0; cf4 < 3; ++cf4)
                    acc[rf][cf4] = __builtin_amdgcn_mfma_f32_16x16x32_f16(ah, b[cf4], acc[rf][cf4], 0, 0, 0);
            }
        }
        __builtin_amdgcn_s_setprio(0);
        __syncthreads();
    }

    const int wrow0 = row0 + (w >> 1) * (MT / 2);
    const int wcol0 = col0 + (w & 1) * 48;
    #pragma unroll
    for (int cf4 = 0; cf4 < 3; ++cf4) {
        const int c = wcol0 + cf4 * 16 + l15;
        const float bb = bias[c];
        #pragma unroll
        for (int rf = 0; rf < RF; ++rf) {
            #pragma unroll
            for (int reg = 0; reg < 4; ++reg) {
                const int r = wrow0 + rf * 16 + l4 * 4 + reg;
                float y = acc[rf][cf4][reg] + bb;
                if (AMODE == 1) {
                    ((float*)Y0)[(size_t)r * DIM + c] = y;
                } else {
                    _Float16* Yh = (_Float16*)((sel == 0) ? Y0 : (sel == 1) ? Y1 : Y2);
                    size_t base = ((size_t)((r >> 10) * NH + (c >> 6)) * HWN + (r & 1023)) * HD + (c & 63);
                    Yh[base] = (_Float16)y;
                }
            }
        }
    }
}

// ---------------------------------------------------------------------------
// fp16 MFMA fused attention. R11: shuffle-free softmax common path —
// per-lane partial l (reduced once after loop), group-max shuffles moved
// inside the rare defer-max branch, RelH pair fetched as one u32.
// ---------------------------------------------------------------------------
#define AT_REL   0        // 8704
#define AT_VT    8704     // 2 x 8192 -> 25088
#define AT_P     25088    // 4 x 2048 -> 33280
#define AT_KB    33280    // 2 x 8192 -> 49664
#define AT_QF    8704     // prologue overlay
#define AT_RELT  17920    // prologue overlay
#define AT_PG    17920    // prologue overlay
#define AT_OF    8704     // epilogue overlay
#define AT_TOTAL 49664

__global__ __launch_bounds__(256, 3) void attn_kernel(
    const _Float16* __restrict__ qh, const _Float16* __restrict__ kh,
    const _Float16* __restrict__ vh, const _Float16* __restrict__ relTg,
    _Float16* __restrict__ aout)
{
    __shared__ __align__(16) char smem[AT_TOTAL];
    const int bid = blockIdx.x;
    const int j   = bid >> 3;
    const int bh  = (bid & 7) * 6 + (j >> 4);   // 0..47
    const int qb  = j & 15;                     // 0..15
    const int t  = threadIdx.x;
    const int w  = t >> 6;
    const int lane = t & 63;
    const int l15 = lane & 15, l4 = lane >> 4;

    _Float16* Rel = (_Float16*)(smem + AT_REL);
    _Float16* Qf  = (_Float16*)(smem + AT_QF);

    const int r = t >> 2, dc = (t & 3) * 16;
    {
        const _Float16* qp = qh + ((size_t)bh * HWN + qb * 64 + r) * HD + dc;
        *(short8*)(&Qf[r * 72 + dc])     = *(const short8*)(qp);
        *(short8*)(&Qf[r * 72 + dc + 8]) = *(const short8*)(qp + 8);
        #pragma unroll
        for (int it = 0; it < 4; ++it) {
            const int f = it * 4 + w;
            const int ct = f >> 1, ks = f & 1;
            gl_lds16((const char*)relTg + (ct * 16 + l15) * 128 + ks * 64 + l4 * 16,
                     smem + AT_RELT + f * 1024);
        }
    }
    __syncthreads();

    const _Float16* kb_ = kh + (size_t)bh * HWN * HD;
    const _Float16* vb_ = vh + (size_t)bh * HWN * HD;
    const int key2 = (t & 31) * 2, dgrp = t >> 5;
    short8 rv0, rv1;
#define LOADV(KT) {                                                            \
        const _Float16* vp = vb_ + (size_t)((KT) * 64 + key2) * HD + dgrp * 8; \
        rv0 = *(const short8*)vp; rv1 = *(const short8*)(vp + HD); }
    LOADV(0);

    h8 qf2[2];
    {
        const int qr = w * 16 + l15;
        qf2[0] = *(const h8*)(&Qf[qr * 72 + l4 * 8]);
        qf2[1] = *(const h8*)(&Qf[qr * 72 + 32 + l4 * 8]);
        #pragma unroll
        for (int j2 = 0; j2 < 8; ++j2) { qf2[0][j2] *= (_Float16)0.125f; qf2[1][j2] *= (_Float16)0.125f; }
    }

    f32x4 pacc[4][2];
    #pragma unroll
    for (int i = 0; i < 4; ++i)
        #pragma unroll
        for (int j2 = 0; j2 < 2; ++j2) pacc[i][j2] = (f32x4){0, 0, 0, 0};
    #pragma unroll
    for (int ks = 0; ks < 2; ++ks) {
        h8 b0 = *(const h8*)(smem + AT_RELT + ((w * 2 + 0) * 2 + ks) * 1024 + lane * 16);
        h8 b1 = *(const h8*)(smem + AT_RELT + ((w * 2 + 1) * 2 + ks) * 1024 + lane * 16);
        #pragma unroll
        for (int rt = 0; rt < 4; ++rt) {
            h8 a = *(const h8*)(&Qf[(rt * 16 + l15) * 72 + ks * 32 + l4 * 8]);
            pacc[rt][0] = __builtin_amdgcn_mfma_f32_16x16x32_f16(a, b0, pacc[rt][0], 0, 0, 0);
            pacc[rt][1] = __builtin_amdgcn_mfma_f32_16x16x32_f16(a, b1, pacc[rt][1], 0, 0, 0);
        }
    }

    __syncthreads();
    _Float16* Pg = (_Float16*)(smem + AT_PG);
    #pragma unroll
    for (int rt = 0; rt < 4; ++rt)
        #pragma unroll
        for (int cb2 = 0; cb2 < 2; ++cb2)
            #pragma unroll
            for (int reg = 0; reg < 4; ++reg)
                Pg[(rt * 16 + l4 * 4 + reg) * 130 + w * 32 + cb2 * 16 + l15] =
                    (_Float16)pacc[rt][cb2][reg];
    __syncthreads();

    {
        const int q = t >> 2, kk0 = (t & 3) * 8;
        const int hw = qb * 64 + q;
        const int hq = hw >> 5, wq = hw & 31;
        short8 vh_, vw_;
        #pragma unroll
        for (int j2 = 0; j2 < 8; ++j2) {
            const int kk = kk0 + j2;
            vh_[j2] = *(const short*)&Pg[q * 130 + (hq + 31 - kk)];
            vw_[j2] = *(const short*)&Pg[q * 130 + 64 + (wq + 31 - kk)];
        }
        *(short8*)(&Rel[q * 68 + kk0])      = vh_;
        *(short8*)(&Rel[q * 68 + 32 + kk0]) = vw_;
    }
    __syncthreads();

    const int qrow_bias = w * 16 + l15;
    float rw_[2][4];
    #pragma unroll
    for (int c2 = 0; c2 < 2; ++c2)
        #pragma unroll
        for (int reg = 0; reg < 4; ++reg)
            rw_[c2][reg] = (float)Rel[qrow_bias * 68 + 32 + c2 * 16 + l4 * 4 + reg];

#define STAGEK(KT, BUF) {                                                      \
        _Pragma("unroll")                                                      \
        for (int i2 = 0; i2 < 2; ++i2) {                                       \
            const int f = w * 2 + i2;                                          \
            const int keyk = f * 8 + (lane >> 3);                              \
            const int srcb = ((lane & 7) * 16) ^ ((lane >> 3) << 4);           \
            gl_lds16((const char*)kb_ + (size_t)((KT) * 64 + keyk) * 128 + srcb, \
                     smem + AT_KB + (BUF) * 8192 + f * 1024);                  \
        } }

#define WRITEVT(BUF) {                                                         \
        _Pragma("unroll")                                                      \
        for (int j2 = 0; j2 < 8; ++j2) {                                       \
            const int d = dgrp * 8 + j2;                                       \
            unsigned pk = ((unsigned short)rv0[j2]) |                          \
                          (((unsigned)(unsigned short)rv1[j2]) << 16);         \
            *(unsigned*)(smem + AT_VT + (BUF) * 8192 + d * 128 +               \
                         ((key2 * 2) ^ ((d & 7) << 4))) = pk; } }
    WRITEVT(0);
    STAGEK(0, 0);

    f32x4 acc_o[4] = {{0,0,0,0},{0,0,0,0},{0,0,0,0},{0,0,0,0}};
    float m_ = -INFINITY, lsum = 0.f;
    char* Pw = smem + AT_P + w * 2048;
    const int swzP = (l15 & 7) << 4;

    #pragma unroll 2
    for (int kt = 0; kt < 16; ++kt) {
        const int cur = kt & 1;
        __syncthreads();                 // K/V buf[cur] ready (drains gl_lds)
        if (kt < 15) { LOADV(kt + 1); STAGEK(kt + 1, cur ^ 1); }

        // ---- QK^T swapped from K-LDS: D[key][q], C-init = rel bias ----
        h2 rhp = *(const h2*)(&Rel[qrow_bias * 68 + kt * 2]);
        const float rh0 = (float)rhp[0];
        const float rh1 = (float)rhp[1];
        f32x4 accs[4];
        #pragma unroll
        for (int ct = 0; ct < 4; ++ct) {
            const float rhc = (ct >> 1) ? rh1 : rh0;
            #pragma unroll
            for (int reg = 0; reg < 4; ++reg)
                accs[ct][reg] = rw_[ct & 1][reg] + rhc;
        }
        __builtin_amdgcn_s_setprio(1);
        #pragma unroll
        for (int ct = 0; ct < 4; ++ct) {
            const int row = ct * 16 + l15;
            const int swzK = (row & 7) << 4;
            #pragma unroll
            for (int ks = 0; ks < 2; ++ks) {
                h8 kfr = *(const h8*)(smem + AT_KB + cur * 8192 + row * 128 +
                                      ((ks * 64 + l4 * 16) ^ swzK));
                accs[ct] = __builtin_amdgcn_mfma_f32_16x16x32_f16(kfr, qf2[ks], accs[ct], 0, 0, 0);
            }
        }
        __builtin_amdgcn_s_setprio(0);

        // ---- lane-local softmax: NO shuffles on the common path ----
        float mx[4];
        #pragma unroll
        for (int ct = 0; ct < 4; ++ct)
            mx[ct] = fmaxf(fmaxf(accs[ct][0], accs[ct][1]),
                           fmaxf(accs[ct][2], accs[ct][3]));
        float tmax = fmaxf(fmaxf(mx[0], mx[1]), fmaxf(mx[2], mx[3]));

        if (__any(tmax > m_ + 8.f)) {    // rare: group max + rescale
            float tg = fmaxf(tmax, __shfl_xor(tmax, 16));
            tg = fmaxf(tg, __shfl_xor(tg, 32));
            const float mnew = fmaxf(m_, tg);
            const float factor = __expf(m_ - mnew);
            m_ = mnew;
            lsum *= factor;
            #pragma unroll
            for (int reg = 0; reg < 4; ++reg) {
                const float fr = __shfl(factor, l4 * 4 + reg);
                #pragma unroll
                for (int dt = 0; dt < 4; ++dt) acc_o[dt][reg] *= fr;
            }
        }

        float tsum = 0.f;
        #pragma unroll
        for (int ct = 0; ct < 4; ++ct) {
            float p0 = __expf(accs[ct][0] - m_);
            float p1 = __expf(accs[ct][1] - m_);
            float p2 = __expf(accs[ct][2] - m_);
            float p3 = __expf(accs[ct][3] - m_);
            tsum += (p0 + p1) + (p2 + p3);
            h2 pa = {(_Float16)p0, (_Float16)p1};
            h2 pb = {(_Float16)p2, (_Float16)p3};
            uint2 pk;
            pk.x = *(unsigned*)&pa;
            pk.y = *(unsigned*)&pb;
            *(uint2*)(Pw + l15 * 128 + ((ct * 32 + l4 * 8) ^ swzP)) = pk;
        }
        lsum += tsum;                    // deferred reduction (no shuffles)

        // ---- PV ----
        __builtin_amdgcn_s_setprio(1);
        #pragma unroll
        for (int ks = 0; ks < 2; ++ks) {
            h8 pa = *(const h8*)(Pw + l15 * 128 + ((ks * 64 + l4 * 16) ^ swzP));
            #pragma unroll
            for (int dt = 0; dt < 4; ++dt) {
                const int d = dt * 16 + l15;
                h8 vf = *(const h8*)(smem + AT_VT + cur * 8192 + d * 128 +
                                     ((ks * 64 + l4 * 16) ^ ((d & 7) << 4)));
                acc_o[dt] = __builtin_amdgcn_mfma_f32_16x16x32_f16(pa, vf, acc_o[dt], 0, 0, 0);
            }
        }
        __builtin_amdgcn_s_setprio(0);

        if (kt < 15) WRITEVT(cur ^ 1);
    }

    // ---- final l reduction (once) + epilogue ----
    float ltot = lsum + __shfl_xor(lsum, 16);
    ltot += __shfl_xor(ltot, 32);
    const float invl = 1.0f / ltot;
    float linv[4];
    #pragma unroll
    for (int reg = 0; reg < 4; ++reg) linv[reg] = __shfl(invl, l4 * 4 + reg);
    __syncthreads();
    _Float16* Of = (_Float16*)(smem + AT_OF);
    #pragma unroll
    for (int reg = 0; reg < 4; ++reg) {
        const int qloc = w * 16 + l4 * 4 + reg;
        #pragma unroll
        for (int dt = 0; dt < 4; ++dt)
            Of[qloc * 72 + dt * 16 + l15] = (_Float16)(acc_o[dt][reg] * linv[reg]);
    }
    __syncthreads();
    {
        const int b_ = bh / NH, nh = bh % NH;
        _Float16* op = aout + ((size_t)b_ * HWN + qb * 64 + r) * DIM + nh * HD + dc;
        *(short8*)op       = *(const short8*)(&Of[r * 72 + dc]);
        *(short8*)(op + 8) = *(const short8*)(&Of[r * 72 + dc + 8]);
    }
}

// ---------------------------------------------------------------------------
extern "C" void kernel_launch(void* const* d_in, const int* in_sizes, int n_in,
                              void* d_out, int out_size, void* d_ws, size_t ws_size,
                              hipStream_t stream) {
    const float* q   = (const float*)d_in[0];
    const float* k   = (const float*)d_in[1];
    const float* v   = (const float*)d_in[2];
    const float* Wq  = (const float*)d_in[3];
    const float* bq  = (const float*)d_in[4];
    const float* Wk  = (const float*)d_in[5];
    const float* bk  = (const float*)d_in[6];
    const float* Wv  = (const float*)d_in[7];
    const float* bv  = (const float*)d_in[8];
    const float* Wp  = (const float*)d_in[9];
    const float* bp  = (const float*)d_in[10];
    const float* rph = (const float*)d_in[11];
    const float* rpw = (const float*)d_in[12];

    float* out = (float*)d_out;
    char*  w0  = (char*)d_ws;

    _Float16* wtAll = (_Float16*)(w0);                // 4,718,592
    _Float16* relTg = (_Float16*)(w0 + 4718592);      //    16,384
    _Float16* xf16  = (_Float16*)(w0 + 4734976);      // 18,874,368 (q,k,v fp16)
    _Float16* aout  = (_Float16*)(w0 + 4734976);      // overlays xf16 (dead by attn)
    _Float16* qf16  = (_Float16*)(w0 + 23609344);     // 6,291,456
    _Float16* kf16  = (_Float16*)(w0 + 29900800);     // 6,291,456
    _Float16* vf16  = (_Float16*)(w0 + 36192256);     // 6,291,456 -> 42,483,712

    dim3 blk(256);
    xconv_kernel<<<2048, blk, 0, stream>>>(q, k, v, xf16);
    wconv_kernel<<<dim3(12, 12, 4), blk, 0, stream>>>(Wq, Wk, Wv, Wp, wtAll);
    rel2frag_kernel<<<1, blk, 0, stream>>>(rph, rpw, relTg);
    gemm_mfma_kernel<0><<<768, blk, 0, stream>>>(
        xf16, wtAll, bq, bk, bv, qf16, kf16, vf16);
    attn_kernel<<<768, blk, 0, stream>>>(qf16, kf16, vf16, relTg, aout);
    gemm_mfma_kernel<1><<<512, blk, 0, stream>>>(
        aout, wtAll, bp, nullptr, nullptr, out, nullptr, nullptr);
}